// Round 15
// baseline (191.014 us; speedup 1.0000x reference)
//
#include <hip/hip_runtime.h>
#include <hip/hip_bf16.h>

#define BATCH 2
#define SEQ 2048
#define DMODEL 1024
#define NH 16
#define HD 64
#define NRF 266
#define NRFP 288   // padded feature dim (multiple of 32), cols [266,288) are zero
#define SROW 320   // transposed-S row stride
#define CHK 128
#define NCH 16
#define NBH 32
#define NROWS 4096  // BATCH*SEQ

constexpr float SCAL = 0.17677669529663687f;   // DMODEL^-0.25
constexpr float SCAL2 = 0.03125f;              // SCAL^2 = DMODEL^-0.5
constexpr float LN_CNORM = -2.7917480361965505f;   // ln(1/sqrt(266))
constexpr float CKEPS = 6.131393094576169e-6f;     // CNORM*KEPS

typedef short bf16x8 __attribute__((ext_vector_type(8)));
typedef float f32x4 __attribute__((ext_vector_type(4)));

__device__ __forceinline__ short f2bs(float v) {
  __hip_bfloat16 h = __float2bfloat16(v);
  return *reinterpret_cast<short*>(&h);
}
__device__ __forceinline__ float bs2f(short s) {
  __hip_bfloat16 h;
  *reinterpret_cast<short*>(&h) = s;
  return __bfloat162float(h);
}
__device__ __forceinline__ void gload_lds16(const void* g, void* l) {
  __builtin_amdgcn_global_load_lds(
      (const __attribute__((address_space(1))) void*)g,
      (__attribute__((address_space(3))) void*)l, 16, 0, 0);
}
// monotone float<->uint order encoding (for atomicMax over floats)
__device__ __forceinline__ unsigned f2ord(float f) {
  unsigned u = __float_as_uint(f);
  return (u & 0x80000000u) ? ~u : (u | 0x80000000u);
}
__device__ __forceinline__ float ord2f(unsigned e) {
  return (e & 0x80000000u) ? __uint_as_float(e & 0x7fffffffu)
                           : __uint_as_float(~e);
}

// ---------------- fused f32 -> bf16 convert for q,k,v ----------------
__global__ __launch_bounds__(256) void cvt3_kernel(const float* __restrict__ q,
                                                   const float* __restrict__ k,
                                                   const float* __restrict__ v,
                                                   short* __restrict__ out) {
  int z = blockIdx.y;
  const float* x = (z == 0) ? q : (z == 1) ? k : v;
  short* y = out + (size_t)z * NROWS * DMODEL;
  int i = (blockIdx.x * 256 + threadIdx.x) * 8;
  float4 a = *(const float4*)&x[i];
  float4 b = *(const float4*)&x[i + 4];
  bf16x8 o;
  o[0] = f2bs(a.x); o[1] = f2bs(a.y); o[2] = f2bs(a.z); o[3] = f2bs(a.w);
  o[4] = f2bs(b.x); o[5] = f2bs(b.y); o[6] = f2bs(b.z); o[7] = f2bs(b.w);
  *(bf16x8*)&y[i] = o;
}

// ---------------- rf pad + SCAL fold; also zero the kstab atomic slot ----------------
__global__ __launch_bounds__(256) void rf_pad_bf16(const float* __restrict__ rf,
                                                   short* __restrict__ rfb,
                                                   unsigned* __restrict__ kord) {
  int idx = blockIdx.x * 256 + threadIdx.x;  // grid 72*256 = 18432 exact
  rfb[idx] = (idx < NRF * HD) ? f2bs(rf[idx] * SCAL) : (short)0;
  if (idx == 0) *kord = 0u;
}

// ---------------- fused W transposes: W[K][N] f32 -> Wt[N][K] bf16, 4 weights ----------------
__global__ __launch_bounds__(256) void transpose4_bf16(
    const float* __restrict__ Wq, const float* __restrict__ Wk,
    const float* __restrict__ Wv, const float* __restrict__ Wo,
    short* __restrict__ WtBase) {
  __shared__ float t[32][33];
  int z = blockIdx.z;
  const float* W = (z == 0) ? Wq : (z == 1) ? Wk : (z == 2) ? Wv : Wo;
  short* Wt = WtBase + (size_t)z * DMODEL * DMODEL;
  int k0 = blockIdx.y << 5, n0 = blockIdx.x << 5;
  int tx = threadIdx.x & 31, ty = threadIdx.x >> 5;
#pragma unroll
  for (int rr = 0; rr < 4; ++rr) {
    int r = ty + (rr << 3);
    t[r][tx] = W[(size_t)(k0 + r) * DMODEL + n0 + tx];
  }
  __syncthreads();
#pragma unroll
  for (int rr = 0; rr < 4; ++rr) {
    int r = ty + (rr << 3);
    Wt[(size_t)(n0 + r) * DMODEL + k0 + tx] = f2bs(t[tx][r]);
  }
}

// ---------------- MFMA GEMM core 128x128, BK=64, dbuf + counted vmcnt ----------------
template <bool OUTBF>
__device__ __forceinline__ void gemm_core128(const short* __restrict__ A,
                                             const short* __restrict__ Bt,
                                             const float* __restrict__ bias,
                                             void* __restrict__ C, int bm, int bn) {
  __shared__ short As[2][128 * 64];
  __shared__ short Bs[2][128 * 64];
  int tid = threadIdx.x;
  int lane = tid & 63, wid = tid >> 6;
  int wr = wid >> 1, wc = wid & 1;
  int cl = lane & 15, rq = lane >> 4;
  f32x4 acc[4][4];
#pragma unroll
  for (int m = 0; m < 4; ++m)
#pragma unroll
    for (int n = 0; n < 4; ++n) acc[m][n] = f32x4{0.f, 0.f, 0.f, 0.f};

  auto stage = [&](int buf, int k0) {
#pragma unroll
    for (int i = 0; i < 4; ++i) {
      int e = tid * 8 + i * 2048;
      int row = e >> 6;
      int k = (e & 63) ^ ((row & 7) << 3);
      gload_lds16(A + (size_t)(bm + row) * DMODEL + k0 + k,
                  &As[buf][wid * 512 + i * 2048]);
    }
#pragma unroll
    for (int i = 0; i < 4; ++i) {
      int e = tid * 8 + i * 2048;
      int row = e >> 6;
      int k = (e & 63) ^ ((row & 7) << 3);
      gload_lds16(Bt + (size_t)(bn + row) * DMODEL + k0 + k,
                  &Bs[buf][wid * 512 + i * 2048]);
    }
  };

  stage(0, 0);
#pragma unroll 2
  for (int t = 0; t < 16; ++t) {
    int cur = t & 1;
    if (t < 15) {
      stage(cur ^ 1, (t + 1) * 64);
      asm volatile("s_waitcnt vmcnt(8)" ::: "memory");
    } else {
      asm volatile("s_waitcnt vmcnt(0)" ::: "memory");
    }
    __builtin_amdgcn_s_barrier();
    asm volatile("" ::: "memory");
    const short* curA = &As[cur][0];
    const short* curB = &Bs[cur][0];
#pragma unroll
    for (int ks = 0; ks < 2; ++ks) {
      int kb = ks * 32 + (rq << 3);
      bf16x8 af[4], bfv[4];
#pragma unroll
      for (int mf = 0; mf < 4; ++mf) {
        int row = wr * 64 + mf * 16 + cl;
        af[mf] = *(const bf16x8*)&curA[row * 64 + (kb ^ ((row & 7) << 3))];
      }
#pragma unroll
      for (int nf = 0; nf < 4; ++nf) {
        int row = wc * 64 + nf * 16 + cl;
        bfv[nf] = *(const bf16x8*)&curB[row * 64 + (kb ^ ((row & 7) << 3))];
      }
#pragma unroll
      for (int mf = 0; mf < 4; ++mf)
#pragma unroll
        for (int nf = 0; nf < 4; ++nf)
          acc[mf][nf] = __builtin_amdgcn_mfma_f32_16x16x32_bf16(af[mf], bfv[nf],
                                                                acc[mf][nf], 0, 0, 0);
    }
    __builtin_amdgcn_s_barrier();
    asm volatile("" ::: "memory");
  }
  int rbase = bm + wr * 64 + (rq << 2);
  int cbase = bn + wc * 64 + cl;
#pragma unroll
  for (int nf = 0; nf < 4; ++nf) {
    int col = cbase + nf * 16;
    float bv = bias[col];
#pragma unroll
    for (int mf = 0; mf < 4; ++mf)
#pragma unroll
      for (int r = 0; r < 4; ++r) {
        int row = rbase + mf * 16 + r;
        float v = acc[mf][nf][r] + bv;
        if (OUTBF)
          ((short*)C)[(size_t)row * DMODEL + col] = f2bs(v);
        else
          ((float*)C)[(size_t)row * DMODEL + col] = v;
      }
  }
}

// ---------------- MFMA GEMM core 128x64, BK=64, dbuf + counted vmcnt ----------------
template <bool OUTBF>
__device__ __forceinline__ void gemm_core64(const short* __restrict__ A,
                                            const short* __restrict__ Bt,
                                            const float* __restrict__ bias,
                                            void* __restrict__ C, int bm, int bn) {
  __shared__ short As[2][128 * 64];
  __shared__ short Bs[2][64 * 64];
  int tid = threadIdx.x;
  int lane = tid & 63, wid = tid >> 6;
  int wr = wid >> 1, wc = wid & 1;
  f32x4 acc[4][2];
#pragma unroll
  for (int m = 0; m < 4; ++m)
#pragma unroll
    for (int n = 0; n < 2; ++n) acc[m][n] = f32x4{0.f, 0.f, 0.f, 0.f};

  auto stage = [&](int buf, int k0) {
#pragma unroll
    for (int i = 0; i < 4; ++i) {
      int e = tid * 8 + i * 2048;
      int row = e >> 6;
      int k = (e & 63) ^ ((row & 7) << 3);
      gload_lds16(A + (size_t)(bm + row) * DMODEL + k0 + k,
                  &As[buf][wid * 512 + i * 2048]);
    }
#pragma unroll
    for (int i = 0; i < 2; ++i) {
      int e = tid * 8 + i * 2048;
      int row = e >> 6;
      int k = (e & 63) ^ ((row & 7) << 3);
      gload_lds16(Bt + (size_t)(bn + row) * DMODEL + k0 + k,
                  &Bs[buf][wid * 512 + i * 2048]);
    }
  };

  stage(0, 0);
#pragma unroll 2
  for (int t = 0; t < 16; ++t) {
    int cur = t & 1;
    if (t < 15) {
      stage(cur ^ 1, (t + 1) * 64);
      asm volatile("s_waitcnt vmcnt(6)" ::: "memory");
    } else {
      asm volatile("s_waitcnt vmcnt(0)" ::: "memory");
    }
    __builtin_amdgcn_s_barrier();
    asm volatile("" ::: "memory");
    const short* curA = &As[cur][0];
    const short* curB = &Bs[cur][0];
#pragma unroll
    for (int ks = 0; ks < 2; ++ks) {
      int kb = ks * 32 + ((lane >> 4) << 3);
      bf16x8 af[4], bfv[2];
#pragma unroll
      for (int mf = 0; mf < 4; ++mf) {
        int row = wr * 64 + mf * 16 + (lane & 15);
        af[mf] = *(const bf16x8*)&curA[row * 64 + (kb ^ ((row & 7) << 3))];
      }
#pragma unroll
      for (int nf = 0; nf < 2; ++nf) {
        int row = wc * 32 + nf * 16 + (lane & 15);
        bfv[nf] = *(const bf16x8*)&curB[row * 64 + (kb ^ ((row & 7) << 3))];
      }
#pragma unroll
      for (int mf = 0; mf < 4; ++mf)
#pragma unroll
        for (int nf = 0; nf < 2; ++nf)
          acc[mf][nf] = __builtin_amdgcn_mfma_f32_16x16x32_bf16(af[mf], bfv[nf],
                                                                acc[mf][nf], 0, 0, 0);
    }
    __builtin_amdgcn_s_barrier();
    asm volatile("" ::: "memory");
  }
  int rbase = bm + wr * 64 + ((lane >> 4) << 2);
  int cbase = bn + wc * 32 + (lane & 15);
#pragma unroll
  for (int nf = 0; nf < 2; ++nf) {
    int col = cbase + nf * 16;
    float bv = bias[col];
#pragma unroll
    for (int mf = 0; mf < 4; ++mf)
#pragma unroll
      for (int r = 0; r < 4; ++r) {
        int row = rbase + mf * 16 + r;
        float v = acc[mf][nf][r] + bv;
        if (OUTBF)
          ((short*)C)[(size_t)row * DMODEL + col] = f2bs(v);
        else
          ((float*)C)[(size_t)row * DMODEL + col] = v;
      }
  }
}

// fused QKV projection: grid (8, 32, 3), 128x128 tile, XCD-swizzled
__global__ __launch_bounds__(256) void gemm_qkv3(
    const short* __restrict__ Abase, const short* __restrict__ WtBase,
    const float* __restrict__ bq, const float* __restrict__ bk,
    const float* __restrict__ bv, short* __restrict__ OutBase) {
  int z = blockIdx.z;
  const short* A = Abase + (size_t)z * NROWS * DMODEL;
  const short* Bt = WtBase + (size_t)z * DMODEL * DMODEL;
  const float* bias = (z == 0) ? bq : (z == 1) ? bk : bv;
  short* C = OutBase + (size_t)z * NROWS * DMODEL;
  int bid = blockIdx.x + (blockIdx.y << 3);
  int swz = ((bid & 7) << 5) + (bid >> 3);
  int bn = (swz & 7) << 7;
  int bm = (swz >> 3) << 7;
  gemm_core128<true>(A, Bt, bias, C, bm, bn);
}

// output projection: grid (16, 32), 128x64 tile, XCD-swizzled
__global__ __launch_bounds__(256) void gemm_out(const short* __restrict__ A,
                                                const short* __restrict__ Bt,
                                                const float* __restrict__ bias,
                                                float* __restrict__ C) {
  int bid = blockIdx.x + (blockIdx.y << 4);  // nwg=512
  int swz = ((bid & 7) << 6) + (bid >> 3);
  int bn = (swz & 15) << 6;
  int bm = (swz >> 4) << 7;
  gemm_core64<false>(A, Bt, bias, C, bm, bn);
}

// ---------------- h_k: 256 blocks x 256 thr; thread = one (row,head); 1 atomic/block ----------------
__global__ __launch_bounds__(256) void hk_kernel(const short* __restrict__ Kb,
                                                 float* __restrict__ hkbuf,
                                                 unsigned* __restrict__ kord) {
  int tid = threadIdx.x;
  int rloc = tid >> 4, h = tid & 15;
  int n = blockIdx.x * 16 + rloc;
  const short* p = Kb + (size_t)n * DMODEL + h * HD;
  float ss = 0.f;
#pragma unroll
  for (int g = 0; g < 8; ++g) {
    bf16x8 v = *(const bf16x8*)(p + g * 8);
#pragma unroll
    for (int e = 0; e < 8; ++e) {
      float x = bs2f(v[e]);
      ss += x * x;
    }
  }
  float hkv = -0.5f * SCAL2 * ss;
  int b = n >> 11, l = n & (SEQ - 1);
  hkbuf[((size_t)(b * NH + h)) * SEQ + l] = hkv;
  __shared__ float red[256];
  red[tid] = hkv;
  __syncthreads();
  for (int s = 128; s > 0; s >>= 1) {
    if (tid < s) red[tid] = fmaxf(red[tid], red[tid + s]);
    __syncthreads();
  }
  if (tid == 0) atomicMax(kord, f2ord(red[0]));
}

// ---------------- feature map via MFMA (fast-exp epilogue) ----------------
__global__ __launch_bounds__(256, 1) void featmap_mfma(
    const short* __restrict__ Qproj, const short* __restrict__ Kproj,
    const short* __restrict__ rfb, const float* __restrict__ hkbuf,
    const unsigned* __restrict__ kord, short* __restrict__ Qp,
    short* __restrict__ Kp) {
  __shared__ short smem[26624];  // A:8192 | B:18432 ; epilogue reuses as P[128][152]
  __shared__ float hks[128];
  short* As = smem;
  short* Bs = smem + 8192;
  int isK = blockIdx.z;
  const short* X = isK ? Kproj : Qproj;
  short* O = isK ? Kp : Qp;
  int bh = blockIdx.y, b = bh >> 4, h = bh & 15;
  int l0 = blockIdx.x << 7;
  int tid = threadIdx.x, lane = tid & 63, wid = tid >> 6;
  int cl = lane & 15, rq = lane >> 4;

#pragma unroll
  for (int i = 0; i < 4; ++i) {
    int e = tid * 8 + i * 2048;
    int row = e >> 6;
    int k = (e & 63) ^ ((row & 7) << 3);
    gload_lds16(X + ((size_t)b * SEQ + l0 + row) * DMODEL + h * HD + k,
                &As[wid * 512 + i * 2048]);
  }
#pragma unroll
  for (int i = 0; i < 9; ++i) {
    int e = tid * 8 + i * 2048;
    int row = e >> 6;
    int k = (e & 63) ^ ((row & 7) << 3);
    gload_lds16(rfb + row * HD + k, &Bs[wid * 512 + i * 2048]);
  }
  if (isK) {
    float ksv = ord2f(*kord);
    if (tid < 128)
      hks[tid] = hkbuf[(size_t)bh * SEQ + l0 + tid] - ksv + LN_CNORM;
  }
  __syncthreads();

  int i0 = wid * 32;
  f32x4 acc[2][18];
#pragma unroll
  for (int m = 0; m < 2; ++m)
#pragma unroll
    for (int n = 0; n < 18; ++n) acc[m][n] = f32x4{0.f, 0.f, 0.f, 0.f};
#pragma unroll
  for (int ks = 0; ks < 2; ++ks) {
    int kb = ks * 32 + (rq << 3);
    int swz = (cl & 7) << 3;
    bf16x8 af[2];
#pragma unroll
    for (int mf = 0; mf < 2; ++mf) {
      int row = i0 + mf * 16 + cl;
      af[mf] = *(const bf16x8*)&As[row * 64 + (kb ^ swz)];
    }
#pragma unroll
    for (int nf = 0; nf < 18; ++nf) {
      int brow = nf * 16 + cl;
      bf16x8 bv = *(const bf16x8*)&Bs[brow * 64 + (kb ^ swz)];
#pragma unroll
      for (int mf = 0; mf < 2; ++mf)
        acc[mf][nf] = __builtin_amdgcn_mfma_f32_16x16x32_bf16(af[mf], bv,
                                                              acc[mf][nf], 0, 0, 0);
    }
  }

  short* Ps = smem;  // [128][152]
#pragma unroll
  for (int hf = 0; hf < 2; ++hf) {
    __syncthreads();
#pragma unroll
    for (int mf = 0; mf < 2; ++mf)
#pragma unroll
      for (int r = 0; r < 4; ++r) {
        int rl = i0 + mf * 16 + (rq << 2) + r;
        float addk = isK ? hks[rl] : LN_CNORM;
#pragma unroll
        for (int nf2 = 0; nf2 < 9; ++nf2) {
          int m = hf * 144 + nf2 * 16 + cl;
          float v = acc[mf][hf * 9 + nf2][r] + addk;
          float o = (m < NRF) ? (__expf(v) + CKEPS) : 0.f;
          Ps[rl * 152 + nf2 * 16 + cl] = f2bs(o);
        }
      }
    __syncthreads();
#pragma unroll
    for (int it = 0; it < 9; ++it) {
      int idx = tid + it * 256;
      int row = idx / 18, ch = idx - row * 18;
      bf16x8 val = *(const bf16x8*)&Ps[row * 152 + ch * 8];
      *(bf16x8*)&O[((size_t)bh * SEQ + l0 + row) * NRFP + hf * 144 + ch * 8] = val;
    }
  }
}

// ---------------- per-chunk sums via MFMA -> Sct TRANSPOSED [bh][c][d][SROW] bf16 ----------------
__global__ __launch_bounds__(256) void chunksum_mfma(
    const short* __restrict__ Kp, const short* __restrict__ Vb,
    short* __restrict__ Sct, float* __restrict__ ksum) {
  constexpr int ST = 70;
  __shared__ short KT[NRFP * ST];  // [m][i_loc]
  __shared__ short VT[HD * ST];    // [d][i_loc]
  int c = blockIdx.x, bh = blockIdx.y;
  int b = bh >> 4, h = bh & 15;
  int tid = threadIdx.x, lane = tid & 63, wv = tid >> 6;
  int cl = lane & 15, rq = lane >> 4;
  int irow = tid >> 2;
  int mq = tid & 3;
  size_t rowb = (size_t)bh * SEQ + (size_t)c * CHK;

  f32x4 acc[18];
#pragma unroll
  for (int m = 0; m < 18; ++m) acc[m] = f32x4{0.f, 0.f, 0.f, 0.f};
  float k1 = 0.f, k2 = 0.f;

  for (int hf = 0; hf < 2; ++hf) {
    __syncthreads();
    const short* Krow = Kp + (rowb + hf * 64 + irow) * NRFP;
#pragma unroll
    for (int cg = 0; cg < 9; ++cg) {
      int m0 = cg * 32 + mq * 8;
      bf16x8 v = *(const bf16x8*)(Krow + m0);
#pragma unroll
      for (int e = 0; e < 8; ++e) KT[(m0 + e) * ST + irow] = v[e];
    }
    const short* Vrow =
        Vb + ((size_t)b * SEQ + (size_t)c * CHK + hf * 64 + irow) * DMODEL + h * HD;
    {
      int d0 = mq * 16;
      bf16x8 v0 = *(const bf16x8*)(Vrow + d0);
      bf16x8 v1 = *(const bf16x8*)(Vrow + d0 + 8);
#pragma unroll
      for (int e = 0; e < 8; ++e) VT[(d0 + e) * ST + irow] = v0[e];
#pragma unroll
      for (int e = 0; e < 8; ++e) VT[(d0 + 8 + e) * ST + irow] = v1[e];
    }
    __syncthreads();
#pragma unroll
    for (int ks = 0; ks < 2; ++ks) {
      int kb = ks * 32 + rq * 8;
      bf16x8 bv = *(const bf16x8*)&VT[(wv * 16 + cl) * ST + kb];
#pragma unroll
      for (int mf = 0; mf < 18; ++mf) {
        bf16x8 av = *(const bf16x8*)&KT[(mf * 16 + cl) * ST + kb];
        acc[mf] = __builtin_amdgcn_mfma_f32_16x16x32_bf16(av, bv, acc[mf], 0, 0, 0);
      }
    }
    {
      const short* r1 = &KT[tid * ST];
#pragma unroll
      for (int g = 0; g < 8; ++g) {
        bf16x8 v = *(const bf16x8*)(r1 + g * 8);
#pragma unroll
        for (int e = 0; e < 8; ++e) k1 += bs2f(v[e]);
      }
      if (tid < 10) {
        const short* r2 = &KT[(256 + tid) * ST];
#pragma unroll
        for (int g = 0; g < 8; ++g) {
          bf16x8 v = *(const bf16x8*)(r2 + g * 8);
#pragma unroll
          for (int e = 0; e < 8; ++e) k2 += bs2f(v[e]);
        }
      }
    }
  }
  // transposed store: Sct[(bh,c)][d][m], d = wv*16+cl, m = mf*16 + rq*4 + r; stride SROW
  size_t sbase = ((size_t)bh * NCH + c) * (size_t)(HD * SROW);
  int d = wv * 16 + cl;
#pragma unroll
  for (int mf = 0; mf < 18; ++mf) {
    short4 o4 = make_short4(f2bs(acc[mf][0]), f2bs(acc[mf][1]),
                            f2bs(acc[mf][2]), f2bs(acc[mf][3]));
    *(short4*)&Sct[sbase + (size_t)d * SROW + mf * 16 + rq * 4] = o4;
  }
  // zero pad columns [288, 320)
  {
    int dz = tid >> 2, off = NRFP + ((tid & 3) << 3);
    bf16x8 z = {0, 0, 0, 0, 0, 0, 0, 0};
    *(bf16x8*)&Sct[sbase + (size_t)dz * SROW + off] = z;
  }
  size_t kbase = ((size_t)bh * NCH + c) * (size_t)NRF;
  if (tid < NRF) ksum[kbase + tid] = k1;
  if (tid < 10) ksum[kbase + 256 + tid] = k2;
}

// ---------------- fused exclusive prefixes over chunks ----------------
__global__ __launch_bounds__(256) void prefix_all(const short* __restrict__ Sct,
                                                  short* __restrict__ Spt,
                                                  const float* __restrict__ ksum,
                                                  short* __restrict__ ksb) {
  int bh = blockIdx.y;
  if (blockIdx.x == 80) {
    for (int m = threadIdx.x; m < NRFP; m += 256) {
      if (m < NRF) {
        size_t base = (size_t)bh * NCH * NRF + m;
        float a = 0.f;
#pragma unroll
        for (int c = 0; c < NCH; ++c) {
          float v = ksum[base + (size_t)c * NRF];
          ksb[((size_t)bh * NCH + c) * NRFP + m] = f2bs(a);
          a += v;
        }
      } else {
#pragma unroll
        for (int c = 0; c < NCH; ++c)
          ksb[((size_t)bh * NCH + c) * NRFP + m] = 0;
      }
    }
    return;
  }
  int e = blockIdx.x * 256 + threadIdx.x;  // over 64*SROW = 20480 (80 blocks exact)
  float a = 0.f;
#pragma unroll
  for (int c = 0; c < NCH; ++c) {
    size_t idx = ((size_t)bh * NCH + c) * (size_t)(HD * SROW) + e;
    float v = bs2f(Sct[idx]);
    Spt[idx] = f2bs(a);
    a += v;
  }
}

// ---------------- FUSED inter+intra, row-split (Z half) for 2x TLP ----------------
// Z=0: chunk rows 0..63 (history cols 0..63); Z=1: rows 64..127 (cols 0..127).
// Wave owns 16 rows. Sp^T + K fragments read directly from global (L2-hot).
template <int Z>
__device__ __forceinline__ void attn_body(short* smem, const short* __restrict__ Qp,
                                          const short* __restrict__ Kp,
                                          const short* __restrict__ Vb,
                                          const short* __restrict__ Spt,
                                          const short* __restrict__ ksb,
                                          short* __restrict__ ctxb, int c, int bh) {
  constexpr int JN = Z ? 128 : 64;   // history length
  constexpr int PST = Z ? 136 : 72;  // LDS row stride (shorts)
  constexpr int NPF = Z ? 8 : 4;     // P col fragments
  constexpr int KK = Z ? 4 : 2;      // PV k-steps
  short* Vt = smem;              // [64][PST] V^T
  short* Pl = smem + 64 * PST;   // [64][PST] P (block-local rows)
  int b = bh >> 4, h = bh & 15;
  int tid = threadIdx.x, lane = tid & 63, wid = tid >> 6;
  int cl = lane & 15, rq = lane >> 4;
  size_t rowb = (size_t)bh * SEQ + (size_t)c * CHK;

  // stage V^T: Vt[d][j] for j in [0, JN)
  {
    int jj = tid >> 3, d0 = (tid & 7) << 3;
#pragma unroll
    for (int jt = 0; jt < JN / 32; ++jt) {
      int j = jj + jt * 32;
      bf16x8 v = *(const bf16x8*)(Vb + ((size_t)b * SEQ + (size_t)c * CHK + j) * DMODEL +
                                  h * HD + d0);
#pragma unroll
      for (int e = 0; e < 8; ++e) Vt[(d0 + e) * PST + j] = v[e];
    }
  }
  __syncthreads();

  int i0 = Z * 64 + wid * 16;  // chunk-local wave row base
  const short* Arow = Qp + (rowb + i0) * NRFP;
  const short* Krow = Kp + rowb * NRFP;
  const short* SptG = Spt + ((size_t)bh * NCH + c) * (size_t)(HD * SROW);
  const short* krow = ksb + ((size_t)bh * NCH + c) * NRFP;
  f32x4 accI[4];
  f32x4 accD = f32x4{0.f, 0.f, 0.f, 0.f};
  f32x4 accP[NPF];
#pragma unroll
  for (int n = 0; n < 4; ++n) accI[n] = f32x4{0.f, 0.f, 0.f, 0.f};
#pragma unroll
  for (int n = 0; n < NPF; ++n) accP[n] = f32x4{0.f, 0.f, 0.f, 0.f};

#pragma unroll
  for (int k9 = 0; k9 < 9; ++k9) {
    int kb = k9 * 32 + (rq << 3);
    bf16x8 af = *(const bf16x8*)(Arow + (size_t)cl * NRFP + kb);
    bf16x8 bvD = {0, 0, 0, 0, 0, 0, 0, 0};
    if (cl == 0) bvD = *(const bf16x8*)(krow + kb);
    accD = __builtin_amdgcn_mfma_f32_16x16x32_bf16(af, bvD, accD, 0, 0, 0);
#pragma unroll
    for (int nf = 0; nf < 4; ++nf) {
      bf16x8 bv = *(const bf16x8*)(SptG + (size_t)(nf * 16 + cl) * SROW + kb);
      accI[nf] = __builtin_amdgcn_mfma_f32_16x16x32_bf16(af, bv, accI[nf], 0, 0, 0);
    }
#pragma unroll
    for (int nf = 0; nf < NPF; ++nf) {
      bf16x8 bv = *(const bf16x8*)(Krow + (size_t)(nf * 16 + cl) * NRFP + kb);
      accP[nf] = __builtin_amdgcn_mfma_f32_16x16x32_bf16(af, bv, accP[nf], 0, 0, 0);
    }
  }

  // mask, rowsum + den (registers); write P to LDS
  float dtot[4];
#pragma unroll
  for (int r = 0; r < 4; ++r) {
    int rl = (rq << 2) + r;       // wave-local row 0..15
    int rowc = i0 + rl;           // chunk row
    int rowl = wid * 16 + rl;     // block-local row 0..63
    float dsum = 0.f;
#pragma unroll
    for (int nf = 0; nf < NPF; ++nf) {
      int col = nf * 16 + cl;
      float v = (col > rowc) ? 0.f : accP[nf][r];
      dsum += v;
      Pl[rowl * PST + col] = f2bs(v);
    }
    dsum += __shfl_xor(dsum, 1);
    dsum += __shfl_xor(dsum, 2);
    dsum += __shfl_xor(dsum, 4);
    dsum += __shfl_xor(dsum, 8);
    float dden = __shfl(accD[r], lane & 48);  // broadcast from cl==0 of same rq
    dtot[r] = dden + dsum;
  }
  __syncthreads();

  // PV phase
  f32x4 pacc[4];
#pragma unroll
  for (int n = 0; n < 4; ++n) pacc[n] = f32x4{0.f, 0.f, 0.f, 0.f};
#pragma unroll
  for (int kk = 0; kk < KK; ++kk) {
    int kb = kk * 32 + (rq << 3);
    bf16x8 paf = *(const bf16x8*)&Pl[(wid * 16 + cl) * PST + kb];
#pragma unroll
    for (int nf = 0; nf < 4; ++nf) {
      bf16x8 bv = *(const bf16x8*)&Vt[(nf * 16 + cl) * PST + kb];
      pacc[nf] = __builtin_amdgcn_mfma_f32_16x16x32_bf16(paf, bv, pacc[nf], 0, 0, 0);
    }
  }
  // finalize
#pragma unroll
  for (int r = 0; r < 4; ++r) {
    int rowc = i0 + (rq << 2) + r;
    float inv = 1.0f / dtot[r];
    size_t ob = ((size_t)b * SEQ + (size_t)c * CHK + rowc) * DMODEL + h * HD;
#pragma unroll
    for (int nf = 0; nf < 4; ++nf) {
      int d = nf * 16 + cl;
      ctxb[ob + d] = f2bs((accI[nf][r] + pacc[nf][r]) * inv);
    }
  }
}

__global__ __launch_bounds__(256) void attn_mfma(
    const short* __restrict__ Qp, const short* __restrict__ Kp,
    const short* __restrict__ Vb, const short* __restrict__ Spt,
    const short* __restrict__ ksb, short* __restrict__ ctxb) {
  __shared__ short smem[2 * 64 * 136];  // 34816 B (Z=1 size; Z=0 uses prefix)
  int c = blockIdx.x, bh = blockIdx.y;
  if (blockIdx.z == 0)
    attn_body<0>(smem, Qp, Kp, Vb, Spt, ksb, ctxb, c, bh);
  else
    attn_body<1>(smem, Qp, Kp, Vb, Spt, ksb, ctxb, c, bh);
}

// ---------------- launch ----------------
extern "C" void kernel_launch(void* const* d_in, const int* in_sizes, int n_in,
                              void* d_out, int out_size, void* d_ws, size_t ws_size,
                              hipStream_t stream) {
  (void)in_sizes; (void)n_in; (void)out_size;
  const float* query = (const float*)d_in[0];
  const float* key_  = (const float*)d_in[1];
  const float* value = (const float*)d_in[2];
  const float* Wq = (const float*)d_in[3];
  const float* bq = (const float*)d_in[4];
  const float* Wk = (const float*)d_in[5];
  const float* bk = (const float*)d_in[6];
  const float* Wv = (const float*)d_in[7];
  const float* bv = (const float*)d_in[8];
  const float* Wo = (const float*)d_in[9];
  const float* bo = (const float*)d_in[10];
  const float* rf = (const float*)d_in[11];

  constexpr size_t SZ_INBF = (size_t)NROWS * DMODEL * 2;
  constexpr size_t SZ_QP   = (size_t)NBH * SEQ * NRFP * 2;
  constexpr size_t SZ_WT   = (size_t)DMODEL * DMODEL * 2;
  constexpr size_t SZ_SCH  = (size_t)NBH * NCH * HD * SROW * 2;
  constexpr size_t SZ_KS   = (size_t)NBH * NCH * NRF * 4;
  constexpr size_t SZ_KSB  = (size_t)NBH * NCH * NRFP * 2;
  constexpr size_t SZ_HK   = (size_t)NBH * SEQ * 4;
  constexpr size_t SZ_RFB  = (size_t)NRFP * HD * 2;

  constexpr size_t O_QP   = 0;
  constexpr size_t O_KP   = O_QP + SZ_QP;
  constexpr size_t O_WT   = O_KP + SZ_QP;
  constexpr size_t O_QPR  = O_WT + 4 * SZ_WT;
  constexpr size_t O_SCH  = O_QPR + 3 * SZ_INBF;
  constexpr size_t O_SPR  = O_SCH + SZ_SCH;
  constexpr size_t O_KSUM = O_SPR + SZ_SCH;
  constexpr size_t O_KSB  = O_KSUM + SZ_KS;
  constexpr size_t O_HK   = O_KSB + SZ_KSB;
  constexpr size_t O_KST  = O_HK + SZ_HK;
  constexpr size_t O_CTXB = O_KST + 256;
  constexpr size_t O_RFB  = O_CTXB + SZ_INBF;
  constexpr size_t O_END  = O_RFB + SZ_RFB;
  if (ws_size < O_END) return;

  char* w = (char*)d_ws;
  short* Qbf  = (short*)(w + O_QP);
  short* Qp   = (short*)(w + O_QP);
  short* Kp   = (short*)(w + O_KP);
  short* WtB  = (short*)(w + O_WT);
  short* QprB = (short*)(w + O_QPR);
  short* Kpr  = (short*)(w + O_QPR + SZ_INBF);
  short* Vpr  = (short*)(w + O_QPR + 2 * SZ_INBF);
  short* Sct  = (short*)(w + O_SCH);
  short* Spt  = (short*)(w + O_SPR);
  float* ksum = (float*)(w + O_KSUM);
  short* ksb  = (short*)(w + O_KSB);
  float* hkbuf = (float*)(w + O_HK);
  unsigned* kord = (unsigned*)(w + O_KST);
  short* ctxb = (short*)(w + O_CTXB);
  short* rfb  = (short*)(w + O_RFB);

  constexpr int NEL = NROWS * DMODEL;
  cvt3_kernel<<<dim3(NEL / 2048, 3), 256, 0, stream>>>(query, key_, value, Qbf);
  transpose4_bf16<<<dim3(32, 32, 4), 256, 0, stream>>>(Wq, Wk, Wv, Wo, WtB);
  rf_pad_bf16<<<(NRFP * HD) / 256, 256, 0, stream>>>(rf, rfb, kord);
  gemm_qkv3<<<dim3(8, 32, 3), 256, 0, stream>>>(Qbf, WtB, bq, bk, bv, QprB);
  hk_kernel<<<256, 256, 0, stream>>>(Kpr, hkbuf, kord);
  featmap_mfma<<<dim3(SEQ / 128, NBH, 2), 256, 0, stream>>>(QprB, Kpr, rfb, hkbuf,
                                                            kord, Qp, Kp);
  chunksum_mfma<<<dim3(NCH, NBH), 256, 0, stream>>>(Kp, Vpr, Sct, ksum);
  prefix_all<<<dim3(81, NBH), 256, 0, stream>>>(Sct, Spt, ksum, ksb);
  attn_mfma<<<dim3(NCH, NBH, 2), 256, 0, stream>>>(Qp, Kp, Vpr, Spt, ksb, ctxb);
  gemm_out<<<dim3(16, 32), 256, 0, stream>>>(ctxb, WtB + 3 * (size_t)DMODEL * DMODEL,
                                             bo, (float*)d_out);
}

// Round 16
// 171.292 us; speedup vs baseline: 1.1151x; 1.1151x over previous
//
#include <hip/hip_runtime.h>
#include <hip/hip_bf16.h>

#define BATCH 2
#define SEQ 2048
#define DMODEL 1024
#define NH 16
#define HD 64
#define NRF 266
#define NRFP 288   // padded feature dim (multiple of 32), cols [266,288) are zero
#define SROW 320   // transposed-S row stride
#define CHK 128
#define NCH 16
#define NBH 32
#define NROWS 4096  // BATCH*SEQ

constexpr float SCAL = 0.17677669529663687f;   // DMODEL^-0.25
constexpr float SCAL2 = 0.03125f;              // SCAL^2 = DMODEL^-0.5
constexpr float LN_CNORM = -2.7917480361965505f;   // ln(1/sqrt(266))
constexpr float CKEPS = 6.131393094576169e-6f;     // CNORM*KEPS

typedef short bf16x8 __attribute__((ext_vector_type(8)));
typedef float f32x4 __attribute__((ext_vector_type(4)));

__device__ __forceinline__ short f2bs(float v) {
  __hip_bfloat16 h = __float2bfloat16(v);
  return *reinterpret_cast<short*>(&h);
}
__device__ __forceinline__ float bs2f(short s) {
  __hip_bfloat16 h;
  *reinterpret_cast<short*>(&h) = s;
  return __bfloat162float(h);
}
__device__ __forceinline__ void gload_lds16(const void* g, void* l) {
  __builtin_amdgcn_global_load_lds(
      (const __attribute__((address_space(1))) void*)g,
      (__attribute__((address_space(3))) void*)l, 16, 0, 0);
}
// monotone float<->uint order encoding (for atomicMax over floats)
__device__ __forceinline__ unsigned f2ord(float f) {
  unsigned u = __float_as_uint(f);
  return (u & 0x80000000u) ? ~u : (u | 0x80000000u);
}
__device__ __forceinline__ float ord2f(unsigned e) {
  return (e & 0x80000000u) ? __uint_as_float(e & 0x7fffffffu)
                           : __uint_as_float(~e);
}

// ---------------- fused f32 -> bf16 convert for q,k,v ----------------
__global__ __launch_bounds__(256) void cvt3_kernel(const float* __restrict__ q,
                                                   const float* __restrict__ k,
                                                   const float* __restrict__ v,
                                                   short* __restrict__ out) {
  int z = blockIdx.y;
  const float* x = (z == 0) ? q : (z == 1) ? k : v;
  short* y = out + (size_t)z * NROWS * DMODEL;
  int i = (blockIdx.x * 256 + threadIdx.x) * 8;
  float4 a = *(const float4*)&x[i];
  float4 b = *(const float4*)&x[i + 4];
  bf16x8 o;
  o[0] = f2bs(a.x); o[1] = f2bs(a.y); o[2] = f2bs(a.z); o[3] = f2bs(a.w);
  o[4] = f2bs(b.x); o[5] = f2bs(b.y); o[6] = f2bs(b.z); o[7] = f2bs(b.w);
  *(bf16x8*)&y[i] = o;
}

// ---------------- rf pad + SCAL fold; also zero the kstab atomic slot ----------------
__global__ __launch_bounds__(256) void rf_pad_bf16(const float* __restrict__ rf,
                                                   short* __restrict__ rfb,
                                                   unsigned* __restrict__ kord) {
  int idx = blockIdx.x * 256 + threadIdx.x;  // grid 72*256 = 18432 exact
  rfb[idx] = (idx < NRF * HD) ? f2bs(rf[idx] * SCAL) : (short)0;
  if (idx == 0) *kord = 0u;
}

// ---------------- fused W transposes: W[K][N] f32 -> Wt[N][K] bf16, 4 weights ----------------
__global__ __launch_bounds__(256) void transpose4_bf16(
    const float* __restrict__ Wq, const float* __restrict__ Wk,
    const float* __restrict__ Wv, const float* __restrict__ Wo,
    short* __restrict__ WtBase) {
  __shared__ float t[32][33];
  int z = blockIdx.z;
  const float* W = (z == 0) ? Wq : (z == 1) ? Wk : (z == 2) ? Wv : Wo;
  short* Wt = WtBase + (size_t)z * DMODEL * DMODEL;
  int k0 = blockIdx.y << 5, n0 = blockIdx.x << 5;
  int tx = threadIdx.x & 31, ty = threadIdx.x >> 5;
#pragma unroll
  for (int rr = 0; rr < 4; ++rr) {
    int r = ty + (rr << 3);
    t[r][tx] = W[(size_t)(k0 + r) * DMODEL + n0 + tx];
  }
  __syncthreads();
#pragma unroll
  for (int rr = 0; rr < 4; ++rr) {
    int r = ty + (rr << 3);
    Wt[(size_t)(n0 + r) * DMODEL + k0 + tx] = f2bs(t[tx][r]);
  }
}

// ---------------- MFMA GEMM core 128x128, BK=64, dbuf + counted vmcnt ----------------
template <bool OUTBF>
__device__ __forceinline__ void gemm_core128(const short* __restrict__ A,
                                             const short* __restrict__ Bt,
                                             const float* __restrict__ bias,
                                             void* __restrict__ C, int bm, int bn) {
  __shared__ short As[2][128 * 64];
  __shared__ short Bs[2][128 * 64];
  int tid = threadIdx.x;
  int lane = tid & 63, wid = tid >> 6;
  int wr = wid >> 1, wc = wid & 1;
  int cl = lane & 15, rq = lane >> 4;
  f32x4 acc[4][4];
#pragma unroll
  for (int m = 0; m < 4; ++m)
#pragma unroll
    for (int n = 0; n < 4; ++n) acc[m][n] = f32x4{0.f, 0.f, 0.f, 0.f};

  auto stage = [&](int buf, int k0) {
#pragma unroll
    for (int i = 0; i < 4; ++i) {
      int e = tid * 8 + i * 2048;
      int row = e >> 6;
      int k = (e & 63) ^ ((row & 7) << 3);
      gload_lds16(A + (size_t)(bm + row) * DMODEL + k0 + k,
                  &As[buf][wid * 512 + i * 2048]);
    }
#pragma unroll
    for (int i = 0; i < 4; ++i) {
      int e = tid * 8 + i * 2048;
      int row = e >> 6;
      int k = (e & 63) ^ ((row & 7) << 3);
      gload_lds16(Bt + (size_t)(bn + row) * DMODEL + k0 + k,
                  &Bs[buf][wid * 512 + i * 2048]);
    }
  };

  stage(0, 0);
#pragma unroll 2
  for (int t = 0; t < 16; ++t) {
    int cur = t & 1;
    if (t < 15) {
      stage(cur ^ 1, (t + 1) * 64);
      asm volatile("s_waitcnt vmcnt(8)" ::: "memory");
    } else {
      asm volatile("s_waitcnt vmcnt(0)" ::: "memory");
    }
    __builtin_amdgcn_s_barrier();
    asm volatile("" ::: "memory");
    const short* curA = &As[cur][0];
    const short* curB = &Bs[cur][0];
#pragma unroll
    for (int ks = 0; ks < 2; ++ks) {
      int kb = ks * 32 + (rq << 3);
      bf16x8 af[4], bfv[4];
#pragma unroll
      for (int mf = 0; mf < 4; ++mf) {
        int row = wr * 64 + mf * 16 + cl;
        af[mf] = *(const bf16x8*)&curA[row * 64 + (kb ^ ((row & 7) << 3))];
      }
#pragma unroll
      for (int nf = 0; nf < 4; ++nf) {
        int row = wc * 64 + nf * 16 + cl;
        bfv[nf] = *(const bf16x8*)&curB[row * 64 + (kb ^ ((row & 7) << 3))];
      }
#pragma unroll
      for (int mf = 0; mf < 4; ++mf)
#pragma unroll
        for (int nf = 0; nf < 4; ++nf)
          acc[mf][nf] = __builtin_amdgcn_mfma_f32_16x16x32_bf16(af[mf], bfv[nf],
                                                                acc[mf][nf], 0, 0, 0);
    }
    __builtin_amdgcn_s_barrier();
    asm volatile("" ::: "memory");
  }
  int rbase = bm + wr * 64 + (rq << 2);
  int cbase = bn + wc * 64 + cl;
#pragma unroll
  for (int nf = 0; nf < 4; ++nf) {
    int col = cbase + nf * 16;
    float bv = bias[col];
#pragma unroll
    for (int mf = 0; mf < 4; ++mf)
#pragma unroll
      for (int r = 0; r < 4; ++r) {
        int row = rbase + mf * 16 + r;
        float v = acc[mf][nf][r] + bv;
        if (OUTBF)
          ((short*)C)[(size_t)row * DMODEL + col] = f2bs(v);
        else
          ((float*)C)[(size_t)row * DMODEL + col] = v;
      }
  }
}

// ---------------- MFMA GEMM core 128x64, BK=64, dbuf + counted vmcnt ----------------
template <bool OUTBF>
__device__ __forceinline__ void gemm_core64(const short* __restrict__ A,
                                            const short* __restrict__ Bt,
                                            const float* __restrict__ bias,
                                            void* __restrict__ C, int bm, int bn) {
  __shared__ short As[2][128 * 64];
  __shared__ short Bs[2][64 * 64];
  int tid = threadIdx.x;
  int lane = tid & 63, wid = tid >> 6;
  int wr = wid >> 1, wc = wid & 1;
  f32x4 acc[4][2];
#pragma unroll
  for (int m = 0; m < 4; ++m)
#pragma unroll
    for (int n = 0; n < 2; ++n) acc[m][n] = f32x4{0.f, 0.f, 0.f, 0.f};

  auto stage = [&](int buf, int k0) {
#pragma unroll
    for (int i = 0; i < 4; ++i) {
      int e = tid * 8 + i * 2048;
      int row = e >> 6;
      int k = (e & 63) ^ ((row & 7) << 3);
      gload_lds16(A + (size_t)(bm + row) * DMODEL + k0 + k,
                  &As[buf][wid * 512 + i * 2048]);
    }
#pragma unroll
    for (int i = 0; i < 2; ++i) {
      int e = tid * 8 + i * 2048;
      int row = e >> 6;
      int k = (e & 63) ^ ((row & 7) << 3);
      gload_lds16(Bt + (size_t)(bn + row) * DMODEL + k0 + k,
                  &Bs[buf][wid * 512 + i * 2048]);
    }
  };

  stage(0, 0);
#pragma unroll 2
  for (int t = 0; t < 16; ++t) {
    int cur = t & 1;
    if (t < 15) {
      stage(cur ^ 1, (t + 1) * 64);
      asm volatile("s_waitcnt vmcnt(6)" ::: "memory");
    } else {
      asm volatile("s_waitcnt vmcnt(0)" ::: "memory");
    }
    __builtin_amdgcn_s_barrier();
    asm volatile("" ::: "memory");
    const short* curA = &As[cur][0];
    const short* curB = &Bs[cur][0];
#pragma unroll
    for (int ks = 0; ks < 2; ++ks) {
      int kb = ks * 32 + ((lane >> 4) << 3);
      bf16x8 af[4], bfv[2];
#pragma unroll
      for (int mf = 0; mf < 4; ++mf) {
        int row = wr * 64 + mf * 16 + (lane & 15);
        af[mf] = *(const bf16x8*)&curA[row * 64 + (kb ^ ((row & 7) << 3))];
      }
#pragma unroll
      for (int nf = 0; nf < 2; ++nf) {
        int row = wc * 32 + nf * 16 + (lane & 15);
        bfv[nf] = *(const bf16x8*)&curB[row * 64 + (kb ^ ((row & 7) << 3))];
      }
#pragma unroll
      for (int mf = 0; mf < 4; ++mf)
#pragma unroll
        for (int nf = 0; nf < 2; ++nf)
          acc[mf][nf] = __builtin_amdgcn_mfma_f32_16x16x32_bf16(af[mf], bfv[nf],
                                                                acc[mf][nf], 0, 0, 0);
    }
    __builtin_amdgcn_s_barrier();
    asm volatile("" ::: "memory");
  }
  int rbase = bm + wr * 64 + ((lane >> 4) << 2);
  int cbase = bn + wc * 32 + (lane & 15);
#pragma unroll
  for (int nf = 0; nf < 2; ++nf) {
    int col = cbase + nf * 16;
    float bv = bias[col];
#pragma unroll
    for (int mf = 0; mf < 4; ++mf)
#pragma unroll
      for (int r = 0; r < 4; ++r) {
        int row = rbase + mf * 16 + r;
        float v = acc[mf][nf][r] + bv;
        if (OUTBF)
          ((short*)C)[(size_t)row * DMODEL + col] = f2bs(v);
        else
          ((float*)C)[(size_t)row * DMODEL + col] = v;
      }
  }
}

// fused QKV projection: grid (8, 32, 3), 128x128 tile, XCD-swizzled
__global__ __launch_bounds__(256) void gemm_qkv3(
    const short* __restrict__ Abase, const short* __restrict__ WtBase,
    const float* __restrict__ bq, const float* __restrict__ bk,
    const float* __restrict__ bv, short* __restrict__ OutBase) {
  int z = blockIdx.z;
  const short* A = Abase + (size_t)z * NROWS * DMODEL;
  const short* Bt = WtBase + (size_t)z * DMODEL * DMODEL;
  const float* bias = (z == 0) ? bq : (z == 1) ? bk : bv;
  short* C = OutBase + (size_t)z * NROWS * DMODEL;
  int bid = blockIdx.x + (blockIdx.y << 3);
  int swz = ((bid & 7) << 5) + (bid >> 3);
  int bn = (swz & 7) << 7;
  int bm = (swz >> 3) << 7;
  gemm_core128<true>(A, Bt, bias, C, bm, bn);
}

// output projection: grid (16, 32), 128x64 tile, XCD-swizzled
__global__ __launch_bounds__(256) void gemm_out(const short* __restrict__ A,
                                                const short* __restrict__ Bt,
                                                const float* __restrict__ bias,
                                                float* __restrict__ C) {
  int bid = blockIdx.x + (blockIdx.y << 4);  // nwg=512
  int swz = ((bid & 7) << 6) + (bid >> 3);
  int bn = (swz & 15) << 6;
  int bm = (swz >> 4) << 7;
  gemm_core64<false>(A, Bt, bias, C, bm, bn);
}

// ---------------- h_k: 256 blocks x 256 thr; thread = one (row,head); 1 atomic/block ----------------
__global__ __launch_bounds__(256) void hk_kernel(const short* __restrict__ Kb,
                                                 float* __restrict__ hkbuf,
                                                 unsigned* __restrict__ kord) {
  int tid = threadIdx.x;
  int rloc = tid >> 4, h = tid & 15;
  int n = blockIdx.x * 16 + rloc;
  const short* p = Kb + (size_t)n * DMODEL + h * HD;
  float ss = 0.f;
#pragma unroll
  for (int g = 0; g < 8; ++g) {
    bf16x8 v = *(const bf16x8*)(p + g * 8);
#pragma unroll
    for (int e = 0; e < 8; ++e) {
      float x = bs2f(v[e]);
      ss += x * x;
    }
  }
  float hkv = -0.5f * SCAL2 * ss;
  int b = n >> 11, l = n & (SEQ - 1);
  hkbuf[((size_t)(b * NH + h)) * SEQ + l] = hkv;
  __shared__ float red[256];
  red[tid] = hkv;
  __syncthreads();
  for (int s = 128; s > 0; s >>= 1) {
    if (tid < s) red[tid] = fmaxf(red[tid], red[tid + s]);
    __syncthreads();
  }
  if (tid == 0) atomicMax(kord, f2ord(red[0]));
}

// ---------------- feature map via MFMA (fast-exp epilogue) ----------------
__global__ __launch_bounds__(256, 1) void featmap_mfma(
    const short* __restrict__ Qproj, const short* __restrict__ Kproj,
    const short* __restrict__ rfb, const float* __restrict__ hkbuf,
    const unsigned* __restrict__ kord, short* __restrict__ Qp,
    short* __restrict__ Kp) {
  __shared__ short smem[26624];  // A:8192 | B:18432 ; epilogue reuses as P[128][152]
  __shared__ float hks[128];
  short* As = smem;
  short* Bs = smem + 8192;
  int isK = blockIdx.z;
  const short* X = isK ? Kproj : Qproj;
  short* O = isK ? Kp : Qp;
  int bh = blockIdx.y, b = bh >> 4, h = bh & 15;
  int l0 = blockIdx.x << 7;
  int tid = threadIdx.x, lane = tid & 63, wid = tid >> 6;
  int cl = lane & 15, rq = lane >> 4;

#pragma unroll
  for (int i = 0; i < 4; ++i) {
    int e = tid * 8 + i * 2048;
    int row = e >> 6;
    int k = (e & 63) ^ ((row & 7) << 3);
    gload_lds16(X + ((size_t)b * SEQ + l0 + row) * DMODEL + h * HD + k,
                &As[wid * 512 + i * 2048]);
  }
#pragma unroll
  for (int i = 0; i < 9; ++i) {
    int e = tid * 8 + i * 2048;
    int row = e >> 6;
    int k = (e & 63) ^ ((row & 7) << 3);
    gload_lds16(rfb + row * HD + k, &Bs[wid * 512 + i * 2048]);
  }
  if (isK) {
    float ksv = ord2f(*kord);
    if (tid < 128)
      hks[tid] = hkbuf[(size_t)bh * SEQ + l0 + tid] - ksv + LN_CNORM;
  }
  __syncthreads();

  int i0 = wid * 32;
  f32x4 acc[2][18];
#pragma unroll
  for (int m = 0; m < 2; ++m)
#pragma unroll
    for (int n = 0; n < 18; ++n) acc[m][n] = f32x4{0.f, 0.f, 0.f, 0.f};
#pragma unroll
  for (int ks = 0; ks < 2; ++ks) {
    int kb = ks * 32 + (rq << 3);
    int swz = (cl & 7) << 3;
    bf16x8 af[2];
#pragma unroll
    for (int mf = 0; mf < 2; ++mf) {
      int row = i0 + mf * 16 + cl;
      af[mf] = *(const bf16x8*)&As[row * 64 + (kb ^ swz)];
    }
#pragma unroll
    for (int nf = 0; nf < 18; ++nf) {
      int brow = nf * 16 + cl;
      bf16x8 bv = *(const bf16x8*)&Bs[brow * 64 + (kb ^ swz)];
#pragma unroll
      for (int mf = 0; mf < 2; ++mf)
        acc[mf][nf] = __builtin_amdgcn_mfma_f32_16x16x32_bf16(af[mf], bv,
                                                              acc[mf][nf], 0, 0, 0);
    }
  }

  short* Ps = smem;  // [128][152]
#pragma unroll
  for (int hf = 0; hf < 2; ++hf) {
    __syncthreads();
#pragma unroll
    for (int mf = 0; mf < 2; ++mf)
#pragma unroll
      for (int r = 0; r < 4; ++r) {
        int rl = i0 + mf * 16 + (rq << 2) + r;
        float addk = isK ? hks[rl] : LN_CNORM;
#pragma unroll
        for (int nf2 = 0; nf2 < 9; ++nf2) {
          int m = hf * 144 + nf2 * 16 + cl;
          float v = acc[mf][hf * 9 + nf2][r] + addk;
          float o = (m < NRF) ? (__expf(v) + CKEPS) : 0.f;
          Ps[rl * 152 + nf2 * 16 + cl] = f2bs(o);
        }
      }
    __syncthreads();
#pragma unroll
    for (int it = 0; it < 9; ++it) {
      int idx = tid + it * 256;
      int row = idx / 18, ch = idx - row * 18;
      bf16x8 val = *(const bf16x8*)&Ps[row * 152 + ch * 8];
      *(bf16x8*)&O[((size_t)bh * SEQ + l0 + row) * NRFP + hf * 144 + ch * 8] = val;
    }
  }
}

// ---------------- per-chunk sums via MFMA -> Sct TRANSPOSED [bh][c][d][SROW] bf16 ----------------
__global__ __launch_bounds__(256) void chunksum_mfma(
    const short* __restrict__ Kp, const short* __restrict__ Vb,
    short* __restrict__ Sct, float* __restrict__ ksum) {
  constexpr int ST = 70;
  __shared__ short KT[NRFP * ST];  // [m][i_loc]
  __shared__ short VT[HD * ST];    // [d][i_loc]
  int c = blockIdx.x, bh = blockIdx.y;
  int b = bh >> 4, h = bh & 15;
  int tid = threadIdx.x, lane = tid & 63, wv = tid >> 6;
  int cl = lane & 15, rq = lane >> 4;
  int irow = tid >> 2;
  int mq = tid & 3;
  size_t rowb = (size_t)bh * SEQ + (size_t)c * CHK;

  f32x4 acc[18];
#pragma unroll
  for (int m = 0; m < 18; ++m) acc[m] = f32x4{0.f, 0.f, 0.f, 0.f};
  float k1 = 0.f, k2 = 0.f;

  for (int hf = 0; hf < 2; ++hf) {
    __syncthreads();
    const short* Krow = Kp + (rowb + hf * 64 + irow) * NRFP;
#pragma unroll
    for (int cg = 0; cg < 9; ++cg) {
      int m0 = cg * 32 + mq * 8;
      bf16x8 v = *(const bf16x8*)(Krow + m0);
#pragma unroll
      for (int e = 0; e < 8; ++e) KT[(m0 + e) * ST + irow] = v[e];
    }
    const short* Vrow =
        Vb + ((size_t)b * SEQ + (size_t)c * CHK + hf * 64 + irow) * DMODEL + h * HD;
    {
      int d0 = mq * 16;
      bf16x8 v0 = *(const bf16x8*)(Vrow + d0);
      bf16x8 v1 = *(const bf16x8*)(Vrow + d0 + 8);
#pragma unroll
      for (int e = 0; e < 8; ++e) VT[(d0 + e) * ST + irow] = v0[e];
#pragma unroll
      for (int e = 0; e < 8; ++e) VT[(d0 + 8 + e) * ST + irow] = v1[e];
    }
    __syncthreads();
#pragma unroll
    for (int ks = 0; ks < 2; ++ks) {
      int kb = ks * 32 + rq * 8;
      bf16x8 bv = *(const bf16x8*)&VT[(wv * 16 + cl) * ST + kb];
#pragma unroll
      for (int mf = 0; mf < 18; ++mf) {
        bf16x8 av = *(const bf16x8*)&KT[(mf * 16 + cl) * ST + kb];
        acc[mf] = __builtin_amdgcn_mfma_f32_16x16x32_bf16(av, bv, acc[mf], 0, 0, 0);
      }
    }
    {
      const short* r1 = &KT[tid * ST];
#pragma unroll
      for (int g = 0; g < 8; ++g) {
        bf16x8 v = *(const bf16x8*)(r1 + g * 8);
#pragma unroll
        for (int e = 0; e < 8; ++e) k1 += bs2f(v[e]);
      }
      if (tid < 10) {
        const short* r2 = &KT[(256 + tid) * ST];
#pragma unroll
        for (int g = 0; g < 8; ++g) {
          bf16x8 v = *(const bf16x8*)(r2 + g * 8);
#pragma unroll
          for (int e = 0; e < 8; ++e) k2 += bs2f(v[e]);
        }
      }
    }
  }
  // transposed store: Sct[(bh,c)][d][m], d = wv*16+cl, m = mf*16 + rq*4 + r; stride SROW
  size_t sbase = ((size_t)bh * NCH + c) * (size_t)(HD * SROW);
  int d = wv * 16 + cl;
#pragma unroll
  for (int mf = 0; mf < 18; ++mf) {
    short4 o4 = make_short4(f2bs(acc[mf][0]), f2bs(acc[mf][1]),
                            f2bs(acc[mf][2]), f2bs(acc[mf][3]));
    *(short4*)&Sct[sbase + (size_t)d * SROW + mf * 16 + rq * 4] = o4;
  }
  // zero pad columns [288, 320)
  {
    int dz = tid >> 2, off = NRFP + ((tid & 3) << 3);
    bf16x8 z = {0, 0, 0, 0, 0, 0, 0, 0};
    *(bf16x8*)&Sct[sbase + (size_t)dz * SROW + off] = z;
  }
  size_t kbase = ((size_t)bh * NCH + c) * (size_t)NRF;
  if (tid < NRF) ksum[kbase + tid] = k1;
  if (tid < 10) ksum[kbase + 256 + tid] = k2;
}

// ---------------- fused exclusive prefixes over chunks ----------------
__global__ __launch_bounds__(256) void prefix_all(const short* __restrict__ Sct,
                                                  short* __restrict__ Spt,
                                                  const float* __restrict__ ksum,
                                                  short* __restrict__ ksb) {
  int bh = blockIdx.y;
  if (blockIdx.x == 80) {
    for (int m = threadIdx.x; m < NRFP; m += 256) {
      if (m < NRF) {
        size_t base = (size_t)bh * NCH * NRF + m;
        float a = 0.f;
#pragma unroll
        for (int c = 0; c < NCH; ++c) {
          float v = ksum[base + (size_t)c * NRF];
          ksb[((size_t)bh * NCH + c) * NRFP + m] = f2bs(a);
          a += v;
        }
      } else {
#pragma unroll
        for (int c = 0; c < NCH; ++c)
          ksb[((size_t)bh * NCH + c) * NRFP + m] = 0;
      }
    }
    return;
  }
  int e = blockIdx.x * 256 + threadIdx.x;  // over 64*SROW = 20480 (80 blocks exact)
  float a = 0.f;
#pragma unroll
  for (int c = 0; c < NCH; ++c) {
    size_t idx = ((size_t)bh * NCH + c) * (size_t)(HD * SROW) + e;
    float v = bs2f(Sct[idx]);
    Spt[idx] = f2bs(a);
    a += v;
  }
}

// ---------------- FUSED inter+intra: LDS-staged K (dbuf, counted vmcnt) ----------------
// grid (NCH, NBH), 4 waves; wave owns 32 chunk rows. K' staged 128x32/step via DMA.
__global__ __launch_bounds__(256) void attn_mfma(
    const short* __restrict__ Qp, const short* __restrict__ Kp,
    const short* __restrict__ Vb, const short* __restrict__ Spt,
    const short* __restrict__ ksb, short* __restrict__ ctxb) {
  constexpr int PST = 136;
  __shared__ short Vt[64 * PST];      // V^T [d][j]            17408 B
  __shared__ short SP[64 * SROW];     // Sp^T (swizzled) -> later P region  40960 B
  __shared__ short Kb2[2][128 * 32];  // K' slice dbuf         16384 B
  int c = blockIdx.x, bh = blockIdx.y;
  int b = bh >> 4, h = bh & 15;
  int tid = threadIdx.x, lane = tid & 63, wid = tid >> 6;
  int cl = lane & 15, rq = lane >> 4;
  size_t rowb = (size_t)bh * SEQ + (size_t)c * CHK;

  // stage V^T (register path; loads retired before loop via compiler waits)
  {
    int jj = tid >> 3, d0 = (tid & 7) << 3;
#pragma unroll
    for (int jt = 0; jt < 4; ++jt) {
      int j = jj + jt * 32;
      bf16x8 v = *(const bf16x8*)(Vb + ((size_t)b * SEQ + (size_t)c * CHK + j) * DMODEL +
                                  h * HD + d0);
#pragma unroll
      for (int e = 0; e < 8; ++e) Vt[(d0 + e) * PST + j] = v[e];
    }
  }
  // issue Sp^T staging (10 gload_lds, XOR-swizzled source; involution closed in SROW=320)
  const short* sg = Spt + ((size_t)bh * NCH + c) * (size_t)(HD * SROW);
#pragma unroll
  for (int i = 0; i < 10; ++i) {
    int o = tid * 8 + i * 2048;
    int d = o / SROW;
    int m = o - d * SROW;
    int ms = m ^ ((d & 7) << 3);
    gload_lds16(sg + (size_t)d * SROW + ms, &SP[wid * 512 + i * 2048]);
  }
  // K' slice staging: 128 rows x 32 cols, linear LDS dest, 2-bit XOR on source cols
  const short* Kbase = Kp + rowb * NRFP;
  auto stageK = [&](int buf, int k0) {
#pragma unroll
    for (int i = 0; i < 2; ++i) {
      int chunk = tid + i * 256;       // 0..511
      int row = chunk >> 2, cc = chunk & 3;
      int col = k0 + ((cc ^ (row & 3)) << 3);
      gload_lds16(Kbase + (size_t)row * NRFP + col,
                  &Kb2[buf][(wid * 64 + i * 256) * 8]);
    }
  };
  stageK(0, 0);

  int i0 = wid * 32;
  const short* Arow = Qp + (rowb + i0) * NRFP;
  const short* krow = ksb + ((size_t)bh * NCH + c) * NRFP;
  f32x4 accI[2][4];  // inter numerator
  f32x4 accD[2];     // inter denominator (col-0 trick; valid on cl==0 lanes)
  f32x4 accP[2][8];  // P = Q'K'^T
#pragma unroll
  for (int m = 0; m < 2; ++m) {
#pragma unroll
    for (int n = 0; n < 4; ++n) accI[m][n] = f32x4{0.f, 0.f, 0.f, 0.f};
    accD[m] = f32x4{0.f, 0.f, 0.f, 0.f};
#pragma unroll
    for (int n = 0; n < 8; ++n) accP[m][n] = f32x4{0.f, 0.f, 0.f, 0.f};
  }
  for (int k9 = 0; k9 < 9; ++k9) {
    int cur = k9 & 1;
    if (k9 < 8) {
      stageK(cur ^ 1, (k9 + 1) * 32);
      asm volatile("s_waitcnt vmcnt(2)" ::: "memory");  // SP + K[k9] done; K[k9+1] in flight
    } else {
      asm volatile("s_waitcnt vmcnt(0)" ::: "memory");
    }
    __builtin_amdgcn_s_barrier();
    asm volatile("" ::: "memory");
    int kb = k9 * 32 + (rq << 3);
    bf16x8 af[2];
#pragma unroll
    for (int mf = 0; mf < 2; ++mf)
      af[mf] = *(const bf16x8*)(Arow + (size_t)(mf * 16 + cl) * NRFP + kb);
    bf16x8 bvD = {0, 0, 0, 0, 0, 0, 0, 0};
    if (cl == 0) bvD = *(const bf16x8*)(krow + kb);
#pragma unroll
    for (int mf = 0; mf < 2; ++mf)
      accD[mf] = __builtin_amdgcn_mfma_f32_16x16x32_bf16(af[mf], bvD, accD[mf], 0, 0, 0);
#pragma unroll
    for (int nf = 0; nf < 4; ++nf) {
      int row = nf * 16 + cl;
      bf16x8 bv = *(const bf16x8*)&SP[row * SROW + (kb ^ ((cl & 7) << 3))];
#pragma unroll
      for (int mf = 0; mf < 2; ++mf)
        accI[mf][nf] = __builtin_amdgcn_mfma_f32_16x16x32_bf16(af[mf], bv,
                                                               accI[mf][nf], 0, 0, 0);
    }
    const short* kcur = &Kb2[cur][0];
#pragma unroll
    for (int nf = 0; nf < 8; ++nf) {
      int row = nf * 16 + cl;
      bf16x8 bv = *(const bf16x8*)&kcur[row * 32 + ((rq ^ (cl & 3)) << 3)];
#pragma unroll
      for (int mf = 0; mf < 2; ++mf)
        accP[mf][nf] = __builtin_amdgcn_mfma_f32_16x16x32_bf16(af[mf], bv,
                                                               accP[mf][nf], 0, 0, 0);
    }
    __builtin_amdgcn_s_barrier();  // frees Kb2[cur] for restage; last iter guards SP->P
    asm volatile("" ::: "memory");
  }

  // mask, rowsum, den (registers); write P into SP region
  float dtot[2][4];
#pragma unroll
  for (int mf = 0; mf < 2; ++mf)
#pragma unroll
    for (int r = 0; r < 4; ++r) {
      int rl = mf * 16 + (rq << 2) + r;
      int row = i0 + rl;
      float dsum = 0.f;
#pragma unroll
      for (int nf = 0; nf < 8; ++nf) {
        int col = nf * 16 + cl;
        float v = (col > row) ? 0.f : accP[mf][nf][r];
        dsum += v;
        SP[wid * 32 * PST + rl * PST + col] = f2bs(v);
      }
      dsum += __shfl_xor(dsum, 1);
      dsum += __shfl_xor(dsum, 2);
      dsum += __shfl_xor(dsum, 4);
      dsum += __shfl_xor(dsum, 8);
      float dden = __shfl(accD[mf][r], lane & 48);  // broadcast from cl==0 of same rq
      dtot[mf][r] = dden + dsum;
    }
  __syncthreads();  // P tiles complete

  // PV phase
  f32x4 pacc[2][4];
#pragma unroll
  for (int m = 0; m < 2; ++m)
#pragma unroll
    for (int n = 0; n < 4; ++n) pacc[m][n] = f32x4{0.f, 0.f, 0.f, 0.f};
#pragma unroll
  for (int kk = 0; kk < 4; ++kk) {
    int kb = kk * 32 + (rq << 3);
    bf16x8 paf[2];
#pragma unroll
    for (int mf = 0; mf < 2; ++mf)
      paf[mf] = *(const bf16x8*)&SP[wid * 32 * PST + (mf * 16 + cl) * PST + kb];
#pragma unroll
    for (int nf = 0; nf < 4; ++nf) {
      bf16x8 bv = *(const bf16x8*)&Vt[(nf * 16 + cl) * PST + kb];
#pragma unroll
      for (int mf = 0; mf < 2; ++mf)
        pacc[mf][nf] = __builtin_amdgcn_mfma_f32_16x16x32_bf16(paf[mf], bv,
                                                               pacc[mf][nf], 0, 0, 0);
    }
  }
  // finalize: (accI + pacc) / dtot
#pragma unroll
  for (int mf = 0; mf < 2; ++mf)
#pragma unroll
    for (int r = 0; r < 4; ++r) {
      int row = i0 + mf * 16 + (rq << 2) + r;
      float inv = 1.0f / dtot[mf][r];
      size_t ob = ((size_t)b * SEQ + (size_t)c * CHK + row) * DMODEL + h * HD;
#pragma unroll
      for (int nf = 0; nf < 4; ++nf) {
        int d = nf * 16 + cl;
        float v = (accI[mf][nf][r] + pacc[mf][nf][r]) * inv;
        ctxb[ob + d] = f2bs(v);
      }
    }
}

// ---------------- launch ----------------
extern "C" void kernel_launch(void* const* d_in, const int* in_sizes, int n_in,
                              void* d_out, int out_size, void* d_ws, size_t ws_size,
                              hipStream_t stream) {
  (void)in_sizes; (void)n_in; (void)out_size;
  const float* query = (const float*)d_in[0];
  const float* key_  = (const float*)d_in[1];
  const float* value = (const float*)d_in[2];
  const float* Wq = (const float*)d_in[3];
  const float* bq = (const float*)d_in[4];
  const float* Wk = (const float*)d_in[5];
  const float* bk = (const float*)d_in[6];
  const float* Wv = (const float*)d_in[7];
  const float* bv = (const float*)d_in[8];
  const float* Wo = (const float*)d_in[9];
  const float* bo = (const float*)d_in[10];
  const float* rf = (const float*)d_in[11];

  constexpr size_t SZ_INBF = (size_t)NROWS * DMODEL * 2;
  constexpr size_t SZ_QP   = (size_t)NBH * SEQ * NRFP * 2;
  constexpr size_t SZ_WT   = (size_t)DMODEL * DMODEL * 2;
  constexpr size_t SZ_SCH  = (size_t)NBH * NCH * HD * SROW * 2;
  constexpr size_t SZ_KS   = (size_t)NBH * NCH * NRF * 4;
  constexpr size_t SZ_KSB  = (size_t)NBH * NCH * NRFP * 2;
  constexpr size_t SZ_HK   = (size_t)NBH * SEQ * 4;
  constexpr size_t SZ_RFB  = (size_t)NRFP * HD * 2;

  constexpr size_t O_QP   = 0;
  constexpr size_t O_KP   = O_QP + SZ_QP;
  constexpr size_t O_WT   = O_KP + SZ_QP;
  constexpr size_t O_QPR  = O_WT + 4 * SZ_WT;
  constexpr size_t O_SCH  = O_QPR + 3 * SZ_INBF;
  constexpr size_t O_SPR  = O_SCH + SZ_SCH;
  constexpr size_t O_KSUM = O_SPR + SZ_SCH;
  constexpr size_t O_KSB  = O_KSUM + SZ_KS;
  constexpr size_t O_HK   = O_KSB + SZ_KSB;
  constexpr size_t O_KST  = O_HK + SZ_HK;
  constexpr size_t O_CTXB = O_KST + 256;
  constexpr size_t O_RFB  = O_CTXB + SZ_INBF;
  constexpr size_t O_END  = O_RFB + SZ_RFB;
  if (ws_size < O_END) return;

  char* w = (char*)d_ws;
  short* Qbf  = (short*)(w + O_QP);
  short* Qp   = (short*)(w + O_QP);
  short* Kp   = (short*)(w + O_KP);
  short* WtB  = (short*)(w + O_WT);
  short* QprB = (short*)(w + O_QPR);
  short* Kpr  = (short*)(w + O_QPR + SZ_INBF);
  short* Vpr  = (short*)(w + O_QPR + 2 * SZ_INBF);
  short* Sct  = (short*)(w + O_SCH);
  short* Spt  = (short*)(w + O_SPR);
  float* ksum = (float*)(w + O_KSUM);
  short* ksb  = (short*)(w + O_KSB);
  float* hkbuf = (float*)(w + O_HK);
  unsigned* kord = (unsigned*)(w + O_KST);
  short* ctxb = (short*)(w + O_CTXB);
  short* rfb  = (short*)(w + O_RFB);

  constexpr int NEL = NROWS * DMODEL;
  cvt3_kernel<<<dim3(NEL / 2048, 3), 256, 0, stream>>>(query, key_, value, Qbf);
  transpose4_bf16<<<dim3(32, 32, 4), 256, 0, stream>>>(Wq, Wk, Wv, Wo, WtB);
  rf_pad_bf16<<<(NRFP * HD) / 256, 256, 0, stream>>>(rf, rfb, kord);
  gemm_qkv3<<<dim3(8, 32, 3), 256, 0, stream>>>(Qbf, WtB, bq, bk, bv, QprB);
  hk_kernel<<<256, 256, 0, stream>>>(Kpr, hkbuf, kord);
  featmap_mfma<<<dim3(SEQ / 128, NBH, 2), 256, 0, stream>>>(QprB, Kpr, rfb, hkbuf,
                                                            kord, Qp, Kp);
  chunksum_mfma<<<dim3(NCH, NBH), 256, 0, stream>>>(Kp, Vpr, Sct, ksum);
  prefix_all<<<dim3(81, NBH), 256, 0, stream>>>(Sct, Spt, ksum, ksb);
  attn_mfma<<<dim3(NCH, NBH), 256, 0, stream>>>(Qp, Kp, Vpr, Spt, ksb, ctxb);
  gemm_out<<<dim3(16, 32), 256, 0, stream>>>(ctxb, WtB + 3 * (size_t)DMODEL * DMODEL,
                                             bo, (float*)d_out);
}

// Round 17
// 164.349 us; speedup vs baseline: 1.1622x; 1.0422x over previous
//
#include <hip/hip_runtime.h>
#include <hip/hip_bf16.h>

#define BATCH 2
#define SEQ 2048
#define DMODEL 1024
#define NH 16
#define HD 64
#define NRF 266
#define NRFP 288   // padded feature dim (multiple of 32), cols [266,288) are zero
#define SROW 320   // transposed-S row stride
#define CHK 128
#define NCH 16
#define NBH 32
#define NROWS 4096  // BATCH*SEQ

constexpr float SCAL = 0.17677669529663687f;   // DMODEL^-0.25
constexpr float SCAL2 = 0.03125f;              // SCAL^2 = DMODEL^-0.5
constexpr float LN_CNORM = -2.7917480361965505f;   // ln(1/sqrt(266))
constexpr float CKEPS = 6.131393094576169e-6f;     // CNORM*KEPS

typedef short bf16x8 __attribute__((ext_vector_type(8)));
typedef float f32x4 __attribute__((ext_vector_type(4)));

__device__ __forceinline__ short f2bs(float v) {
  __hip_bfloat16 h = __float2bfloat16(v);
  return *reinterpret_cast<short*>(&h);
}
__device__ __forceinline__ float bs2f(short s) {
  __hip_bfloat16 h;
  *reinterpret_cast<short*>(&h) = s;
  return __bfloat162float(h);
}
__device__ __forceinline__ void gload_lds16(const void* g, void* l) {
  __builtin_amdgcn_global_load_lds(
      (const __attribute__((address_space(1))) void*)g,
      (__attribute__((address_space(3))) void*)l, 16, 0, 0);
}

// ---------------- fused f32 -> bf16 convert for q,k,v ----------------
__global__ __launch_bounds__(256) void cvt3_kernel(const float* __restrict__ q,
                                                   const float* __restrict__ k,
                                                   const float* __restrict__ v,
                                                   short* __restrict__ out) {
  int z = blockIdx.y;
  const float* x = (z == 0) ? q : (z == 1) ? k : v;
  short* y = out + (size_t)z * NROWS * DMODEL;
  int i = (blockIdx.x * 256 + threadIdx.x) * 8;
  float4 a = *(const float4*)&x[i];
  float4 b = *(const float4*)&x[i + 4];
  bf16x8 o;
  o[0] = f2bs(a.x); o[1] = f2bs(a.y); o[2] = f2bs(a.z); o[3] = f2bs(a.w);
  o[4] = f2bs(b.x); o[5] = f2bs(b.y); o[6] = f2bs(b.z); o[7] = f2bs(b.w);
  *(bf16x8*)&y[i] = o;
}

// ---------------- fused: 4 weight transposes (z<4) + rf pad/scale (z==4) ----------------
__global__ __launch_bounds__(256) void transpose5_bf16(
    const float* __restrict__ Wq, const float* __restrict__ Wk,
    const float* __restrict__ Wv, const float* __restrict__ Wo,
    const float* __restrict__ rf, short* __restrict__ WtBase,
    short* __restrict__ rfb) {
  int z = blockIdx.z;
  if (z == 4) {
    int idx = (blockIdx.y * 32 + blockIdx.x) * 256 + threadIdx.x;
    if (idx < NRFP * HD)
      rfb[idx] = (idx < NRF * HD) ? f2bs(rf[idx] * SCAL) : (short)0;
    return;
  }
  __shared__ float t[32][33];
  const float* W = (z == 0) ? Wq : (z == 1) ? Wk : (z == 2) ? Wv : Wo;
  short* Wt = WtBase + (size_t)z * DMODEL * DMODEL;
  int k0 = blockIdx.y << 5, n0 = blockIdx.x << 5;
  int tx = threadIdx.x & 31, ty = threadIdx.x >> 5;
#pragma unroll
  for (int rr = 0; rr < 4; ++rr) {
    int r = ty + (rr << 3);
    t[r][tx] = W[(size_t)(k0 + r) * DMODEL + n0 + tx];
  }
  __syncthreads();
#pragma unroll
  for (int rr = 0; rr < 4; ++rr) {
    int r = ty + (rr << 3);
    Wt[(size_t)(n0 + r) * DMODEL + k0 + tx] = f2bs(t[tx][r]);
  }
}

// ---------------- MFMA GEMM core 128x128, BK=64, dbuf + counted vmcnt ----------------
template <bool OUTBF>
__device__ __forceinline__ void gemm_core128(const short* __restrict__ A,
                                             const short* __restrict__ Bt,
                                             const float* __restrict__ bias,
                                             void* __restrict__ C, int bm, int bn) {
  __shared__ short As[2][128 * 64];
  __shared__ short Bs[2][128 * 64];
  int tid = threadIdx.x;
  int lane = tid & 63, wid = tid >> 6;
  int wr = wid >> 1, wc = wid & 1;
  int cl = lane & 15, rq = lane >> 4;
  f32x4 acc[4][4];
#pragma unroll
  for (int m = 0; m < 4; ++m)
#pragma unroll
    for (int n = 0; n < 4; ++n) acc[m][n] = f32x4{0.f, 0.f, 0.f, 0.f};

  // hoisted staging offsets (per-thread constants)
  size_t abase[4], bbase[4];
#pragma unroll
  for (int i = 0; i < 4; ++i) {
    int e = tid * 8 + i * 2048;
    int row = e >> 6;
    int k = (e & 63) ^ ((row & 7) << 3);
    abase[i] = (size_t)(bm + row) * DMODEL + k;
    bbase[i] = (size_t)(bn + row) * DMODEL + k;
  }
  auto stage = [&](int buf, int k0) {
#pragma unroll
    for (int i = 0; i < 4; ++i)
      gload_lds16(A + abase[i] + k0, &As[buf][wid * 512 + i * 2048]);
#pragma unroll
    for (int i = 0; i < 4; ++i)
      gload_lds16(Bt + bbase[i] + k0, &Bs[buf][wid * 512 + i * 2048]);
  };

  stage(0, 0);
#pragma unroll 2
  for (int t = 0; t < 16; ++t) {
    int cur = t & 1;
    if (t < 15) {
      stage(cur ^ 1, (t + 1) * 64);
      asm volatile("s_waitcnt vmcnt(8)" ::: "memory");
    } else {
      asm volatile("s_waitcnt vmcnt(0)" ::: "memory");
    }
    __builtin_amdgcn_s_barrier();
    asm volatile("" ::: "memory");
    const short* curA = &As[cur][0];
    const short* curB = &Bs[cur][0];
#pragma unroll
    for (int ks = 0; ks < 2; ++ks) {
      int kb = ks * 32 + (rq << 3);
      bf16x8 af[4], bfv[4];
#pragma unroll
      for (int mf = 0; mf < 4; ++mf) {
        int row = wr * 64 + mf * 16 + cl;
        af[mf] = *(const bf16x8*)&curA[row * 64 + (kb ^ ((row & 7) << 3))];
      }
#pragma unroll
      for (int nf = 0; nf < 4; ++nf) {
        int row = wc * 64 + nf * 16 + cl;
        bfv[nf] = *(const bf16x8*)&curB[row * 64 + (kb ^ ((row & 7) << 3))];
      }
#pragma unroll
      for (int mf = 0; mf < 4; ++mf)
#pragma unroll
        for (int nf = 0; nf < 4; ++nf)
          acc[mf][nf] = __builtin_amdgcn_mfma_f32_16x16x32_bf16(af[mf], bfv[nf],
                                                                acc[mf][nf], 0, 0, 0);
    }
    __builtin_amdgcn_s_barrier();
    asm volatile("" ::: "memory");
  }
  int rbase = bm + wr * 64 + (rq << 2);
  int cbase = bn + wc * 64 + cl;
#pragma unroll
  for (int nf = 0; nf < 4; ++nf) {
    int col = cbase + nf * 16;
    float bv = bias[col];
#pragma unroll
    for (int mf = 0; mf < 4; ++mf)
#pragma unroll
      for (int r = 0; r < 4; ++r) {
        int row = rbase + mf * 16 + r;
        float v = acc[mf][nf][r] + bv;
        if (OUTBF)
          ((short*)C)[(size_t)row * DMODEL + col] = f2bs(v);
        else
          ((float*)C)[(size_t)row * DMODEL + col] = v;
      }
  }
}

// ---------------- MFMA GEMM core 128x64, BK=64, dbuf + counted vmcnt ----------------
template <bool OUTBF>
__device__ __forceinline__ void gemm_core64(const short* __restrict__ A,
                                            const short* __restrict__ Bt,
                                            const float* __restrict__ bias,
                                            void* __restrict__ C, int bm, int bn) {
  __shared__ short As[2][128 * 64];
  __shared__ short Bs[2][64 * 64];
  int tid = threadIdx.x;
  int lane = tid & 63, wid = tid >> 6;
  int wr = wid >> 1, wc = wid & 1;
  f32x4 acc[4][2];
#pragma unroll
  for (int m = 0; m < 4; ++m)
#pragma unroll
    for (int n = 0; n < 2; ++n) acc[m][n] = f32x4{0.f, 0.f, 0.f, 0.f};

  size_t abase[4], bbase[2];
#pragma unroll
  for (int i = 0; i < 4; ++i) {
    int e = tid * 8 + i * 2048;
    int row = e >> 6;
    int k = (e & 63) ^ ((row & 7) << 3);
    abase[i] = (size_t)(bm + row) * DMODEL + k;
    if (i < 2) bbase[i] = (size_t)(bn + row) * DMODEL + k;
  }
  auto stage = [&](int buf, int k0) {
#pragma unroll
    for (int i = 0; i < 4; ++i)
      gload_lds16(A + abase[i] + k0, &As[buf][wid * 512 + i * 2048]);
#pragma unroll
    for (int i = 0; i < 2; ++i)
      gload_lds16(Bt + bbase[i] + k0, &Bs[buf][wid * 512 + i * 2048]);
  };

  stage(0, 0);
#pragma unroll 2
  for (int t = 0; t < 16; ++t) {
    int cur = t & 1;
    if (t < 15) {
      stage(cur ^ 1, (t + 1) * 64);
      asm volatile("s_waitcnt vmcnt(6)" ::: "memory");
    } else {
      asm volatile("s_waitcnt vmcnt(0)" ::: "memory");
    }
    __builtin_amdgcn_s_barrier();
    asm volatile("" ::: "memory");
    const short* curA = &As[cur][0];
    const short* curB = &Bs[cur][0];
#pragma unroll
    for (int ks = 0; ks < 2; ++ks) {
      int kb = ks * 32 + ((lane >> 4) << 3);
      bf16x8 af[4], bfv[2];
#pragma unroll
      for (int mf = 0; mf < 4; ++mf) {
        int row = wr * 64 + mf * 16 + (lane & 15);
        af[mf] = *(const bf16x8*)&curA[row * 64 + (kb ^ ((row & 7) << 3))];
      }
#pragma unroll
      for (int nf = 0; nf < 2; ++nf) {
        int row = wc * 32 + nf * 16 + (lane & 15);
        bfv[nf] = *(const bf16x8*)&curB[row * 64 + (kb ^ ((row & 7) << 3))];
      }
#pragma unroll
      for (int mf = 0; mf < 4; ++mf)
#pragma unroll
        for (int nf = 0; nf < 2; ++nf)
          acc[mf][nf] = __builtin_amdgcn_mfma_f32_16x16x32_bf16(af[mf], bfv[nf],
                                                                acc[mf][nf], 0, 0, 0);
    }
    __builtin_amdgcn_s_barrier();
    asm volatile("" ::: "memory");
  }
  int rbase = bm + wr * 64 + ((lane >> 4) << 2);
  int cbase = bn + wc * 32 + (lane & 15);
#pragma unroll
  for (int nf = 0; nf < 2; ++nf) {
    int col = cbase + nf * 16;
    float bv = bias[col];
#pragma unroll
    for (int mf = 0; mf < 4; ++mf)
#pragma unroll
      for (int r = 0; r < 4; ++r) {
        int row = rbase + mf * 16 + r;
        float v = acc[mf][nf][r] + bv;
        if (OUTBF)
          ((short*)C)[(size_t)row * DMODEL + col] = f2bs(v);
        else
          ((float*)C)[(size_t)row * DMODEL + col] = v;
      }
  }
}

// fused QKV projection: grid (8, 32, 3), 128x128 tile, XCD-swizzled
__global__ __launch_bounds__(256) void gemm_qkv3(
    const short* __restrict__ Abase, const short* __restrict__ WtBase,
    const float* __restrict__ bq, const float* __restrict__ bk,
    const float* __restrict__ bv, short* __restrict__ OutBase) {
  int z = blockIdx.z;
  const short* A = Abase + (size_t)z * NROWS * DMODEL;
  const short* Bt = WtBase + (size_t)z * DMODEL * DMODEL;
  const float* bias = (z == 0) ? bq : (z == 1) ? bk : bv;
  short* C = OutBase + (size_t)z * NROWS * DMODEL;
  int bid = blockIdx.x + (blockIdx.y << 3);
  int swz = ((bid & 7) << 5) + (bid >> 3);
  int bn = (swz & 7) << 7;
  int bm = (swz >> 3) << 7;
  gemm_core128<true>(A, Bt, bias, C, bm, bn);
}

// output projection: grid (16, 32), 128x64 tile, XCD-swizzled
__global__ __launch_bounds__(256) void gemm_out(const short* __restrict__ A,
                                                const short* __restrict__ Bt,
                                                const float* __restrict__ bias,
                                                float* __restrict__ C) {
  int bid = blockIdx.x + (blockIdx.y << 4);  // nwg=512
  int swz = ((bid & 7) << 6) + (bid >> 3);
  int bn = (swz & 15) << 6;
  int bm = (swz >> 4) << 7;
  gemm_core64<false>(A, Bt, bias, C, bm, bn);
}

// ---------------- feature map via MFMA (fast-exp epilogue; hk computed inline) ----------------
// kstab dropped: k' scales by e^{kstab} in BOTH numerator and denominator of the
// final ratio, so only the eps regularizer shifts (<=0.1% of denominator).
__global__ __launch_bounds__(256, 1) void featmap_mfma(
    const short* __restrict__ Qproj, const short* __restrict__ Kproj,
    const short* __restrict__ rfb, short* __restrict__ Qp, short* __restrict__ Kp) {
  __shared__ short smem[26624];  // A:8192 | B:18432 ; epilogue reuses as P[128][152]
  __shared__ float hks[128];
  short* As = smem;
  short* Bs = smem + 8192;
  int isK = blockIdx.z;
  const short* X = isK ? Kproj : Qproj;
  short* O = isK ? Kp : Qp;
  int bh = blockIdx.y, b = bh >> 4, h = bh & 15;
  int l0 = blockIdx.x << 7;
  int tid = threadIdx.x, lane = tid & 63, wid = tid >> 6;
  int cl = lane & 15, rq = lane >> 4;

#pragma unroll
  for (int i = 0; i < 4; ++i) {
    int e = tid * 8 + i * 2048;
    int row = e >> 6;
    int k = (e & 63) ^ ((row & 7) << 3);
    gload_lds16(X + ((size_t)b * SEQ + l0 + row) * DMODEL + h * HD + k,
                &As[wid * 512 + i * 2048]);
  }
#pragma unroll
  for (int i = 0; i < 9; ++i) {
    int e = tid * 8 + i * 2048;
    int row = e >> 6;
    int k = (e & 63) ^ ((row & 7) << 3);
    gload_lds16(rfb + row * HD + k, &Bs[wid * 512 + i * 2048]);
  }
  __syncthreads();

  int i0 = wid * 32;
  f32x4 acc[2][18];
#pragma unroll
  for (int m = 0; m < 2; ++m)
#pragma unroll
    for (int n = 0; n < 18; ++n) acc[m][n] = f32x4{0.f, 0.f, 0.f, 0.f};
#pragma unroll
  for (int ks = 0; ks < 2; ++ks) {
    int kb = ks * 32 + (rq << 3);
    int swz = (cl & 7) << 3;
    bf16x8 af[2];
#pragma unroll
    for (int mf = 0; mf < 2; ++mf) {
      int row = i0 + mf * 16 + cl;
      af[mf] = *(const bf16x8*)&As[row * 64 + (kb ^ swz)];
    }
#pragma unroll
    for (int nf = 0; nf < 18; ++nf) {
      int brow = nf * 16 + cl;
      bf16x8 bv = *(const bf16x8*)&Bs[brow * 64 + (kb ^ swz)];
#pragma unroll
      for (int mf = 0; mf < 2; ++mf)
        acc[mf][nf] = __builtin_amdgcn_mfma_f32_16x16x32_bf16(af[mf], bv,
                                                              acc[mf][nf], 0, 0, 0);
    }
  }

  // inline h_k from staged As (within-row XOR permutation doesn't affect sum of squares)
  if (isK) {
    int row = tid >> 1, half = tid & 1;
    const short* rp = &As[row * 64 + half * 32];
    float ss = 0.f;
#pragma unroll
    for (int g = 0; g < 4; ++g) {
      bf16x8 v = *(const bf16x8*)(rp + g * 8);
#pragma unroll
      for (int e = 0; e < 8; ++e) {
        float x = bs2f(v[e]);
        ss += x * x;
      }
    }
    ss += __shfl_xor(ss, 1);
    if (!half) hks[row] = -0.5f * SCAL2 * ss + LN_CNORM;
  }

  short* Ps = smem;  // [128][152]
#pragma unroll
  for (int hf = 0; hf < 2; ++hf) {
    __syncthreads();
#pragma unroll
    for (int mf = 0; mf < 2; ++mf)
#pragma unroll
      for (int r = 0; r < 4; ++r) {
        int rl = i0 + mf * 16 + (rq << 2) + r;
        float addk = isK ? hks[rl] : LN_CNORM;
#pragma unroll
        for (int nf2 = 0; nf2 < 9; ++nf2) {
          int m = hf * 144 + nf2 * 16 + cl;
          float v = acc[mf][hf * 9 + nf2][r] + addk;
          float o = (m < NRF) ? (__expf(v) + CKEPS) : 0.f;
          Ps[rl * 152 + nf2 * 16 + cl] = f2bs(o);
        }
      }
    __syncthreads();
#pragma unroll
    for (int it = 0; it < 9; ++it) {
      int idx = tid + it * 256;
      int row = idx / 18, ch = idx - row * 18;
      bf16x8 val = *(const bf16x8*)&Ps[row * 152 + ch * 8];
      *(bf16x8*)&O[((size_t)bh * SEQ + l0 + row) * NRFP + hf * 144 + ch * 8] = val;
    }
  }
}

// ---------------- per-chunk sums via MFMA -> Sct TRANSPOSED [bh][c][d][SROW] bf16 ----------------
__global__ __launch_bounds__(256) void chunksum_mfma(
    const short* __restrict__ Kp, const short* __restrict__ Vb,
    short* __restrict__ Sct, float* __restrict__ ksum) {
  constexpr int ST = 70;
  __shared__ short KT[NRFP * ST];  // [m][i_loc]
  __shared__ short VT[HD * ST];    // [d][i_loc]
  int c = blockIdx.x, bh = blockIdx.y;
  int b = bh >> 4, h = bh & 15;
  int tid = threadIdx.x, lane = tid & 63, wv = tid >> 6;
  int cl = lane & 15, rq = lane >> 4;
  int irow = tid >> 2;
  int mq = tid & 3;
  size_t rowb = (size_t)bh * SEQ + (size_t)c * CHK;

  f32x4 acc[18];
#pragma unroll
  for (int m = 0; m < 18; ++m) acc[m] = f32x4{0.f, 0.f, 0.f, 0.f};
  float k1 = 0.f, k2 = 0.f;

  for (int hf = 0; hf < 2; ++hf) {
    __syncthreads();
    const short* Krow = Kp + (rowb + hf * 64 + irow) * NRFP;
#pragma unroll
    for (int cg = 0; cg < 9; ++cg) {
      int m0 = cg * 32 + mq * 8;
      bf16x8 v = *(const bf16x8*)(Krow + m0);
#pragma unroll
      for (int e = 0; e < 8; ++e) KT[(m0 + e) * ST + irow] = v[e];
    }
    const short* Vrow =
        Vb + ((size_t)b * SEQ + (size_t)c * CHK + hf * 64 + irow) * DMODEL + h * HD;
    {
      int d0 = mq * 16;
      bf16x8 v0 = *(const bf16x8*)(Vrow + d0);
      bf16x8 v1 = *(const bf16x8*)(Vrow + d0 + 8);
#pragma unroll
      for (int e = 0; e < 8; ++e) VT[(d0 + e) * ST + irow] = v0[e];
#pragma unroll
      for (int e = 0; e < 8; ++e) VT[(d0 + 8 + e) * ST + irow] = v1[e];
    }
    __syncthreads();
#pragma unroll
    for (int ks = 0; ks < 2; ++ks) {
      int kb = ks * 32 + rq * 8;
      bf16x8 bv = *(const bf16x8*)&VT[(wv * 16 + cl) * ST + kb];
#pragma unroll
      for (int mf = 0; mf < 18; ++mf) {
        bf16x8 av = *(const bf16x8*)&KT[(mf * 16 + cl) * ST + kb];
        acc[mf] = __builtin_amdgcn_mfma_f32_16x16x32_bf16(av, bv, acc[mf], 0, 0, 0);
      }
    }
    {
      const short* r1 = &KT[tid * ST];
#pragma unroll
      for (int g = 0; g < 8; ++g) {
        bf16x8 v = *(const bf16x8*)(r1 + g * 8);
#pragma unroll
        for (int e = 0; e < 8; ++e) k1 += bs2f(v[e]);
      }
      if (tid < 10) {
        const short* r2 = &KT[(256 + tid) * ST];
#pragma unroll
        for (int g = 0; g < 8; ++g) {
          bf16x8 v = *(const bf16x8*)(r2 + g * 8);
#pragma unroll
          for (int e = 0; e < 8; ++e) k2 += bs2f(v[e]);
        }
      }
    }
  }
  // transposed store: Sct[(bh,c)][d][m]; stride SROW
  size_t sbase = ((size_t)bh * NCH + c) * (size_t)(HD * SROW);
  int d = wv * 16 + cl;
#pragma unroll
  for (int mf = 0; mf < 18; ++mf) {
    short4 o4 = make_short4(f2bs(acc[mf][0]), f2bs(acc[mf][1]),
                            f2bs(acc[mf][2]), f2bs(acc[mf][3]));
    *(short4*)&Sct[sbase + (size_t)d * SROW + mf * 16 + rq * 4] = o4;
  }
  // zero pad columns [288, 320)
  {
    int dz = tid >> 2, off = NRFP + ((tid & 3) << 3);
    bf16x8 z = {0, 0, 0, 0, 0, 0, 0, 0};
    *(bf16x8*)&Sct[sbase + (size_t)dz * SROW + off] = z;
  }
  size_t kbase = ((size_t)bh * NCH + c) * (size_t)NRF;
  if (tid < NRF) ksum[kbase + tid] = k1;
  if (tid < 10) ksum[kbase + 256 + tid] = k2;
}

// ---------------- fused exclusive prefixes over chunks ----------------
__global__ __launch_bounds__(256) void prefix_all(const short* __restrict__ Sct,
                                                  short* __restrict__ Spt,
                                                  const float* __restrict__ ksum,
                                                  short* __restrict__ ksb) {
  int bh = blockIdx.y;
  if (blockIdx.x == 80) {
    for (int m = threadIdx.x; m < NRFP; m += 256) {
      if (m < NRF) {
        size_t base = (size_t)bh * NCH * NRF + m;
        float a = 0.f;
#pragma unroll
        for (int c = 0; c < NCH; ++c) {
          float v = ksum[base + (size_t)c * NRF];
          ksb[((size_t)bh * NCH + c) * NRFP + m] = f2bs(a);
          a += v;
        }
      } else {
#pragma unroll
        for (int c = 0; c < NCH; ++c)
          ksb[((size_t)bh * NCH + c) * NRFP + m] = 0;
      }
    }
    return;
  }
  int e = blockIdx.x * 256 + threadIdx.x;  // over 64*SROW = 20480 (80 blocks exact)
  float a = 0.f;
#pragma unroll
  for (int c = 0; c < NCH; ++c) {
    size_t idx = ((size_t)bh * NCH + c) * (size_t)(HD * SROW) + e;
    float v = bs2f(Sct[idx]);
    Spt[idx] = f2bs(a);
    a += v;
  }
}

// ---------------- FUSED inter+intra: LDS-staged K (dbuf, counted vmcnt) ----------------
__global__ __launch_bounds__(256) void attn_mfma(
    const short* __restrict__ Qp, const short* __restrict__ Kp,
    const short* __restrict__ Vb, const short* __restrict__ Spt,
    const short* __restrict__ ksb, short* __restrict__ ctxb) {
  constexpr int PST = 136;
  __shared__ short Vt[64 * PST];      // V^T [d][j]
  __shared__ short SP[64 * SROW];     // Sp^T (swizzled) -> later P region
  __shared__ short Kb2[2][128 * 32];  // K' slice dbuf
  int c = blockIdx.x, bh = blockIdx.y;
  int b = bh >> 4, h = bh & 15;
  int tid = threadIdx.x, lane = tid & 63, wid = tid >> 6;
  int cl = lane & 15, rq = lane >> 4;
  size_t rowb = (size_t)bh * SEQ + (size_t)c * CHK;

  // stage V^T (register path)
  {
    int jj = tid >> 3, d0 = (tid & 7) << 3;
#pragma unroll
    for (int jt = 0; jt < 4; ++jt) {
      int j = jj + jt * 32;
      bf16x8 v = *(const bf16x8*)(Vb + ((size_t)b * SEQ + (size_t)c * CHK + j) * DMODEL +
                                  h * HD + d0);
#pragma unroll
      for (int e = 0; e < 8; ++e) Vt[(d0 + e) * PST + j] = v[e];
    }
  }
  // issue Sp^T staging (10 gload_lds, XOR-swizzled source; involution closed in SROW=320)
  const short* sg = Spt + ((size_t)bh * NCH + c) * (size_t)(HD * SROW);
#pragma unroll
  for (int i = 0; i < 10; ++i) {
    int o = tid * 8 + i * 2048;
    int d = o / SROW;
    int m = o - d * SROW;
    int ms = m ^ ((d & 7) << 3);
    gload_lds16(sg + (size_t)d * SROW + ms, &SP[wid * 512 + i * 2048]);
  }
  // K' slice staging: 128 rows x 32 cols, linear LDS dest, 2-bit XOR on source cols
  const short* Kbase = Kp + rowb * NRFP;
  auto stageK = [&](int buf, int k0) {
#pragma unroll
    for (int i = 0; i < 2; ++i) {
      int chunk = tid + i * 256;
      int row = chunk >> 2, cc = chunk & 3;
      int col = k0 + ((cc ^ (row & 3)) << 3);
      gload_lds16(Kbase + (size_t)row * NRFP + col,
                  &Kb2[buf][(wid * 64 + i * 256) * 8]);
    }
  };
  stageK(0, 0);

  int i0 = wid * 32;
  const short* Arow = Qp + (rowb + i0) * NRFP;
  const short* krow = ksb + ((size_t)bh * NCH + c) * NRFP;
  f32x4 accI[2][4];
  f32x4 accD[2];
  f32x4 accP[2][8];
#pragma unroll
  for (int m = 0; m < 2; ++m) {
#pragma unroll
    for (int n = 0; n < 4; ++n) accI[m][n] = f32x4{0.f, 0.f, 0.f, 0.f};
    accD[m] = f32x4{0.f, 0.f, 0.f, 0.f};
#pragma unroll
    for (int n = 0; n < 8; ++n) accP[m][n] = f32x4{0.f, 0.f, 0.f, 0.f};
  }
  for (int k9 = 0; k9 < 9; ++k9) {
    int cur = k9 & 1;
    if (k9 < 8) {
      stageK(cur ^ 1, (k9 + 1) * 32);
      asm volatile("s_waitcnt vmcnt(2)" ::: "memory");
    } else {
      asm volatile("s_waitcnt vmcnt(0)" ::: "memory");
    }
    __builtin_amdgcn_s_barrier();
    asm volatile("" ::: "memory");
    int kb = k9 * 32 + (rq << 3);
    bf16x8 af[2];
#pragma unroll
    for (int mf = 0; mf < 2; ++mf)
      af[mf] = *(const bf16x8*)(Arow + (size_t)(mf * 16 + cl) * NRFP + kb);
    bf16x8 bvD = {0, 0, 0, 0, 0, 0, 0, 0};
    if (cl == 0) bvD = *(const bf16x8*)(krow + kb);
#pragma unroll
    for (int mf = 0; mf < 2; ++mf)
      accD[mf] = __builtin_amdgcn_mfma_f32_16x16x32_bf16(af[mf], bvD, accD[mf], 0, 0, 0);
#pragma unroll
    for (int nf = 0; nf < 4; ++nf) {
      int row = nf * 16 + cl;
      bf16x8 bv = *(const bf16x8*)&SP[row * SROW + (kb ^ ((cl & 7) << 3))];
#pragma unroll
      for (int mf = 0; mf < 2; ++mf)
        accI[mf][nf] = __builtin_amdgcn_mfma_f32_16x16x32_bf16(af[mf], bv,
                                                               accI[mf][nf], 0, 0, 0);
    }
    const short* kcur = &Kb2[cur][0];
#pragma unroll
    for (int nf = 0; nf < 8; ++nf) {
      int row = nf * 16 + cl;
      bf16x8 bv = *(const bf16x8*)&kcur[row * 32 + ((rq ^ (cl & 3)) << 3)];
#pragma unroll
      for (int mf = 0; mf < 2; ++mf)
        accP[mf][nf] = __builtin_amdgcn_mfma_f32_16x16x32_bf16(af[mf], bv,
                                                               accP[mf][nf], 0, 0, 0);
    }
    __builtin_amdgcn_s_barrier();
    asm volatile("" ::: "memory");
  }

  // mask, rowsum, den (registers); write P into SP region
  float dtot[2][4];
#pragma unroll
  for (int mf = 0; mf < 2; ++mf)
#pragma unroll
    for (int r = 0; r < 4; ++r) {
      int rl = mf * 16 + (rq << 2) + r;
      int row = i0 + rl;
      float dsum = 0.f;
#pragma unroll
      for (int nf = 0; nf < 8; ++nf) {
        int col = nf * 16 + cl;
        float v = (col > row) ? 0.f : accP[mf][nf][r];
        dsum += v;
        SP[wid * 32 * PST + rl * PST + col] = f2bs(v);
      }
      dsum += __shfl_xor(dsum, 1);
      dsum += __shfl_xor(dsum, 2);
      dsum += __shfl_xor(dsum, 4);
      dsum += __shfl_xor(dsum, 8);
      float dden = __shfl(accD[mf][r], lane & 48);
      dtot[mf][r] = dden + dsum;
    }
  __syncthreads();

  // PV phase
  f32x4 pacc[2][4];
#pragma unroll
  for (int m = 0; m < 2; ++m)
#pragma unroll
    for (int n = 0; n < 4; ++n) pacc[m][n] = f32x4{0.f, 0.f, 0.f, 0.f};
#pragma unroll
  for (int kk = 0; kk < 4; ++kk) {
    int kb = kk * 32 + (rq << 3);
    bf16x8 paf[2];
#pragma unroll
    for (int mf = 0; mf < 2; ++mf)
      paf[mf] = *(const bf16x8*)&SP[wid * 32 * PST + (mf * 16 + cl) * PST + kb];
#pragma unroll
    for (int nf = 0; nf < 4; ++nf) {
      bf16x8 bv = *(const bf16x8*)&Vt[(nf * 16 + cl) * PST + kb];
#pragma unroll
      for (int mf = 0; mf < 2; ++mf)
        pacc[mf][nf] = __builtin_amdgcn_mfma_f32_16x16x32_bf16(paf[mf], bv,
                                                               pacc[mf][nf], 0, 0, 0);
    }
  }
  // finalize
#pragma unroll
  for (int mf = 0; mf < 2; ++mf)
#pragma unroll
    for (int r = 0; r < 4; ++r) {
      int row = i0 + mf * 16 + (rq << 2) + r;
      float inv = 1.0f / dtot[mf][r];
      size_t ob = ((size_t)b * SEQ + (size_t)c * CHK + row) * DMODEL + h * HD;
#pragma unroll
      for (int nf = 0; nf < 4; ++nf) {
        int d = nf * 16 + cl;
        float v = (accI[mf][nf][r] + pacc[mf][nf][r]) * inv;
        ctxb[ob + d] = f2bs(v);
      }
    }
}

// ---------------- launch ----------------
extern "C" void kernel_launch(void* const* d_in, const int* in_sizes, int n_in,
                              void* d_out, int out_size, void* d_ws, size_t ws_size,
                              hipStream_t stream) {
  (void)in_sizes; (void)n_in; (void)out_size;
  const float* query = (const float*)d_in[0];
  const float* key_  = (const float*)d_in[1];
  const float* value = (const float*)d_in[2];
  const float* Wq = (const float*)d_in[3];
  const float* bq = (const float*)d_in[4];
  const float* Wk = (const float*)d_in[5];
  const float* bk = (const float*)d_in[6];
  const float* Wv = (const float*)d_in[7];
  const float* bv = (const float*)d_in[8];
  const float* Wo = (const float*)d_in[9];
  const float* bo = (const float*)d_in[10];
  const float* rf = (const float*)d_in[11];

  constexpr size_t SZ_INBF = (size_t)NROWS * DMODEL * 2;
  constexpr size_t SZ_QP   = (size_t)NBH * SEQ * NRFP * 2;
  constexpr size_t SZ_WT   = (size_t)DMODEL * DMODEL * 2;
  constexpr size_t SZ_SCH  = (size_t)NBH * NCH * HD * SROW * 2;
  constexpr size_t SZ_KS   = (size_t)NBH * NCH * NRF * 4;
  constexpr size_t SZ_KSB  = (size_t)NBH * NCH * NRFP * 2;
  constexpr size_t SZ_RFB  = (size_t)NRFP * HD * 2;

  constexpr size_t O_QP   = 0;
  constexpr size_t O_KP   = O_QP + SZ_QP;
  constexpr size_t O_WT   = O_KP + SZ_QP;
  constexpr size_t O_QPR  = O_WT + 4 * SZ_WT;
  constexpr size_t O_SCH  = O_QPR + 3 * SZ_INBF;
  constexpr size_t O_SPR  = O_SCH + SZ_SCH;
  constexpr size_t O_KSUM = O_SPR + SZ_SCH;
  constexpr size_t O_KSB  = O_KSUM + SZ_KS;
  constexpr size_t O_CTXB = O_KSB + SZ_KSB;
  constexpr size_t O_RFB  = O_CTXB + SZ_INBF;
  constexpr size_t O_END  = O_RFB + SZ_RFB;
  if (ws_size < O_END) return;

  char* w = (char*)d_ws;
  short* Qbf  = (short*)(w + O_QP);
  short* Qp   = (short*)(w + O_QP);
  short* Kp   = (short*)(w + O_KP);
  short* WtB  = (short*)(w + O_WT);
  short* QprB = (short*)(w + O_QPR);
  short* Kpr  = (short*)(w + O_QPR + SZ_INBF);
  short* Vpr  = (short*)(w + O_QPR + 2 * SZ_INBF);
  short* Sct  = (short*)(w + O_SCH);
  short* Spt  = (short*)(w + O_SPR);
  float* ksum = (float*)(w + O_KSUM);
  short* ksb  = (short*)(w + O_KSB);
  short* ctxb = (short*)(w + O_CTXB);
  short* rfb  = (short*)(w + O_RFB);

  constexpr int NEL = NROWS * DMODEL;
  cvt3_kernel<<<dim3(NEL / 2048, 3), 256, 0, stream>>>(query, key_, value, Qbf);
  transpose5_bf16<<<dim3(32, 32, 5), 256, 0, stream>>>(Wq, Wk, Wv, Wo, rf, WtB, rfb);
  gemm_qkv3<<<dim3(8, 32, 3), 256, 0, stream>>>(Qbf, WtB, bq, bk, bv, QprB);
  featmap_mfma<<<dim3(SEQ / 128, NBH, 2), 256, 0, stream>>>(QprB, Kpr, rfb, Qp, Kp);
  chunksum_mfma<<<dim3(NCH, NBH), 256, 0, stream>>>(Kp, Vpr, Sct, ksum);
  prefix_all<<<dim3(81, NBH), 256, 0, stream>>>(Sct, Spt, ksum, ksb);
  attn_mfma<<<dim3(NCH, NBH), 256, 0, stream>>>(Qp, Kp, Vpr, Spt, ksb, ctxb);
  gemm_out<<<dim3(16, 32), 256, 0, stream>>>(ctxb, WtB + 3 * (size_t)DMODEL * DMODEL,
                                             bo, (float*)d_out);
}

// Round 18
// 160.822 us; speedup vs baseline: 1.1877x; 1.0219x over previous
//
#include <hip/hip_runtime.h>
#include <hip/hip_bf16.h>

#define BATCH 2
#define SEQ 2048
#define DMODEL 1024
#define NH 16
#define HD 64
#define NRF 266
#define NRFP 288   // padded feature dim (multiple of 32), cols [266,288) are zero
#define SROW 320   // transposed-S row stride
#define CHK 128
#define NCH 16
#define NBH 32
#define NROWS 4096  // BATCH*SEQ

constexpr float SCAL = 0.17677669529663687f;   // DMODEL^-0.25
constexpr float SCAL2 = 0.03125f;              // SCAL^2 = DMODEL^-0.5
constexpr float LN_CNORM = -2.7917480361965505f;   // ln(1/sqrt(266))
constexpr float CKEPS = 6.131393094576169e-6f;     // CNORM*KEPS

typedef short bf16x8 __attribute__((ext_vector_type(8)));
typedef float f32x4 __attribute__((ext_vector_type(4)));

__device__ __forceinline__ short f2bs(float v) {
  __hip_bfloat16 h = __float2bfloat16(v);
  return *reinterpret_cast<short*>(&h);
}
__device__ __forceinline__ float bs2f(short s) {
  __hip_bfloat16 h;
  *reinterpret_cast<short*>(&h) = s;
  return __bfloat162float(h);
}
__device__ __forceinline__ void gload_lds16(const void* g, void* l) {
  __builtin_amdgcn_global_load_lds(
      (const __attribute__((address_space(1))) void*)g,
      (__attribute__((address_space(3))) void*)l, 16, 0, 0);
}

// ---------------- fused f32 -> bf16 convert for q,k,v ----------------
__global__ __launch_bounds__(256) void cvt3_kernel(const float* __restrict__ q,
                                                   const float* __restrict__ k,
                                                   const float* __restrict__ v,
                                                   short* __restrict__ out) {
  int z = blockIdx.y;
  const float* x = (z == 0) ? q : (z == 1) ? k : v;
  short* y = out + (size_t)z * NROWS * DMODEL;
  int i = (blockIdx.x * 256 + threadIdx.x) * 8;
  float4 a = *(const float4*)&x[i];
  float4 b = *(const float4*)&x[i + 4];
  bf16x8 o;
  o[0] = f2bs(a.x); o[1] = f2bs(a.y); o[2] = f2bs(a.z); o[3] = f2bs(a.w);
  o[4] = f2bs(b.x); o[5] = f2bs(b.y); o[6] = f2bs(b.z); o[7] = f2bs(b.w);
  *(bf16x8*)&y[i] = o;
}

// ---------------- fused: 4 weight transposes (z<4) + rf pad/scale (z==4) ----------------
__global__ __launch_bounds__(256) void transpose5_bf16(
    const float* __restrict__ Wq, const float* __restrict__ Wk,
    const float* __restrict__ Wv, const float* __restrict__ Wo,
    const float* __restrict__ rf, short* __restrict__ WtBase,
    short* __restrict__ rfb) {
  int z = blockIdx.z;
  if (z == 4) {
    int idx = (blockIdx.y * 32 + blockIdx.x) * 256 + threadIdx.x;
    if (idx < NRFP * HD)
      rfb[idx] = (idx < NRF * HD) ? f2bs(rf[idx] * SCAL) : (short)0;
    return;
  }
  __shared__ float t[32][33];
  const float* W = (z == 0) ? Wq : (z == 1) ? Wk : (z == 2) ? Wv : Wo;
  short* Wt = WtBase + (size_t)z * DMODEL * DMODEL;
  int k0 = blockIdx.y << 5, n0 = blockIdx.x << 5;
  int tx = threadIdx.x & 31, ty = threadIdx.x >> 5;
#pragma unroll
  for (int rr = 0; rr < 4; ++rr) {
    int r = ty + (rr << 3);
    t[r][tx] = W[(size_t)(k0 + r) * DMODEL + n0 + tx];
  }
  __syncthreads();
#pragma unroll
  for (int rr = 0; rr < 4; ++rr) {
    int r = ty + (rr << 3);
    Wt[(size_t)(n0 + r) * DMODEL + k0 + tx] = f2bs(t[tx][r]);
  }
}

// ---------------- MFMA GEMM core 128x64, BK=64, dbuf + counted vmcnt ----------------
template <bool OUTBF>
__device__ __forceinline__ void gemm_core64(const short* __restrict__ A,
                                            const short* __restrict__ Bt,
                                            const float* __restrict__ bias,
                                            void* __restrict__ C, int bm, int bn) {
  __shared__ short As[2][128 * 64];
  __shared__ short Bs[2][64 * 64];
  int tid = threadIdx.x;
  int lane = tid & 63, wid = tid >> 6;
  int wr = wid >> 1, wc = wid & 1;
  f32x4 acc[4][2];
#pragma unroll
  for (int m = 0; m < 4; ++m)
#pragma unroll
    for (int n = 0; n < 2; ++n) acc[m][n] = f32x4{0.f, 0.f, 0.f, 0.f};

  size_t abase[4], bbase[2];
#pragma unroll
  for (int i = 0; i < 4; ++i) {
    int e = tid * 8 + i * 2048;
    int row = e >> 6;
    int k = (e & 63) ^ ((row & 7) << 3);
    abase[i] = (size_t)(bm + row) * DMODEL + k;
    if (i < 2) bbase[i] = (size_t)(bn + row) * DMODEL + k;
  }
  auto stage = [&](int buf, int k0) {
#pragma unroll
    for (int i = 0; i < 4; ++i)
      gload_lds16(A + abase[i] + k0, &As[buf][wid * 512 + i * 2048]);
#pragma unroll
    for (int i = 0; i < 2; ++i)
      gload_lds16(Bt + bbase[i] + k0, &Bs[buf][wid * 512 + i * 2048]);
  };

  stage(0, 0);
#pragma unroll 2
  for (int t = 0; t < 16; ++t) {
    int cur = t & 1;
    if (t < 15) {
      stage(cur ^ 1, (t + 1) * 64);
      asm volatile("s_waitcnt vmcnt(6)" ::: "memory");
    } else {
      asm volatile("s_waitcnt vmcnt(0)" ::: "memory");
    }
    __builtin_amdgcn_s_barrier();
    asm volatile("" ::: "memory");
    const short* curA = &As[cur][0];
    const short* curB = &Bs[cur][0];
#pragma unroll
    for (int ks = 0; ks < 2; ++ks) {
      int kb = ks * 32 + ((lane >> 4) << 3);
      bf16x8 af[4], bfv[2];
#pragma unroll
      for (int mf = 0; mf < 4; ++mf) {
        int row = wr * 64 + mf * 16 + (lane & 15);
        af[mf] = *(const bf16x8*)&curA[row * 64 + (kb ^ ((row & 7) << 3))];
      }
#pragma unroll
      for (int nf = 0; nf < 2; ++nf) {
        int row = wc * 32 + nf * 16 + (lane & 15);
        bfv[nf] = *(const bf16x8*)&curB[row * 64 + (kb ^ ((row & 7) << 3))];
      }
#pragma unroll
      for (int mf = 0; mf < 4; ++mf)
#pragma unroll
        for (int nf = 0; nf < 2; ++nf)
          acc[mf][nf] = __builtin_amdgcn_mfma_f32_16x16x32_bf16(af[mf], bfv[nf],
                                                                acc[mf][nf], 0, 0, 0);
    }
    __builtin_amdgcn_s_barrier();
    asm volatile("" ::: "memory");
  }
  int rbase = bm + wr * 64 + ((lane >> 4) << 2);
  int cbase = bn + wc * 32 + (lane & 15);
#pragma unroll
  for (int nf = 0; nf < 2; ++nf) {
    int col = cbase + nf * 16;
    float bv = bias[col];
#pragma unroll
    for (int mf = 0; mf < 4; ++mf)
#pragma unroll
      for (int r = 0; r < 4; ++r) {
        int row = rbase + mf * 16 + r;
        float v = acc[mf][nf][r] + bv;
        if (OUTBF)
          ((short*)C)[(size_t)row * DMODEL + col] = f2bs(v);
        else
          ((float*)C)[(size_t)row * DMODEL + col] = v;
      }
  }
}

// fused QKV projection: grid (16, 32, 3), 128x64 tile, XCD-swizzled (nwg=512 per z)
__global__ __launch_bounds__(256) void gemm_qkv3(
    const short* __restrict__ Abase, const short* __restrict__ WtBase,
    const float* __restrict__ bq, const float* __restrict__ bk,
    const float* __restrict__ bv, short* __restrict__ OutBase) {
  int z = blockIdx.z;
  const short* A = Abase + (size_t)z * NROWS * DMODEL;
  const short* Bt = WtBase + (size_t)z * DMODEL * DMODEL;
  const float* bias = (z == 0) ? bq : (z == 1) ? bk : bv;
  short* C = OutBase + (size_t)z * NROWS * DMODEL;
  int bid = blockIdx.x + (blockIdx.y << 4);
  int swz = ((bid & 7) << 6) + (bid >> 3);
  int bn = (swz & 15) << 6;
  int bm = (swz >> 4) << 7;
  gemm_core64<true>(A, Bt, bias, C, bm, bn);
}

// output projection: grid (16, 32), 128x64 tile, XCD-swizzled
__global__ __launch_bounds__(256) void gemm_out(const short* __restrict__ A,
                                                const short* __restrict__ Bt,
                                                const float* __restrict__ bias,
                                                float* __restrict__ C) {
  int bid = blockIdx.x + (blockIdx.y << 4);  // nwg=512
  int swz = ((bid & 7) << 6) + (bid >> 3);
  int bn = (swz & 15) << 6;
  int bm = (swz >> 4) << 7;
  gemm_core64<false>(A, Bt, bias, C, bm, bn);
}

// ---------------- feature map via MFMA (fast-exp epilogue; hk computed inline) ----------------
__global__ __launch_bounds__(256, 1) void featmap_mfma(
    const short* __restrict__ Qproj, const short* __restrict__ Kproj,
    const short* __restrict__ rfb, short* __restrict__ Qp, short* __restrict__ Kp) {
  __shared__ short smem[26624];  // A:8192 | B:18432 ; epilogue reuses as P[128][152]
  __shared__ float hks[128];
  short* As = smem;
  short* Bs = smem + 8192;
  int isK = blockIdx.z;
  const short* X = isK ? Kproj : Qproj;
  short* O = isK ? Kp : Qp;
  int bh = blockIdx.y, b = bh >> 4, h = bh & 15;
  int l0 = blockIdx.x << 7;
  int tid = threadIdx.x, lane = tid & 63, wid = tid >> 6;
  int cl = lane & 15, rq = lane >> 4;

#pragma unroll
  for (int i = 0; i < 4; ++i) {
    int e = tid * 8 + i * 2048;
    int row = e >> 6;
    int k = (e & 63) ^ ((row & 7) << 3);
    gload_lds16(X + ((size_t)b * SEQ + l0 + row) * DMODEL + h * HD + k,
                &As[wid * 512 + i * 2048]);
  }
#pragma unroll
  for (int i = 0; i < 9; ++i) {
    int e = tid * 8 + i * 2048;
    int row = e >> 6;
    int k = (e & 63) ^ ((row & 7) << 3);
    gload_lds16(rfb + row * HD + k, &Bs[wid * 512 + i * 2048]);
  }
  __syncthreads();

  int i0 = wid * 32;
  f32x4 acc[2][18];
#pragma unroll
  for (int m = 0; m < 2; ++m)
#pragma unroll
    for (int n = 0; n < 18; ++n) acc[m][n] = f32x4{0.f, 0.f, 0.f, 0.f};
#pragma unroll
  for (int ks = 0; ks < 2; ++ks) {
    int kb = ks * 32 + (rq << 3);
    int swz = (cl & 7) << 3;
    bf16x8 af[2];
#pragma unroll
    for (int mf = 0; mf < 2; ++mf) {
      int row = i0 + mf * 16 + cl;
      af[mf] = *(const bf16x8*)&As[row * 64 + (kb ^ swz)];
    }
#pragma unroll
    for (int nf = 0; nf < 18; ++nf) {
      int brow = nf * 16 + cl;
      bf16x8 bv = *(const bf16x8*)&Bs[brow * 64 + (kb ^ swz)];
#pragma unroll
      for (int mf = 0; mf < 2; ++mf)
        acc[mf][nf] = __builtin_amdgcn_mfma_f32_16x16x32_bf16(af[mf], bv,
                                                              acc[mf][nf], 0, 0, 0);
    }
  }

  // inline h_k from staged As (within-row XOR permutation preserves sum of squares)
  if (isK) {
    int row = tid >> 1, half = tid & 1;
    const short* rp = &As[row * 64 + half * 32];
    float ss = 0.f;
#pragma unroll
    for (int g = 0; g < 4; ++g) {
      bf16x8 v = *(const bf16x8*)(rp + g * 8);
#pragma unroll
      for (int e = 0; e < 8; ++e) {
        float x = bs2f(v[e]);
        ss += x * x;
      }
    }
    ss += __shfl_xor(ss, 1);
    if (!half) hks[row] = -0.5f * SCAL2 * ss + LN_CNORM;
  }

  short* Ps = smem;  // [128][152]
#pragma unroll
  for (int hf = 0; hf < 2; ++hf) {
    __syncthreads();
#pragma unroll
    for (int mf = 0; mf < 2; ++mf)
#pragma unroll
      for (int r = 0; r < 4; ++r) {
        int rl = i0 + mf * 16 + (rq << 2) + r;
        float addk = isK ? hks[rl] : LN_CNORM;
#pragma unroll
        for (int nf2 = 0; nf2 < 9; ++nf2) {
          int m = hf * 144 + nf2 * 16 + cl;
          float v = acc[mf][hf * 9 + nf2][r] + addk;
          float o = (m < NRF) ? (__expf(v) + CKEPS) : 0.f;
          Ps[rl * 152 + nf2 * 16 + cl] = f2bs(o);
        }
      }
    __syncthreads();
#pragma unroll
    for (int it = 0; it < 9; ++it) {
      int idx = tid + it * 256;
      int row = idx / 18, ch = idx - row * 18;
      bf16x8 val = *(const bf16x8*)&Ps[row * 152 + ch * 8];
      *(bf16x8*)&O[((size_t)bh * SEQ + l0 + row) * NRFP + hf * 144 + ch * 8] = val;
    }
  }
}

// ---------------- per-chunk sums via MFMA -> Sct TRANSPOSED [bh][c][d][SROW] bf16 ----------------
__global__ __launch_bounds__(256) void chunksum_mfma(
    const short* __restrict__ Kp, const short* __restrict__ Vb,
    short* __restrict__ Sct, float* __restrict__ ksum) {
  constexpr int ST = 70;
  __shared__ short KT[NRFP * ST];  // [m][i_loc]
  __shared__ short VT[HD * ST];    // [d][i_loc]
  int c = blockIdx.x, bh = blockIdx.y;
  int b = bh >> 4, h = bh & 15;
  int tid = threadIdx.x, lane = tid & 63, wv = tid >> 6;
  int cl = lane & 15, rq = lane >> 4;
  int irow = tid >> 2;
  int mq = tid & 3;
  size_t rowb = (size_t)bh * SEQ + (size_t)c * CHK;

  f32x4 acc[18];
#pragma unroll
  for (int m = 0; m < 18; ++m) acc[m] = f32x4{0.f, 0.f, 0.f, 0.f};
  float k1 = 0.f, k2 = 0.f;

  for (int hf = 0; hf < 2; ++hf) {
    __syncthreads();
    const short* Krow = Kp + (rowb + hf * 64 + irow) * NRFP;
#pragma unroll
    for (int cg = 0; cg < 9; ++cg) {
      int m0 = cg * 32 + mq * 8;
      bf16x8 v = *(const bf16x8*)(Krow + m0);
#pragma unroll
      for (int e = 0; e < 8; ++e) KT[(m0 + e) * ST + irow] = v[e];
    }
    const short* Vrow =
        Vb + ((size_t)b * SEQ + (size_t)c * CHK + hf * 64 + irow) * DMODEL + h * HD;
    {
      int d0 = mq * 16;
      bf16x8 v0 = *(const bf16x8*)(Vrow + d0);
      bf16x8 v1 = *(const bf16x8*)(Vrow + d0 + 8);
#pragma unroll
      for (int e = 0; e < 8; ++e) VT[(d0 + e) * ST + irow] = v0[e];
#pragma unroll
      for (int e = 0; e < 8; ++e) VT[(d0 + 8 + e) * ST + irow] = v1[e];
    }
    __syncthreads();
#pragma unroll
    for (int ks = 0; ks < 2; ++ks) {
      int kb = ks * 32 + rq * 8;
      bf16x8 bv = *(const bf16x8*)&VT[(wv * 16 + cl) * ST + kb];
#pragma unroll
      for (int mf = 0; mf < 18; ++mf) {
        bf16x8 av = *(const bf16x8*)&KT[(mf * 16 + cl) * ST + kb];
        acc[mf] = __builtin_amdgcn_mfma_f32_16x16x32_bf16(av, bv, acc[mf], 0, 0, 0);
      }
    }
    {
      const short* r1 = &KT[tid * ST];
#pragma unroll
      for (int g = 0; g < 8; ++g) {
        bf16x8 v = *(const bf16x8*)(r1 + g * 8);
#pragma unroll
        for (int e = 0; e < 8; ++e) k1 += bs2f(v[e]);
      }
      if (tid < 10) {
        const short* r2 = &KT[(256 + tid) * ST];
#pragma unroll
        for (int g = 0; g < 8; ++g) {
          bf16x8 v = *(const bf16x8*)(r2 + g * 8);
#pragma unroll
          for (int e = 0; e < 8; ++e) k2 += bs2f(v[e]);
        }
      }
    }
  }
  size_t sbase = ((size_t)bh * NCH + c) * (size_t)(HD * SROW);
  int d = wv * 16 + cl;
#pragma unroll
  for (int mf = 0; mf < 18; ++mf) {
    short4 o4 = make_short4(f2bs(acc[mf][0]), f2bs(acc[mf][1]),
                            f2bs(acc[mf][2]), f2bs(acc[mf][3]));
    *(short4*)&Sct[sbase + (size_t)d * SROW + mf * 16 + rq * 4] = o4;
  }
  {
    int dz = tid >> 2, off = NRFP + ((tid & 3) << 3);
    bf16x8 z = {0, 0, 0, 0, 0, 0, 0, 0};
    *(bf16x8*)&Sct[sbase + (size_t)dz * SROW + off] = z;
  }
  size_t kbase = ((size_t)bh * NCH + c) * (size_t)NRF;
  if (tid < NRF) ksum[kbase + tid] = k1;
  if (tid < 10) ksum[kbase + 256 + tid] = k2;
}

// ---------------- fused exclusive prefixes over chunks ----------------
__global__ __launch_bounds__(256) void prefix_all(const short* __restrict__ Sct,
                                                  short* __restrict__ Spt,
                                                  const float* __restrict__ ksum,
                                                  short* __restrict__ ksb) {
  int bh = blockIdx.y;
  if (blockIdx.x == 80) {
    for (int m = threadIdx.x; m < NRFP; m += 256) {
      if (m < NRF) {
        size_t base = (size_t)bh * NCH * NRF + m;
        float a = 0.f;
#pragma unroll
        for (int c = 0; c < NCH; ++c) {
          float v = ksum[base + (size_t)c * NRF];
          ksb[((size_t)bh * NCH + c) * NRFP + m] = f2bs(a);
          a += v;
        }
      } else {
#pragma unroll
        for (int c = 0; c < NCH; ++c)
          ksb[((size_t)bh * NCH + c) * NRFP + m] = 0;
      }
    }
    return;
  }
  int e = blockIdx.x * 256 + threadIdx.x;  // over 64*SROW = 20480 (80 blocks exact)
  float a = 0.f;
#pragma unroll
  for (int c = 0; c < NCH; ++c) {
    size_t idx = ((size_t)bh * NCH + c) * (size_t)(HD * SROW) + e;
    float v = bs2f(Sct[idx]);
    Spt[idx] = f2bs(a);
    a += v;
  }
}

// ---------------- FUSED inter+intra: LDS-staged K (dbuf, counted vmcnt) ----------------
__global__ __launch_bounds__(256) void attn_mfma(
    const short* __restrict__ Qp, const short* __restrict__ Kp,
    const short* __restrict__ Vb, const short* __restrict__ Spt,
    const short* __restrict__ ksb, short* __restrict__ ctxb) {
  constexpr int PST = 136;
  __shared__ short Vt[64 * PST];      // V^T [d][j]
  __shared__ short SP[64 * SROW];     // Sp^T (swizzled) -> later P region
  __shared__ short Kb2[2][128 * 32];  // K' slice dbuf
  int c = blockIdx.x, bh = blockIdx.y;
  int b = bh >> 4, h = bh & 15;
  int tid = threadIdx.x, lane = tid & 63, wid = tid >> 6;
  int cl = lane & 15, rq = lane >> 4;
  size_t rowb = (size_t)bh * SEQ + (size_t)c * CHK;

  {
    int jj = tid >> 3, d0 = (tid & 7) << 3;
#pragma unroll
    for (int jt = 0; jt < 4; ++jt) {
      int j = jj + jt * 32;
      bf16x8 v = *(const bf16x8*)(Vb + ((size_t)b * SEQ + (size_t)c * CHK + j) * DMODEL +
                                  h * HD + d0);
#pragma unroll
      for (int e = 0; e < 8; ++e) Vt[(d0 + e) * PST + j] = v[e];
    }
  }
  const short* sg = Spt + ((size_t)bh * NCH + c) * (size_t)(HD * SROW);
#pragma unroll
  for (int i = 0; i < 10; ++i) {
    int o = tid * 8 + i * 2048;
    int d = o / SROW;
    int m = o - d * SROW;
    int ms = m ^ ((d & 7) << 3);
    gload_lds16(sg + (size_t)d * SROW + ms, &SP[wid * 512 + i * 2048]);
  }
  const short* Kbase = Kp + rowb * NRFP;
  auto stageK = [&](int buf, int k0) {
#pragma unroll
    for (int i = 0; i < 2; ++i) {
      int chunk = tid + i * 256;
      int row = chunk >> 2, cc = chunk & 3;
      int col = k0 + ((cc ^ (row & 3)) << 3);
      gload_lds16(Kbase + (size_t)row * NRFP + col,
                  &Kb2[buf][(wid * 64 + i * 256) * 8]);
    }
  };
  stageK(0, 0);

  int i0 = wid * 32;
  const short* Arow = Qp + (rowb + i0) * NRFP;
  const short* krow = ksb + ((size_t)bh * NCH + c) * NRFP;
  f32x4 accI[2][4];
  f32x4 accD[2];
  f32x4 accP[2][8];
#pragma unroll
  for (int m = 0; m < 2; ++m) {
#pragma unroll
    for (int n = 0; n < 4; ++n) accI[m][n] = f32x4{0.f, 0.f, 0.f, 0.f};
    accD[m] = f32x4{0.f, 0.f, 0.f, 0.f};
#pragma unroll
    for (int n = 0; n < 8; ++n) accP[m][n] = f32x4{0.f, 0.f, 0.f, 0.f};
  }
  for (int k9 = 0; k9 < 9; ++k9) {
    int cur = k9 & 1;
    if (k9 < 8) {
      stageK(cur ^ 1, (k9 + 1) * 32);
      asm volatile("s_waitcnt vmcnt(2)" ::: "memory");
    } else {
      asm volatile("s_waitcnt vmcnt(0)" ::: "memory");
    }
    __builtin_amdgcn_s_barrier();
    asm volatile("" ::: "memory");
    int kb = k9 * 32 + (rq << 3);
    bf16x8 af[2];
#pragma unroll
    for (int mf = 0; mf < 2; ++mf)
      af[mf] = *(const bf16x8*)(Arow + (size_t)(mf * 16 + cl) * NRFP + kb);
    bf16x8 bvD = {0, 0, 0, 0, 0, 0, 0, 0};
    if (cl == 0) bvD = *(const bf16x8*)(krow + kb);
#pragma unroll
    for (int mf = 0; mf < 2; ++mf)
      accD[mf] = __builtin_amdgcn_mfma_f32_16x16x32_bf16(af[mf], bvD, accD[mf], 0, 0, 0);
#pragma unroll
    for (int nf = 0; nf < 4; ++nf) {
      int row = nf * 16 + cl;
      bf16x8 bv = *(const bf16x8*)&SP[row * SROW + (kb ^ ((cl & 7) << 3))];
#pragma unroll
      for (int mf = 0; mf < 2; ++mf)
        accI[mf][nf] = __builtin_amdgcn_mfma_f32_16x16x32_bf16(af[mf], bv,
                                                               accI[mf][nf], 0, 0, 0);
    }
    const short* kcur = &Kb2[cur][0];
#pragma unroll
    for (int nf = 0; nf < 8; ++nf) {
      int row = nf * 16 + cl;
      bf16x8 bv = *(const bf16x8*)&kcur[row * 32 + ((rq ^ (cl & 3)) << 3)];
#pragma unroll
      for (int mf = 0; mf < 2; ++mf)
        accP[mf][nf] = __builtin_amdgcn_mfma_f32_16x16x32_bf16(af[mf], bv,
                                                               accP[mf][nf], 0, 0, 0);
    }
    __builtin_amdgcn_s_barrier();
    asm volatile("" ::: "memory");
  }

  float dtot[2][4];
#pragma unroll
  for (int mf = 0; mf < 2; ++mf)
#pragma unroll
    for (int r = 0; r < 4; ++r) {
      int rl = mf * 16 + (rq << 2) + r;
      int row = i0 + rl;
      float dsum = 0.f;
#pragma unroll
      for (int nf = 0; nf < 8; ++nf) {
        int col = nf * 16 + cl;
        float v = (col > row) ? 0.f : accP[mf][nf][r];
        dsum += v;
        SP[wid * 32 * PST + rl * PST + col] = f2bs(v);
      }
      dsum += __shfl_xor(dsum, 1);
      dsum += __shfl_xor(dsum, 2);
      dsum += __shfl_xor(dsum, 4);
      dsum += __shfl_xor(dsum, 8);
      float dden = __shfl(accD[mf][r], lane & 48);
      dtot[mf][r] = dden + dsum;
    }
  __syncthreads();

  f32x4 pacc[2][4];
#pragma unroll
  for (int m = 0; m < 2; ++m)
#pragma unroll
    for (int n = 0; n < 4; ++n) pacc[m][n] = f32x4{0.f, 0.f, 0.f, 0.f};
#pragma unroll
  for (int kk = 0; kk < 4; ++kk) {
    int kb = kk * 32 + (rq << 3);
    bf16x8 paf[2];
#pragma unroll
    for (int mf = 0; mf < 2; ++mf)
      paf[mf] = *(const bf16x8*)&SP[wid * 32 * PST + (mf * 16 + cl) * PST + kb];
#pragma unroll
    for (int nf = 0; nf < 4; ++nf) {
      bf16x8 bv = *(const bf16x8*)&Vt[(nf * 16 + cl) * PST + kb];
#pragma unroll
      for (int mf = 0; mf < 2; ++mf)
        pacc[mf][nf] = __builtin_amdgcn_mfma_f32_16x16x32_bf16(paf[mf], bv,
                                                               pacc[mf][nf], 0, 0, 0);
    }
  }
#pragma unroll
  for (int mf = 0; mf < 2; ++mf)
#pragma unroll
    for (int r = 0; r < 4; ++r) {
      int row = i0 + mf * 16 + (rq << 2) + r;
      float inv = 1.0f / dtot[mf][r];
      size_t ob = ((size_t)b * SEQ + (size_t)c * CHK + row) * DMODEL + h * HD;
#pragma unroll
      for (int nf = 0; nf < 4; ++nf) {
        int d = nf * 16 + cl;
        float v = (accI[mf][nf][r] + pacc[mf][nf][r]) * inv;
        ctxb[ob + d] = f2bs(v);
      }
    }
}

// ---------------- launch ----------------
extern "C" void kernel_launch(void* const* d_in, const int* in_sizes, int n_in,
                              void* d_out, int out_size, void* d_ws, size_t ws_size,
                              hipStream_t stream) {
  (void)in_sizes; (void)n_in; (void)out_size;
  const float* query = (const float*)d_in[0];
  const float* key_  = (const float*)d_in[1];
  const float* value = (const float*)d_in[2];
  const float* Wq = (const float*)d_in[3];
  const float* bq = (const float*)d_in[4];
  const float* Wk = (const float*)d_in[5];
  const float* bk = (const float*)d_in[6];
  const float* Wv = (const float*)d_in[7];
  const float* bv = (const float*)d_in[8];
  const float* Wo = (const float*)d_in[9];
  const float* bo = (const float*)d_in[10];
  const float* rf = (const float*)d_in[11];

  constexpr size_t SZ_INBF = (size_t)NROWS * DMODEL * 2;
  constexpr size_t SZ_QP   = (size_t)NBH * SEQ * NRFP * 2;
  constexpr size_t SZ_WT   = (size_t)DMODEL * DMODEL * 2;
  constexpr size_t SZ_SCH  = (size_t)NBH * NCH * HD * SROW * 2;
  constexpr size_t SZ_KS   = (size_t)NBH * NCH * NRF * 4;
  constexpr size_t SZ_KSB  = (size_t)NBH * NCH * NRFP * 2;
  constexpr size_t SZ_RFB  = (size_t)NRFP * HD * 2;

  constexpr size_t O_QP   = 0;
  constexpr size_t O_KP   = O_QP + SZ_QP;
  constexpr size_t O_WT   = O_KP + SZ_QP;
  constexpr size_t O_QPR  = O_WT + 4 * SZ_WT;
  constexpr size_t O_SCH  = O_QPR + 3 * SZ_INBF;
  constexpr size_t O_SPR  = O_SCH + SZ_SCH;
  constexpr size_t O_KSUM = O_SPR + SZ_SCH;
  constexpr size_t O_KSB  = O_KSUM + SZ_KS;
  constexpr size_t O_CTXB = O_KSB + SZ_KSB;
  constexpr size_t O_RFB  = O_CTXB + SZ_INBF;
  constexpr size_t O_END  = O_RFB + SZ_RFB;
  if (ws_size < O_END) return;

  char* w = (char*)d_ws;
  short* Qbf  = (short*)(w + O_QP);
  short* Qp   = (short*)(w + O_QP);
  short* Kp   = (short*)(w + O_KP);
  short* WtB  = (short*)(w + O_WT);
  short* QprB = (short*)(w + O_QPR);
  short* Kpr  = (short*)(w + O_QPR + SZ_INBF);
  short* Vpr  = (short*)(w + O_QPR + 2 * SZ_INBF);
  short* Sct  = (short*)(w + O_SCH);
  short* Spt  = (short*)(w + O_SPR);
  float* ksum = (float*)(w + O_KSUM);
  short* ksb  = (short*)(w + O_KSB);
  short* ctxb = (short*)(w + O_CTXB);
  short* rfb  = (short*)(w + O_RFB);

  constexpr int NEL = NROWS * DMODEL;
  cvt3_kernel<<<dim3(NEL / 2048, 3), 256, 0, stream>>>(query, key_, value, Qbf);
  transpose5_bf16<<<dim3(32, 32, 5), 256, 0, stream>>>(Wq, Wk, Wv, Wo, rf, WtB, rfb);
  gemm_qkv3<<<dim3(16, 32, 3), 256, 0, stream>>>(Qbf, WtB, bq, bk, bv, QprB);
  featmap_mfma<<<dim3(SEQ / 128, NBH, 2), 256, 0, stream>>>(QprB, Kpr, rfb, Qp, Kp);
  chunksum_mfma<<<dim3(NCH, NBH), 256, 0, stream>>>(Kp, Vpr, Sct, ksum);
  prefix_all<<<dim3(81, NBH), 256, 0, stream>>>(Sct, Spt, ksum, ksb);
  attn_mfma<<<dim3(NCH, NBH), 256, 0, stream>>>(Qp, Kp, Vpr, Spt, ksb, ctxb);
  gemm_out<<<dim3(16, 32), 256, 0, stream>>>(ctxb, WtB + 3 * (size_t)DMODEL * DMODEL,
                                             bo, (float*)d_out);
}

// Round 19
// 158.003 us; speedup vs baseline: 1.2089x; 1.0178x over previous
//
#include <hip/hip_runtime.h>
#include <hip/hip_bf16.h>

#define BATCH 2
#define SEQ 2048
#define DMODEL 1024
#define NH 16
#define HD 64
#define NRF 266
#define NRFP 288   // padded feature dim (multiple of 32), cols [266,288) are zero
#define SROW 320   // transposed-S row stride
#define CHK 128
#define NCH 16
#define NBH 32
#define NROWS 4096  // BATCH*SEQ

constexpr float SCAL = 0.17677669529663687f;   // DMODEL^-0.25
constexpr float SCAL2 = 0.03125f;              // SCAL^2 = DMODEL^-0.5
constexpr float LN_CNORM = -2.7917480361965505f;   // ln(1/sqrt(266))
constexpr float CKEPS = 6.131393094576169e-6f;     // CNORM*KEPS

typedef short bf16x8 __attribute__((ext_vector_type(8)));
typedef float f32x4 __attribute__((ext_vector_type(4)));

__device__ __forceinline__ short f2bs(float v) {
  __hip_bfloat16 h = __float2bfloat16(v);
  return *reinterpret_cast<short*>(&h);
}
__device__ __forceinline__ float bs2f(short s) {
  __hip_bfloat16 h;
  *reinterpret_cast<short*>(&h) = s;
  return __bfloat162float(h);
}
__device__ __forceinline__ void gload_lds16(const void* g, void* l) {
  __builtin_amdgcn_global_load_lds(
      (const __attribute__((address_space(1))) void*)g,
      (__attribute__((address_space(3))) void*)l, 16, 0, 0);
}

// ---------------- fused prep: cvt q/k/v (z<3, + rf on z==0), W transposes (z==3,4) ----------------
__global__ __launch_bounds__(256) void prep_kernel(
    const float* __restrict__ q, const float* __restrict__ k,
    const float* __restrict__ v, const float* __restrict__ Wq,
    const float* __restrict__ Wk, const float* __restrict__ Wv,
    const float* __restrict__ Wo, const float* __restrict__ rf,
    short* __restrict__ out, short* __restrict__ WtBase, short* __restrict__ rfb) {
  int z = blockIdx.z;
  int tid = threadIdx.x;
  if (z < 3) {
    const float* x = (z == 0) ? q : (z == 1) ? k : v;
    short* y = out + (size_t)z * NROWS * DMODEL;
    int bid = blockIdx.y * 64 + blockIdx.x;  // 0..2047
    int i = bid * 2048 + tid * 8;
    float4 a = *(const float4*)&x[i];
    float4 b = *(const float4*)&x[i + 4];
    bf16x8 o;
    o[0] = f2bs(a.x); o[1] = f2bs(a.y); o[2] = f2bs(a.z); o[3] = f2bs(a.w);
    o[4] = f2bs(b.x); o[5] = f2bs(b.y); o[6] = f2bs(b.z); o[7] = f2bs(b.w);
    *(bf16x8*)&y[i] = o;
    if (z == 0 && bid < 72) {  // rf pad + SCAL fold (18432 elems = 72*256)
      int idx = bid * 256 + tid;
      rfb[idx] = (idx < NRF * HD) ? f2bs(rf[idx] * SCAL) : (short)0;
    }
    return;
  }
  // z==3: Wq (x<32) / Wk ; z==4: Wv (x<32) / Wo
  __shared__ float t[32][33];
  int wsel = (z - 3) * 2 + (blockIdx.x >> 5);
  const float* W = (wsel == 0) ? Wq : (wsel == 1) ? Wk : (wsel == 2) ? Wv : Wo;
  short* Wt = WtBase + (size_t)wsel * DMODEL * DMODEL;
  int k0 = blockIdx.y << 5, n0 = (blockIdx.x & 31) << 5;
  int tx = tid & 31, ty = tid >> 5;
#pragma unroll
  for (int rr = 0; rr < 4; ++rr) {
    int r = ty + (rr << 3);
    t[r][tx] = W[(size_t)(k0 + r) * DMODEL + n0 + tx];
  }
  __syncthreads();
#pragma unroll
  for (int rr = 0; rr < 4; ++rr) {
    int r = ty + (rr << 3);
    Wt[(size_t)(n0 + r) * DMODEL + k0 + tx] = f2bs(t[tx][r]);
  }
}

// ---------------- MFMA GEMM core 128x64, BK=64, dbuf + counted vmcnt ----------------
template <bool OUTBF>
__device__ __forceinline__ void gemm_core64(const short* __restrict__ A,
                                            const short* __restrict__ Bt,
                                            const float* __restrict__ bias,
                                            void* __restrict__ C, int bm, int bn) {
  __shared__ short As[2][128 * 64];
  __shared__ short Bs[2][64 * 64];
  int tid = threadIdx.x;
  int lane = tid & 63, wid = tid >> 6;
  int wr = wid >> 1, wc = wid & 1;
  f32x4 acc[4][2];
#pragma unroll
  for (int m = 0; m < 4; ++m)
#pragma unroll
    for (int n = 0; n < 2; ++n) acc[m][n] = f32x4{0.f, 0.f, 0.f, 0.f};

  size_t abase[4], bbase[2];
#pragma unroll
  for (int i = 0; i < 4; ++i) {
    int e = tid * 8 + i * 2048;
    int row = e >> 6;
    int k = (e & 63) ^ ((row & 7) << 3);
    abase[i] = (size_t)(bm + row) * DMODEL + k;
    if (i < 2) bbase[i] = (size_t)(bn + row) * DMODEL + k;
  }
  auto stage = [&](int buf, int k0) {
#pragma unroll
    for (int i = 0; i < 4; ++i)
      gload_lds16(A + abase[i] + k0, &As[buf][wid * 512 + i * 2048]);
#pragma unroll
    for (int i = 0; i < 2; ++i)
      gload_lds16(Bt + bbase[i] + k0, &Bs[buf][wid * 512 + i * 2048]);
  };

  stage(0, 0);
#pragma unroll 2
  for (int t = 0; t < 16; ++t) {
    int cur = t & 1;
    if (t < 15) {
      stage(cur ^ 1, (t + 1) * 64);
      asm volatile("s_waitcnt vmcnt(6)" ::: "memory");
    } else {
      asm volatile("s_waitcnt vmcnt(0)" ::: "memory");
    }
    __builtin_amdgcn_s_barrier();
    asm volatile("" ::: "memory");
    const short* curA = &As[cur][0];
    const short* curB = &Bs[cur][0];
#pragma unroll
    for (int ks = 0; ks < 2; ++ks) {
      int kb = ks * 32 + ((lane >> 4) << 3);
      bf16x8 af[4], bfv[2];
#pragma unroll
      for (int mf = 0; mf < 4; ++mf) {
        int row = wr * 64 + mf * 16 + (lane & 15);
        af[mf] = *(const bf16x8*)&curA[row * 64 + (kb ^ ((row & 7) << 3))];
      }
#pragma unroll
      for (int nf = 0; nf < 2; ++nf) {
        int row = wc * 32 + nf * 16 + (lane & 15);
        bfv[nf] = *(const bf16x8*)&curB[row * 64 + (kb ^ ((row & 7) << 3))];
      }
#pragma unroll
      for (int mf = 0; mf < 4; ++mf)
#pragma unroll
        for (int nf = 0; nf < 2; ++nf)
          acc[mf][nf] = __builtin_amdgcn_mfma_f32_16x16x32_bf16(af[mf], bfv[nf],
                                                                acc[mf][nf], 0, 0, 0);
    }
    __builtin_amdgcn_s_barrier();
    asm volatile("" ::: "memory");
  }
  int rbase = bm + wr * 64 + ((lane >> 4) << 2);
  int cbase = bn + wc * 32 + (lane & 15);
#pragma unroll
  for (int nf = 0; nf < 2; ++nf) {
    int col = cbase + nf * 16;
    float bv = bias[col];
#pragma unroll
    for (int mf = 0; mf < 4; ++mf)
#pragma unroll
      for (int r = 0; r < 4; ++r) {
        int row = rbase + mf * 16 + r;
        float v = acc[mf][nf][r] + bv;
        if (OUTBF)
          ((short*)C)[(size_t)row * DMODEL + col] = f2bs(v);
        else
          ((float*)C)[(size_t)row * DMODEL + col] = v;
      }
  }
}

// fused QKV projection: grid (16, 32, 3), 128x64 tile, XCD-swizzled (nwg=512 per z)
__global__ __launch_bounds__(256) void gemm_qkv3(
    const short* __restrict__ Abase, const short* __restrict__ WtBase,
    const float* __restrict__ bq, const float* __restrict__ bk,
    const float* __restrict__ bv, short* __restrict__ OutBase) {
  int z = blockIdx.z;
  const short* A = Abase + (size_t)z * NROWS * DMODEL;
  const short* Bt = WtBase + (size_t)z * DMODEL * DMODEL;
  const float* bias = (z == 0) ? bq : (z == 1) ? bk : bv;
  short* C = OutBase + (size_t)z * NROWS * DMODEL;
  int bid = blockIdx.x + (blockIdx.y << 4);
  int swz = ((bid & 7) << 6) + (bid >> 3);
  int bn = (swz & 15) << 6;
  int bm = (swz >> 4) << 7;
  gemm_core64<true>(A, Bt, bias, C, bm, bn);
}

// output projection: grid (16, 32), 128x64 tile, XCD-swizzled
__global__ __launch_bounds__(256) void gemm_out(const short* __restrict__ A,
                                                const short* __restrict__ Bt,
                                                const float* __restrict__ bias,
                                                float* __restrict__ C) {
  int bid = blockIdx.x + (blockIdx.y << 4);  // nwg=512
  int swz = ((bid & 7) << 6) + (bid >> 3);
  int bn = (swz & 15) << 6;
  int bm = (swz >> 4) << 7;
  gemm_core64<false>(A, Bt, bias, C, bm, bn);
}

// ---------------- feature map via MFMA (fast-exp epilogue; hk computed inline) ----------------
__global__ __launch_bounds__(256, 1) void featmap_mfma(
    const short* __restrict__ Qproj, const short* __restrict__ Kproj,
    const short* __restrict__ rfb, short* __restrict__ Qp, short* __restrict__ Kp) {
  __shared__ short smem[26624];  // A:8192 | B:18432 ; epilogue reuses as P[128][152]
  __shared__ float hks[128];
  short* As = smem;
  short* Bs = smem + 8192;
  int isK = blockIdx.z;
  const short* X = isK ? Kproj : Qproj;
  short* O = isK ? Kp : Qp;
  int bh = blockIdx.y, b = bh >> 4, h = bh & 15;
  int l0 = blockIdx.x << 7;
  int tid = threadIdx.x, lane = tid & 63, wid = tid >> 6;
  int cl = lane & 15, rq = lane >> 4;

#pragma unroll
  for (int i = 0; i < 4; ++i) {
    int e = tid * 8 + i * 2048;
    int row = e >> 6;
    int k = (e & 63) ^ ((row & 7) << 3);
    gload_lds16(X + ((size_t)b * SEQ + l0 + row) * DMODEL + h * HD + k,
                &As[wid * 512 + i * 2048]);
  }
#pragma unroll
  for (int i = 0; i < 9; ++i) {
    int e = tid * 8 + i * 2048;
    int row = e >> 6;
    int k = (e & 63) ^ ((row & 7) << 3);
    gload_lds16(rfb + row * HD + k, &Bs[wid * 512 + i * 2048]);
  }
  __syncthreads();

  int i0 = wid * 32;
  f32x4 acc[2][18];
#pragma unroll
  for (int m = 0; m < 2; ++m)
#pragma unroll
    for (int n = 0; n < 18; ++n) acc[m][n] = f32x4{0.f, 0.f, 0.f, 0.f};
#pragma unroll
  for (int ks = 0; ks < 2; ++ks) {
    int kb = ks * 32 + (rq << 3);
    int swz = (cl & 7) << 3;
    bf16x8 af[2];
#pragma unroll
    for (int mf = 0; mf < 2; ++mf) {
      int row = i0 + mf * 16 + cl;
      af[mf] = *(const bf16x8*)&As[row * 64 + (kb ^ swz)];
    }
#pragma unroll
    for (int nf = 0; nf < 18; ++nf) {
      int brow = nf * 16 + cl;
      bf16x8 bv = *(const bf16x8*)&Bs[brow * 64 + (kb ^ swz)];
#pragma unroll
      for (int mf = 0; mf < 2; ++mf)
        acc[mf][nf] = __builtin_amdgcn_mfma_f32_16x16x32_bf16(af[mf], bv,
                                                              acc[mf][nf], 0, 0, 0);
    }
  }

  // inline h_k from staged As (within-row XOR permutation preserves sum of squares)
  if (isK) {
    int row = tid >> 1, half = tid & 1;
    const short* rp = &As[row * 64 + half * 32];
    float ss = 0.f;
#pragma unroll
    for (int g = 0; g < 4; ++g) {
      bf16x8 v = *(const bf16x8*)(rp + g * 8);
#pragma unroll
      for (int e = 0; e < 8; ++e) {
        float x = bs2f(v[e]);
        ss += x * x;
      }
    }
    ss += __shfl_xor(ss, 1);
    if (!half) hks[row] = -0.5f * SCAL2 * ss + LN_CNORM;
  }

  short* Ps = smem;  // [128][152]
#pragma unroll
  for (int hf = 0; hf < 2; ++hf) {
    __syncthreads();
#pragma unroll
    for (int mf = 0; mf < 2; ++mf)
#pragma unroll
      for (int r = 0; r < 4; ++r) {
        int rl = i0 + mf * 16 + (rq << 2) + r;
        float addk = isK ? hks[rl] : LN_CNORM;
#pragma unroll
        for (int nf2 = 0; nf2 < 9; ++nf2) {
          int m = hf * 144 + nf2 * 16 + cl;
          float v = acc[mf][hf * 9 + nf2][r] + addk;
          float o = (m < NRF) ? (__expf(v) + CKEPS) : 0.f;
          Ps[rl * 152 + nf2 * 16 + cl] = f2bs(o);
        }
      }
    __syncthreads();
#pragma unroll
    for (int it = 0; it < 9; ++it) {
      int idx = tid + it * 256;
      int row = idx / 18, ch = idx - row * 18;
      bf16x8 val = *(const bf16x8*)&Ps[row * 152 + ch * 8];
      *(bf16x8*)&O[((size_t)bh * SEQ + l0 + row) * NRFP + hf * 144 + ch * 8] = val;
    }
  }
}

// ---------------- per-chunk sums via MFMA -> Sct TRANSPOSED [bh][c][d][SROW] bf16 ----------------
__global__ __launch_bounds__(256) void chunksum_mfma(
    const short* __restrict__ Kp, const short* __restrict__ Vb,
    short* __restrict__ Sct, float* __restrict__ ksum) {
  constexpr int ST = 70;
  __shared__ short KT[NRFP * ST];  // [m][i_loc]
  __shared__ short VT[HD * ST];    // [d][i_loc]
  int c = blockIdx.x, bh = blockIdx.y;
  int b = bh >> 4, h = bh & 15;
  int tid = threadIdx.x, lane = tid & 63, wv = tid >> 6;
  int cl = lane & 15, rq = lane >> 4;
  int irow = tid >> 2;
  int mq = tid & 3;
  size_t rowb = (size_t)bh * SEQ + (size_t)c * CHK;

  f32x4 acc[18];
#pragma unroll
  for (int m = 0; m < 18; ++m) acc[m] = f32x4{0.f, 0.f, 0.f, 0.f};
  float k1 = 0.f, k2 = 0.f;

  for (int hf = 0; hf < 2; ++hf) {
    __syncthreads();
    const short* Krow = Kp + (rowb + hf * 64 + irow) * NRFP;
#pragma unroll
    for (int cg = 0; cg < 9; ++cg) {
      int m0 = cg * 32 + mq * 8;
      bf16x8 v = *(const bf16x8*)(Krow + m0);
#pragma unroll
      for (int e = 0; e < 8; ++e) KT[(m0 + e) * ST + irow] = v[e];
    }
    const short* Vrow =
        Vb + ((size_t)b * SEQ + (size_t)c * CHK + hf * 64 + irow) * DMODEL + h * HD;
    {
      int d0 = mq * 16;
      bf16x8 v0 = *(const bf16x8*)(Vrow + d0);
      bf16x8 v1 = *(const bf16x8*)(Vrow + d0 + 8);
#pragma unroll
      for (int e = 0; e < 8; ++e) VT[(d0 + e) * ST + irow] = v0[e];
#pragma unroll
      for (int e = 0; e < 8; ++e) VT[(d0 + 8 + e) * ST + irow] = v1[e];
    }
    __syncthreads();
#pragma unroll
    for (int ks = 0; ks < 2; ++ks) {
      int kb = ks * 32 + rq * 8;
      bf16x8 bv = *(const bf16x8*)&VT[(wv * 16 + cl) * ST + kb];
#pragma unroll
      for (int mf = 0; mf < 18; ++mf) {
        bf16x8 av = *(const bf16x8*)&KT[(mf * 16 + cl) * ST + kb];
        acc[mf] = __builtin_amdgcn_mfma_f32_16x16x32_bf16(av, bv, acc[mf], 0, 0, 0);
      }
    }
    {
      const short* r1 = &KT[tid * ST];
#pragma unroll
      for (int g = 0; g < 8; ++g) {
        bf16x8 v = *(const bf16x8*)(r1 + g * 8);
#pragma unroll
        for (int e = 0; e < 8; ++e) k1 += bs2f(v[e]);
      }
      if (tid < 10) {
        const short* r2 = &KT[(256 + tid) * ST];
#pragma unroll
        for (int g = 0; g < 8; ++g) {
          bf16x8 v = *(const bf16x8*)(r2 + g * 8);
#pragma unroll
          for (int e = 0; e < 8; ++e) k2 += bs2f(v[e]);
        }
      }
    }
  }
  size_t sbase = ((size_t)bh * NCH + c) * (size_t)(HD * SROW);
  int d = wv * 16 + cl;
#pragma unroll
  for (int mf = 0; mf < 18; ++mf) {
    short4 o4 = make_short4(f2bs(acc[mf][0]), f2bs(acc[mf][1]),
                            f2bs(acc[mf][2]), f2bs(acc[mf][3]));
    *(short4*)&Sct[sbase + (size_t)d * SROW + mf * 16 + rq * 4] = o4;
  }
  size_t kbase = ((size_t)bh * NCH + c) * (size_t)NRF;
  if (tid < NRF) ksum[kbase + tid] = k1;
  if (tid < 10) ksum[kbase + 256 + tid] = k2;
}

// ---------------- fused exclusive prefixes over chunks (pad cols written as zero) ----------------
__global__ __launch_bounds__(256) void prefix_all(const short* __restrict__ Sct,
                                                  short* __restrict__ Spt,
                                                  const float* __restrict__ ksum,
                                                  short* __restrict__ ksb) {
  int bh = blockIdx.y;
  if (blockIdx.x == 80) {
    for (int m = threadIdx.x; m < NRFP; m += 256) {
      if (m < NRF) {
        size_t base = (size_t)bh * NCH * NRF + m;
        float a = 0.f;
#pragma unroll
        for (int c = 0; c < NCH; ++c) {
          float v = ksum[base + (size_t)c * NRF];
          ksb[((size_t)bh * NCH + c) * NRFP + m] = f2bs(a);
          a += v;
        }
      } else {
#pragma unroll
        for (int c = 0; c < NCH; ++c)
          ksb[((size_t)bh * NCH + c) * NRFP + m] = 0;
      }
    }
    return;
  }
  int e = blockIdx.x * 256 + threadIdx.x;  // over 64*SROW = 20480 (80 blocks exact)
  int col = e % SROW;
  if (col >= NRFP) {  // pad cols [288,320): Spt must be zero (attn reads them)
#pragma unroll
    for (int c = 0; c < NCH; ++c)
      Spt[((size_t)bh * NCH + c) * (size_t)(HD * SROW) + e] = 0;
    return;
  }
  float a = 0.f;
#pragma unroll
  for (int c = 0; c < NCH; ++c) {
    size_t idx = ((size_t)bh * NCH + c) * (size_t)(HD * SROW) + e;
    float v = bs2f(Sct[idx]);
    Spt[idx] = f2bs(a);
    a += v;
  }
}

// ---------------- FUSED inter+intra: LDS-staged K (dbuf, counted vmcnt) ----------------
__global__ __launch_bounds__(256) void attn_mfma(
    const short* __restrict__ Qp, const short* __restrict__ Kp,
    const short* __restrict__ Vb, const short* __restrict__ Spt,
    const short* __restrict__ ksb, short* __restrict__ ctxb) {
  constexpr int PST = 136;
  __shared__ short Vt[64 * PST];      // V^T [d][j]
  __shared__ short SP[64 * SROW];     // Sp^T (swizzled) -> later P region
  __shared__ short Kb2[2][128 * 32];  // K' slice dbuf
  int c = blockIdx.x, bh = blockIdx.y;
  int b = bh >> 4, h = bh & 15;
  int tid = threadIdx.x, lane = tid & 63, wid = tid >> 6;
  int cl = lane & 15, rq = lane >> 4;
  size_t rowb = (size_t)bh * SEQ + (size_t)c * CHK;

  {
    int jj = tid >> 3, d0 = (tid & 7) << 3;
#pragma unroll
    for (int jt = 0; jt < 4; ++jt) {
      int j = jj + jt * 32;
      bf16x8 v = *(const bf16x8*)(Vb + ((size_t)b * SEQ + (size_t)c * CHK + j) * DMODEL +
                                  h * HD + d0);
#pragma unroll
      for (int e = 0; e < 8; ++e) Vt[(d0 + e) * PST + j] = v[e];
    }
  }
  const short* sg = Spt + ((size_t)bh * NCH + c) * (size_t)(HD * SROW);
#pragma unroll
  for (int i = 0; i < 10; ++i) {
    int o = tid * 8 + i * 2048;
    int d = o / SROW;
    int m = o - d * SROW;
    int ms = m ^ ((d & 7) << 3);
    gload_lds16(sg + (size_t)d * SROW + ms, &SP[wid * 512 + i * 2048]);
  }
  const short* Kbase = Kp + rowb * NRFP;
  auto stageK = [&](int buf, int k0) {
#pragma unroll
    for (int i = 0; i < 2; ++i) {
      int chunk = tid + i * 256;
      int row = chunk >> 2, cc = chunk & 3;
      int col = k0 + ((cc ^ (row & 3)) << 3);
      gload_lds16(Kbase + (size_t)row * NRFP + col,
                  &Kb2[buf][(wid * 64 + i * 256) * 8]);
    }
  };
  stageK(0, 0);

  int i0 = wid * 32;
  const short* Arow = Qp + (rowb + i0) * NRFP;
  const short* krow = ksb + ((size_t)bh * NCH + c) * NRFP;
  f32x4 accI[2][4];
  f32x4 accD[2];
  f32x4 accP[2][8];
#pragma unroll
  for (int m = 0; m < 2; ++m) {
#pragma unroll
    for (int n = 0; n < 4; ++n) accI[m][n] = f32x4{0.f, 0.f, 0.f, 0.f};
    accD[m] = f32x4{0.f, 0.f, 0.f, 0.f};
#pragma unroll
    for (int n = 0; n < 8; ++n) accP[m][n] = f32x4{0.f, 0.f, 0.f, 0.f};
  }
  for (int k9 = 0; k9 < 9; ++k9) {
    int cur = k9 & 1;
    if (k9 < 8) {
      stageK(cur ^ 1, (k9 + 1) * 32);
      asm volatile("s_waitcnt vmcnt(2)" ::: "memory");
    } else {
      asm volatile("s_waitcnt vmcnt(0)" ::: "memory");
    }
    __builtin_amdgcn_s_barrier();
    asm volatile("" ::: "memory");
    int kb = k9 * 32 + (rq << 3);
    bf16x8 af[2];
#pragma unroll
    for (int mf = 0; mf < 2; ++mf)
      af[mf] = *(const bf16x8*)(Arow + (size_t)(mf * 16 + cl) * NRFP + kb);
    bf16x8 bvD = {0, 0, 0, 0, 0, 0, 0, 0};
    if (cl == 0) bvD = *(const bf16x8*)(krow + kb);
#pragma unroll
    for (int mf = 0; mf < 2; ++mf)
      accD[mf] = __builtin_amdgcn_mfma_f32_16x16x32_bf16(af[mf], bvD, accD[mf], 0, 0, 0);
#pragma unroll
    for (int nf = 0; nf < 4; ++nf) {
      int row = nf * 16 + cl;
      bf16x8 bv = *(const bf16x8*)&SP[row * SROW + (kb ^ ((cl & 7) << 3))];
#pragma unroll
      for (int mf = 0; mf < 2; ++mf)
        accI[mf][nf] = __builtin_amdgcn_mfma_f32_16x16x32_bf16(af[mf], bv,
                                                               accI[mf][nf], 0, 0, 0);
    }
    const short* kcur = &Kb2[cur][0];
#pragma unroll
    for (int nf = 0; nf < 8; ++nf) {
      int row = nf * 16 + cl;
      bf16x8 bv = *(const bf16x8*)&kcur[row * 32 + ((rq ^ (cl & 3)) << 3)];
#pragma unroll
      for (int mf = 0; mf < 2; ++mf)
        accP[mf][nf] = __builtin_amdgcn_mfma_f32_16x16x32_bf16(af[mf], bv,
                                                               accP[mf][nf], 0, 0, 0);
    }
    __builtin_amdgcn_s_barrier();
    asm volatile("" ::: "memory");
  }

  float dtot[2][4];
#pragma unroll
  for (int mf = 0; mf < 2; ++mf)
#pragma unroll
    for (int r = 0; r < 4; ++r) {
      int rl = mf * 16 + (rq << 2) + r;
      int row = i0 + rl;
      float dsum = 0.f;
#pragma unroll
      for (int nf = 0; nf < 8; ++nf) {
        int col = nf * 16 + cl;
        float v = (col > row) ? 0.f : accP[mf][nf][r];
        dsum += v;
        SP[wid * 32 * PST + rl * PST + col] = f2bs(v);
      }
      dsum += __shfl_xor(dsum, 1);
      dsum += __shfl_xor(dsum, 2);
      dsum += __shfl_xor(dsum, 4);
      dsum += __shfl_xor(dsum, 8);
      float dden = __shfl(accD[mf][r], lane & 48);
      dtot[mf][r] = dden + dsum;
    }
  __syncthreads();

  f32x4 pacc[2][4];
#pragma unroll
  for (int m = 0; m < 2; ++m)
#pragma unroll
    for (int n = 0; n < 4; ++n) pacc[m][n] = f32x4{0.f, 0.f, 0.f, 0.f};
#pragma unroll
  for (int kk = 0; kk < 4; ++kk) {
    int kb = kk * 32 + (rq << 3);
    bf16x8 paf[2];
#pragma unroll
    for (int mf = 0; mf < 2; ++mf)
      paf[mf] = *(const bf16x8*)&SP[wid * 32 * PST + (mf * 16 + cl) * PST + kb];
#pragma unroll
    for (int nf = 0; nf < 4; ++nf) {
      bf16x8 bv = *(const bf16x8*)&Vt[(nf * 16 + cl) * PST + kb];
#pragma unroll
      for (int mf = 0; mf < 2; ++mf)
        pacc[mf][nf] = __builtin_amdgcn_mfma_f32_16x16x32_bf16(paf[mf], bv,
                                                               pacc[mf][nf], 0, 0, 0);
    }
  }
#pragma unroll
  for (int mf = 0; mf < 2; ++mf)
#pragma unroll
    for (int r = 0; r < 4; ++r) {
      int row = i0 + mf * 16 + (rq << 2) + r;
      float inv = 1.0f / dtot[mf][r];
      size_t ob = ((size_t)b * SEQ + (size_t)c * CHK + row) * DMODEL + h * HD;
#pragma unroll
      for (int nf = 0; nf < 4; ++nf) {
        int d = nf * 16 + cl;
        float v = (accI[mf][nf][r] + pacc[mf][nf][r]) * inv;
        ctxb[ob + d] = f2bs(v);
      }
    }
}

// ---------------- launch ----------------
extern "C" void kernel_launch(void* const* d_in, const int* in_sizes, int n_in,
                              void* d_out, int out_size, void* d_ws, size_t ws_size,
                              hipStream_t stream) {
  (void)in_sizes; (void)n_in; (void)out_size;
  const float* query = (const float*)d_in[0];
  const float* key_  = (const float*)d_in[1];
  const float* value = (const float*)d_in[2];
  const float* Wq = (const float*)d_in[3];
  const float* bq = (const float*)d_in[4];
  const float* Wk = (const float*)d_in[5];
  const float* bk = (const float*)d_in[6];
  const float* Wv = (const float*)d_in[7];
  const float* bv = (const float*)d_in[8];
  const float* Wo = (const float*)d_in[9];
  const float* bo = (const float*)d_in[10];
  const float* rf = (const float*)d_in[11];

  constexpr size_t SZ_INBF = (size_t)NROWS * DMODEL * 2;
  constexpr size_t SZ_QP   = (size_t)NBH * SEQ * NRFP * 2;
  constexpr size_t SZ_WT   = (size_t)DMODEL * DMODEL * 2;
  constexpr size_t SZ_SCH  = (size_t)NBH * NCH * HD * SROW * 2;
  constexpr size_t SZ_KS   = (size_t)NBH * NCH * NRF * 4;
  constexpr size_t SZ_KSB  = (size_t)NBH * NCH * NRFP * 2;
  constexpr size_t SZ_RFB  = (size_t)NRFP * HD * 2;

  constexpr size_t O_QP   = 0;
  constexpr size_t O_KP   = O_QP + SZ_QP;
  constexpr size_t O_WT   = O_KP + SZ_QP;
  constexpr size_t O_QPR  = O_WT + 4 * SZ_WT;
  constexpr size_t O_SCH  = O_QPR + 3 * SZ_INBF;
  constexpr size_t O_SPR  = O_SCH + SZ_SCH;
  constexpr size_t O_KSUM = O_SPR + SZ_SCH;
  constexpr size_t O_KSB  = O_KSUM + SZ_KS;
  constexpr size_t O_CTXB = O_KSB + SZ_KSB;
  constexpr size_t O_RFB  = O_CTXB + SZ_INBF;
  constexpr size_t O_END  = O_RFB + SZ_RFB;
  if (ws_size < O_END) return;

  char* w = (char*)d_ws;
  short* Qbf  = (short*)(w + O_QP);
  short* Qp   = (short*)(w + O_QP);
  short* Kp   = (short*)(w + O_KP);
  short* WtB  = (short*)(w + O_WT);
  short* QprB = (short*)(w + O_QPR);
  short* Kpr  = (short*)(w + O_QPR + SZ_INBF);
  short* Vpr  = (short*)(w + O_QPR + 2 * SZ_INBF);
  short* Sct  = (short*)(w + O_SCH);
  short* Spt  = (short*)(w + O_SPR);
  float* ksum = (float*)(w + O_KSUM);
  short* ksb  = (short*)(w + O_KSB);
  short* ctxb = (short*)(w + O_CTXB);
  short* rfb  = (short*)(w + O_RFB);

  prep_kernel<<<dim3(64, 32, 5), 256, 0, stream>>>(query, key_, value, Wq, Wk, Wv,
                                                   Wo, rf, Qbf, WtB, rfb);
  gemm_qkv3<<<dim3(16, 32, 3), 256, 0, stream>>>(Qbf, WtB, bq, bk, bv, QprB);
  featmap_mfma<<<dim3(SEQ / 128, NBH, 2), 256, 0, stream>>>(QprB, Kpr, rfb, Qp, Kp);
  chunksum_mfma<<<dim3(NCH, NBH), 256, 0, stream>>>(Kp, Vpr, Sct, ksum);
  prefix_all<<<dim3(81, NBH), 256, 0, stream>>>(Sct, Spt, ksum, ksb);
  attn_mfma<<<dim3(NCH, NBH), 256, 0, stream>>>(Qp, Kp, Vpr, Spt, ksb, ctxb);
  gemm_out<<<dim3(16, 32), 256, 0, stream>>>(ctxb, WtB + 3 * (size_t)DMODEL * DMODEL,
                                             bo, (float*)d_out);
}

// Round 20
// 151.073 us; speedup vs baseline: 1.2644x; 1.0459x over previous
//
#include <hip/hip_runtime.h>
#include <hip/hip_bf16.h>

#define BATCH 2
#define SEQ 2048
#define DMODEL 1024
#define NH 16
#define HD 64
#define NRF 266
#define NRFP 288   // padded feature dim (multiple of 32), cols [266,288) are zero
#define SROW 320   // transposed-S row stride
#define CHK 128
#define NCH 16
#define NBH 32
#define NROWS 4096  // BATCH*SEQ

constexpr float SCAL = 0.17677669529663687f;   // DMODEL^-0.25
constexpr float SCAL2 = 0.03125f;              // SCAL^2 = DMODEL^-0.5
constexpr float LN_CNORM = -2.7917480361965505f;   // ln(1/sqrt(266))
constexpr float CKEPS = 6.131393094576169e-6f;     // CNORM*KEPS

typedef short bf16x8 __attribute__((ext_vector_type(8)));
typedef float f32x4 __attribute__((ext_vector_type(4)));

__device__ __forceinline__ short f2bs(float v) {
  __hip_bfloat16 h = __float2bfloat16(v);
  return *reinterpret_cast<short*>(&h);
}
__device__ __forceinline__ float bs2f(short s) {
  __hip_bfloat16 h;
  *reinterpret_cast<short*>(&h) = s;
  return __bfloat162float(h);
}
__device__ __forceinline__ void gload_lds16(const void* g, void* l) {
  __builtin_amdgcn_global_load_lds(
      (const __attribute__((address_space(1))) void*)g,
      (__attribute__((address_space(3))) void*)l, 16, 0, 0);
}

// ---------------- fused prep: cvt q/k/v (z<3, + rf on z==0), W transposes (z==3,4) ----------------
__global__ __launch_bounds__(256) void prep_kernel(
    const float* __restrict__ q, const float* __restrict__ k,
    const float* __restrict__ v, const float* __restrict__ Wq,
    const float* __restrict__ Wk, const float* __restrict__ Wv,
    const float* __restrict__ Wo, const float* __restrict__ rf,
    short* __restrict__ out, short* __restrict__ WtBase, short* __restrict__ rfb) {
  int z = blockIdx.z;
  int tid = threadIdx.x;
  if (z < 3) {
    const float* x = (z == 0) ? q : (z == 1) ? k : v;
    short* y = out + (size_t)z * NROWS * DMODEL;
    int bid = blockIdx.y * 64 + blockIdx.x;  // 0..2047
    int i = bid * 2048 + tid * 8;
    float4 a = *(const float4*)&x[i];
    float4 b = *(const float4*)&x[i + 4];
    bf16x8 o;
    o[0] = f2bs(a.x); o[1] = f2bs(a.y); o[2] = f2bs(a.z); o[3] = f2bs(a.w);
    o[4] = f2bs(b.x); o[5] = f2bs(b.y); o[6] = f2bs(b.z); o[7] = f2bs(b.w);
    *(bf16x8*)&y[i] = o;
    if (z == 0 && bid < 72) {
      int idx = bid * 256 + tid;
      rfb[idx] = (idx < NRF * HD) ? f2bs(rf[idx] * SCAL) : (short)0;
    }
    return;
  }
  __shared__ float t[32][33];
  int wsel = (z - 3) * 2 + (blockIdx.x >> 5);
  const float* W = (wsel == 0) ? Wq : (wsel == 1) ? Wk : (wsel == 2) ? Wv : Wo;
  short* Wt = WtBase + (size_t)wsel * DMODEL * DMODEL;
  int k0 = blockIdx.y << 5, n0 = (blockIdx.x & 31) << 5;
  int tx = tid & 31, ty = tid >> 5;
#pragma unroll
  for (int rr = 0; rr < 4; ++rr) {
    int r = ty + (rr << 3);
    t[r][tx] = W[(size_t)(k0 + r) * DMODEL + n0 + tx];
  }
  __syncthreads();
#pragma unroll
  for (int rr = 0; rr < 4; ++rr) {
    int r = ty + (rr << 3);
    Wt[(size_t)(n0 + r) * DMODEL + k0 + tx] = f2bs(t[tx][r]);
  }
}

// ---------------- GEMM body 128x64, BK=64, dbuf + counted vmcnt (caller-provided smem) ----------------
// smem layout (shorts): As0 [0,8192) As1 [8192,16384) Bs0 [16384,20480) Bs1 [20480,24576)
template <bool OUTBF>
__device__ __forceinline__ void gemm64_body(short* smem, const short* __restrict__ A,
                                            const short* __restrict__ Bt,
                                            const float* __restrict__ bias,
                                            void* __restrict__ C, int bm, int bn,
                                            f32x4 (&acc)[4][2], bool writeC) {
  int tid = threadIdx.x;
  int lane = tid & 63, wid = tid >> 6;
  int wr = wid >> 1, wc = wid & 1;
#pragma unroll
  for (int m = 0; m < 4; ++m)
#pragma unroll
    for (int n = 0; n < 2; ++n) acc[m][n] = f32x4{0.f, 0.f, 0.f, 0.f};

  size_t abase[4], bbase[2];
#pragma unroll
  for (int i = 0; i < 4; ++i) {
    int e = tid * 8 + i * 2048;
    int row = e >> 6;
    int k = (e & 63) ^ ((row & 7) << 3);
    abase[i] = (size_t)(bm + row) * DMODEL + k;
    if (i < 2) bbase[i] = (size_t)(bn + row) * DMODEL + k;
  }
  auto stage = [&](int buf, int k0) {
#pragma unroll
    for (int i = 0; i < 4; ++i)
      gload_lds16(A + abase[i] + k0, smem + buf * 8192 + wid * 512 + i * 2048);
#pragma unroll
    for (int i = 0; i < 2; ++i)
      gload_lds16(Bt + bbase[i] + k0, smem + 16384 + buf * 4096 + wid * 512 + i * 2048);
  };

  stage(0, 0);
#pragma unroll 2
  for (int t = 0; t < 16; ++t) {
    int cur = t & 1;
    if (t < 15) {
      stage(cur ^ 1, (t + 1) * 64);
      asm volatile("s_waitcnt vmcnt(6)" ::: "memory");
    } else {
      asm volatile("s_waitcnt vmcnt(0)" ::: "memory");
    }
    __builtin_amdgcn_s_barrier();
    asm volatile("" ::: "memory");
    const short* curA = smem + cur * 8192;
    const short* curB = smem + 16384 + cur * 4096;
#pragma unroll
    for (int ks = 0; ks < 2; ++ks) {
      int kb = ks * 32 + ((lane >> 4) << 3);
      bf16x8 af[4], bfv[2];
#pragma unroll
      for (int mf = 0; mf < 4; ++mf) {
        int row = wr * 64 + mf * 16 + (lane & 15);
        af[mf] = *(const bf16x8*)&curA[row * 64 + (kb ^ ((row & 7) << 3))];
      }
#pragma unroll
      for (int nf = 0; nf < 2; ++nf) {
        int row = wc * 32 + nf * 16 + (lane & 15);
        bfv[nf] = *(const bf16x8*)&curB[row * 64 + (kb ^ ((row & 7) << 3))];
      }
#pragma unroll
      for (int mf = 0; mf < 4; ++mf)
#pragma unroll
        for (int nf = 0; nf < 2; ++nf)
          acc[mf][nf] = __builtin_amdgcn_mfma_f32_16x16x32_bf16(af[mf], bfv[nf],
                                                                acc[mf][nf], 0, 0, 0);
    }
    __builtin_amdgcn_s_barrier();
    asm volatile("" ::: "memory");
  }
  if (!writeC) return;
  int rbase = bm + wr * 64 + ((lane >> 4) << 2);
  int cbase = bn + wc * 32 + (lane & 15);
#pragma unroll
  for (int nf = 0; nf < 2; ++nf) {
    int col = cbase + nf * 16;
    float bv = bias[col];
#pragma unroll
    for (int mf = 0; mf < 4; ++mf)
#pragma unroll
      for (int r = 0; r < 4; ++r) {
        int row = rbase + mf * 16 + r;
        float v = acc[mf][nf][r] + bv;
        if (OUTBF)
          ((short*)C)[(size_t)row * DMODEL + col] = f2bs(v);
        else
          ((float*)C)[(size_t)row * DMODEL + col] = v;
      }
  }
}

// ---------------- FUSED QKV projection + feature map ----------------
// grid (16, 32, 3). z==2: plain V projection. z<2: GEMM -> featmap -> Q'/K' direct.
__global__ __launch_bounds__(256) void gemm_qkvf(
    const short* __restrict__ Abase, const short* __restrict__ WtBase,
    const float* __restrict__ bq, const float* __restrict__ bk,
    const float* __restrict__ bv, const short* __restrict__ rfb,
    short* __restrict__ Vpr, short* __restrict__ Qp, short* __restrict__ Kp) {
  __shared__ short smem[24576];  // 48KB: gemm dbuf -> At/Rf -> Ps
  __shared__ float hk2[2][128];
  __shared__ float hks[128];
  int z = blockIdx.z;
  const short* A = Abase + (size_t)z * NROWS * DMODEL;
  const short* Bt = WtBase + (size_t)z * DMODEL * DMODEL;
  int bid = blockIdx.x + (blockIdx.y << 4);
  int swz = ((bid & 7) << 6) + (bid >> 3);
  int bn = (swz & 15) << 6;
  int bm = (swz >> 4) << 7;
  f32x4 acc[4][2];
  if (z == 2) {
    gemm64_body<true>(smem, A, Bt, bv, Vpr, bm, bn, acc, true);
    return;
  }
  const float* bias = z ? bk : bq;
  short* O = z ? Kp : Qp;
  gemm64_body<true>(smem, A, Bt, bias, nullptr, bm, bn, acc, false);
  // all waves past final barrier -> staging bufs dead; overlay At/Rf
  short* At = smem;         // [128][72]
  short* Rf = smem + 9216;  // [144][64] rfb half, swizzled
  int tid = threadIdx.x, lane = tid & 63, wid = tid >> 6;
  int cl = lane & 15, rq = lane >> 4;
  int wr = wid >> 1, wc = wid & 1;
  int wrs = wr * 64 + (rq << 2);  // local row base of this lane's acc rows
#pragma unroll
  for (int nf = 0; nf < 2; ++nf) {
    int col = wc * 32 + nf * 16 + cl;
    float bv = bias[bn + col];
#pragma unroll
    for (int mf = 0; mf < 4; ++mf)
#pragma unroll
      for (int r = 0; r < 4; ++r)
        At[(wrs + mf * 16 + r) * 72 + col] = f2bs(acc[mf][nf][r] + bv);
  }
  if (z == 1) {  // hk partials: per-row sum of squares over this wave's 32 cols
    float b0 = bias[bn + wc * 32 + cl], b1 = bias[bn + wc * 32 + 16 + cl];
#pragma unroll
    for (int mf = 0; mf < 4; ++mf)
#pragma unroll
      for (int r = 0; r < 4; ++r) {
        float v0 = acc[mf][0][r] + b0;
        float v1 = acc[mf][1][r] + b1;
        float ss = v0 * v0 + v1 * v1;
        ss += __shfl_xor(ss, 1);
        ss += __shfl_xor(ss, 2);
        ss += __shfl_xor(ss, 4);
        ss += __shfl_xor(ss, 8);
        if (cl == 0) hk2[wc][wrs + mf * 16 + r] = ss;
      }
  }
  __syncthreads();
  if (z == 1 && tid < 128)
    hks[tid] = -0.5f * SCAL2 * (hk2[0][tid] + hk2[1][tid]) + LN_CNORM;

  // featmap MFMAs: wave owns rows i0f..i0f+31 x 288 cols, rfb staged in halves
  int i0f = wid * 32;
  f32x4 fa[2][18];
#pragma unroll
  for (int m = 0; m < 2; ++m)
#pragma unroll
    for (int n = 0; n < 18; ++n) fa[m][n] = f32x4{0.f, 0.f, 0.f, 0.f};
#pragma unroll
  for (int hf = 0; hf < 2; ++hf) {
    if (hf) __syncthreads();  // previous half's Rf reads done
#pragma unroll
    for (int i = 0; i < 4; ++i) {
      int ch = tid + i * 256;
      int row = ch >> 3, c8 = ch & 7;
      gload_lds16(rfb + (size_t)(hf * 144 + row) * HD + ((c8 ^ (row & 7)) << 3),
                  Rf + (wid * 512 + i * 2048));
    }
    if (tid < 128) {
      int ch = 1024 + tid;
      int row = ch >> 3, c8 = ch & 7;
      gload_lds16(rfb + (size_t)(hf * 144 + row) * HD + ((c8 ^ (row & 7)) << 3),
                  Rf + (1024 * 8 + (tid >> 6) * 512 + ((tid & 63) << 3)));
    }
    asm volatile("s_waitcnt vmcnt(0)" ::: "memory");
    __builtin_amdgcn_s_barrier();
    asm volatile("" ::: "memory");
#pragma unroll
    for (int ks = 0; ks < 2; ++ks) {
      int kb = ks * 32 + (rq << 3);
      bf16x8 af[2];
#pragma unroll
      for (int mf = 0; mf < 2; ++mf)
        af[mf] = *(const bf16x8*)&At[(i0f + mf * 16 + cl) * 72 + kb];
#pragma unroll
      for (int nf = 0; nf < 9; ++nf) {
        int brow = nf * 16 + cl;
        bf16x8 bv = *(const bf16x8*)&Rf[brow * 64 + (kb ^ ((cl & 7) << 3))];
#pragma unroll
        for (int mf = 0; mf < 2; ++mf)
          fa[mf][hf * 9 + nf] = __builtin_amdgcn_mfma_f32_16x16x32_bf16(
              af[mf], bv, fa[mf][hf * 9 + nf], 0, 0, 0);
      }
    }
  }

  // exp epilogue via Ps bounce (overwrites At/Rf)
  int bh = ((bm >> 11) * NH) + (bn >> 6);
  int l0 = bm & (SEQ - 1);
  short* Ps = smem;  // [128][152]
#pragma unroll
  for (int hf = 0; hf < 2; ++hf) {
    __syncthreads();
#pragma unroll
    for (int mf = 0; mf < 2; ++mf)
#pragma unroll
      for (int r = 0; r < 4; ++r) {
        int rl = i0f + mf * 16 + (rq << 2) + r;
        float addk = z ? hks[rl] : LN_CNORM;
#pragma unroll
        for (int nf2 = 0; nf2 < 9; ++nf2) {
          int m = hf * 144 + nf2 * 16 + cl;
          float v = fa[mf][hf * 9 + nf2][r] + addk;
          float o = (m < NRF) ? (__expf(v) + CKEPS) : 0.f;
          Ps[rl * 152 + nf2 * 16 + cl] = f2bs(o);
        }
      }
    __syncthreads();
#pragma unroll
    for (int it = 0; it < 9; ++it) {
      int idx = tid + it * 256;
      int row = idx / 18, ch = idx - row * 18;
      bf16x8 val = *(const bf16x8*)&Ps[row * 152 + ch * 8];
      *(bf16x8*)&O[((size_t)bh * SEQ + l0 + row) * NRFP + hf * 144 + ch * 8] = val;
    }
  }
}

// output projection: grid (16, 32), 128x64 tile, XCD-swizzled
__global__ __launch_bounds__(256) void gemm_out(const short* __restrict__ A,
                                                const short* __restrict__ Bt,
                                                const float* __restrict__ bias,
                                                float* __restrict__ C) {
  __shared__ short smem[24576];
  int bid = blockIdx.x + (blockIdx.y << 4);  // nwg=512
  int swz = ((bid & 7) << 6) + (bid >> 3);
  int bn = (swz & 15) << 6;
  int bm = (swz >> 4) << 7;
  f32x4 acc[4][2];
  gemm64_body<false>(smem, A, Bt, bias, C, bm, bn, acc, true);
}

// ---------------- per-chunk sums via MFMA -> Sct TRANSPOSED [bh][c][d][SROW] bf16 ----------------
__global__ __launch_bounds__(256) void chunksum_mfma(
    const short* __restrict__ Kp, const short* __restrict__ Vb,
    short* __restrict__ Sct, float* __restrict__ ksum) {
  constexpr int ST = 70;
  __shared__ short KT[NRFP * ST];  // [m][i_loc]
  __shared__ short VT[HD * ST];    // [d][i_loc]
  int c = blockIdx.x, bh = blockIdx.y;
  int b = bh >> 4, h = bh & 15;
  int tid = threadIdx.x, lane = tid & 63, wv = tid >> 6;
  int cl = lane & 15, rq = lane >> 4;
  int irow = tid >> 2;
  int mq = tid & 3;
  size_t rowb = (size_t)bh * SEQ + (size_t)c * CHK;

  f32x4 acc[18];
#pragma unroll
  for (int m = 0; m < 18; ++m) acc[m] = f32x4{0.f, 0.f, 0.f, 0.f};
  float k1 = 0.f, k2 = 0.f;

  for (int hf = 0; hf < 2; ++hf) {
    __syncthreads();
    const short* Krow = Kp + (rowb + hf * 64 + irow) * NRFP;
#pragma unroll
    for (int cg = 0; cg < 9; ++cg) {
      int m0 = cg * 32 + mq * 8;
      bf16x8 v = *(const bf16x8*)(Krow + m0);
#pragma unroll
      for (int e = 0; e < 8; ++e) KT[(m0 + e) * ST + irow] = v[e];
    }
    const short* Vrow =
        Vb + ((size_t)b * SEQ + (size_t)c * CHK + hf * 64 + irow) * DMODEL + h * HD;
    {
      int d0 = mq * 16;
      bf16x8 v0 = *(const bf16x8*)(Vrow + d0);
      bf16x8 v1 = *(const bf16x8*)(Vrow + d0 + 8);
#pragma unroll
      for (int e = 0; e < 8; ++e) VT[(d0 + e) * ST + irow] = v0[e];
#pragma unroll
      for (int e = 0; e < 8; ++e) VT[(d0 + 8 + e) * ST + irow] = v1[e];
    }
    __syncthreads();
#pragma unroll
    for (int ks = 0; ks < 2; ++ks) {
      int kb = ks * 32 + rq * 8;
      bf16x8 bv = *(const bf16x8*)&VT[(wv * 16 + cl) * ST + kb];
#pragma unroll
      for (int mf = 0; mf < 18; ++mf) {
        bf16x8 av = *(const bf16x8*)&KT[(mf * 16 + cl) * ST + kb];
        acc[mf] = __builtin_amdgcn_mfma_f32_16x16x32_bf16(av, bv, acc[mf], 0, 0, 0);
      }
    }
    {
      const short* r1 = &KT[tid * ST];
#pragma unroll
      for (int g = 0; g < 8; ++g) {
        bf16x8 v = *(const bf16x8*)(r1 + g * 8);
#pragma unroll
        for (int e = 0; e < 8; ++e) k1 += bs2f(v[e]);
      }
      if (tid < 10) {
        const short* r2 = &KT[(256 + tid) * ST];
#pragma unroll
        for (int g = 0; g < 8; ++g) {
          bf16x8 v = *(const bf16x8*)(r2 + g * 8);
#pragma unroll
          for (int e = 0; e < 8; ++e) k2 += bs2f(v[e]);
        }
      }
    }
  }
  size_t sbase = ((size_t)bh * NCH + c) * (size_t)(HD * SROW);
  int d = wv * 16 + cl;
#pragma unroll
  for (int mf = 0; mf < 18; ++mf) {
    short4 o4 = make_short4(f2bs(acc[mf][0]), f2bs(acc[mf][1]),
                            f2bs(acc[mf][2]), f2bs(acc[mf][3]));
    *(short4*)&Sct[sbase + (size_t)d * SROW + mf * 16 + rq * 4] = o4;
  }
  size_t kbase = ((size_t)bh * NCH + c) * (size_t)NRF;
  if (tid < NRF) ksum[kbase + tid] = k1;
  if (tid < 10) ksum[kbase + 256 + tid] = k2;
}

// ---------------- fused exclusive prefixes over chunks (pad cols written as zero) ----------------
__global__ __launch_bounds__(256) void prefix_all(const short* __restrict__ Sct,
                                                  short* __restrict__ Spt,
                                                  const float* __restrict__ ksum,
                                                  short* __restrict__ ksb) {
  int bh = blockIdx.y;
  if (blockIdx.x == 80) {
    for (int m = threadIdx.x; m < NRFP; m += 256) {
      if (m < NRF) {
        size_t base = (size_t)bh * NCH * NRF + m;
        float a = 0.f;
#pragma unroll
        for (int c = 0; c < NCH; ++c) {
          float v = ksum[base + (size_t)c * NRF];
          ksb[((size_t)bh * NCH + c) * NRFP + m] = f2bs(a);
          a += v;
        }
      } else {
#pragma unroll
        for (int c = 0; c < NCH; ++c)
          ksb[((size_t)bh * NCH + c) * NRFP + m] = 0;
      }
    }
    return;
  }
  int e = blockIdx.x * 256 + threadIdx.x;  // over 64*SROW = 20480 (80 blocks exact)
  int col = e % SROW;
  if (col >= NRFP) {
#pragma unroll
    for (int c = 0; c < NCH; ++c)
      Spt[((size_t)bh * NCH + c) * (size_t)(HD * SROW) + e] = 0;
    return;
  }
  float a = 0.f;
#pragma unroll
  for (int c = 0; c < NCH; ++c) {
    size_t idx = ((size_t)bh * NCH + c) * (size_t)(HD * SROW) + e;
    float v = bs2f(Sct[idx]);
    Spt[idx] = f2bs(a);
    a += v;
  }
}

// ---------------- FUSED inter+intra: LDS-staged K (dbuf, counted vmcnt) ----------------
__global__ __launch_bounds__(256) void attn_mfma(
    const short* __restrict__ Qp, const short* __restrict__ Kp,
    const short* __restrict__ Vb, const short* __restrict__ Spt,
    const short* __restrict__ ksb, short* __restrict__ ctxb) {
  constexpr int PST = 136;
  __shared__ short Vt[64 * PST];      // V^T [d][j]
  __shared__ short SP[64 * SROW];     // Sp^T (swizzled) -> later P region
  __shared__ short Kb2[2][128 * 32];  // K' slice dbuf
  int c = blockIdx.x, bh = blockIdx.y;
  int b = bh >> 4, h = bh & 15;
  int tid = threadIdx.x, lane = tid & 63, wid = tid >> 6;
  int cl = lane & 15, rq = lane >> 4;
  size_t rowb = (size_t)bh * SEQ + (size_t)c * CHK;

  {
    int jj = tid >> 3, d0 = (tid & 7) << 3;
#pragma unroll
    for (int jt = 0; jt < 4; ++jt) {
      int j = jj + jt * 32;
      bf16x8 v = *(const bf16x8*)(Vb + ((size_t)b * SEQ + (size_t)c * CHK + j) * DMODEL +
                                  h * HD + d0);
#pragma unroll
      for (int e = 0; e < 8; ++e) Vt[(d0 + e) * PST + j] = v[e];
    }
  }
  const short* sg = Spt + ((size_t)bh * NCH + c) * (size_t)(HD * SROW);
#pragma unroll
  for (int i = 0; i < 10; ++i) {
    int o = tid * 8 + i * 2048;
    int d = o / SROW;
    int m = o - d * SROW;
    int ms = m ^ ((d & 7) << 3);
    gload_lds16(sg + (size_t)d * SROW + ms, &SP[wid * 512 + i * 2048]);
  }
  const short* Kbase = Kp + rowb * NRFP;
  auto stageK = [&](int buf, int k0) {
#pragma unroll
    for (int i = 0; i < 2; ++i) {
      int chunk = tid + i * 256;
      int row = chunk >> 2, cc = chunk & 3;
      int col = k0 + ((cc ^ (row & 3)) << 3);
      gload_lds16(Kbase + (size_t)row * NRFP + col,
                  &Kb2[buf][(wid * 64 + i * 256) * 8]);
    }
  };
  stageK(0, 0);

  int i0 = wid * 32;
  const short* Arow = Qp + (rowb + i0) * NRFP;
  const short* krow = ksb + ((size_t)bh * NCH + c) * NRFP;
  f32x4 accI[2][4];
  f32x4 accD[2];
  f32x4 accP[2][8];
#pragma unroll
  for (int m = 0; m < 2; ++m) {
#pragma unroll
    for (int n = 0; n < 4; ++n) accI[m][n] = f32x4{0.f, 0.f, 0.f, 0.f};
    accD[m] = f32x4{0.f, 0.f, 0.f, 0.f};
#pragma unroll
    for (int n = 0; n < 8; ++n) accP[m][n] = f32x4{0.f, 0.f, 0.f, 0.f};
  }
  for (int k9 = 0; k9 < 9; ++k9) {
    int cur = k9 & 1;
    if (k9 < 8) {
      stageK(cur ^ 1, (k9 + 1) * 32);
      asm volatile("s_waitcnt vmcnt(2)" ::: "memory");
    } else {
      asm volatile("s_waitcnt vmcnt(0)" ::: "memory");
    }
    __builtin_amdgcn_s_barrier();
    asm volatile("" ::: "memory");
    int kb = k9 * 32 + (rq << 3);
    bf16x8 af[2];
#pragma unroll
    for (int mf = 0; mf < 2; ++mf)
      af[mf] = *(const bf16x8*)(Arow + (size_t)(mf * 16 + cl) * NRFP + kb);
    bf16x8 bvD = {0, 0, 0, 0, 0, 0, 0, 0};
    if (cl == 0) bvD = *(const bf16x8*)(krow + kb);
#pragma unroll
    for (int mf = 0; mf < 2; ++mf)
      accD[mf] = __builtin_amdgcn_mfma_f32_16x16x32_bf16(af[mf], bvD, accD[mf], 0, 0, 0);
#pragma unroll
    for (int nf = 0; nf < 4; ++nf) {
      int row = nf * 16 + cl;
      bf16x8 bv = *(const bf16x8*)&SP[row * SROW + (kb ^ ((cl & 7) << 3))];
#pragma unroll
      for (int mf = 0; mf < 2; ++mf)
        accI[mf][nf] = __builtin_amdgcn_mfma_f32_16x16x32_bf16(af[mf], bv,
                                                               accI[mf][nf], 0, 0, 0);
    }
    const short* kcur = &Kb2[cur][0];
#pragma unroll
    for (int nf = 0; nf < 8; ++nf) {
      int row = nf * 16 + cl;
      bf16x8 bv = *(const bf16x8*)&kcur[row * 32 + ((rq ^ (cl & 3)) << 3)];
#pragma unroll
      for (int mf = 0; mf < 2; ++mf)
        accP[mf][nf] = __builtin_amdgcn_mfma_f32_16x16x32_bf16(af[mf], bv,
                                                               accP[mf][nf], 0, 0, 0);
    }
    __builtin_amdgcn_s_barrier();
    asm volatile("" ::: "memory");
  }

  float dtot[2][4];
#pragma unroll
  for (int mf = 0; mf < 2; ++mf)
#pragma unroll
    for (int r = 0; r < 4; ++r) {
      int rl = mf * 16 + (rq << 2) + r;
      int row = i0 + rl;
      float dsum = 0.f;
#pragma unroll
      for (int nf = 0; nf < 8; ++nf) {
        int col = nf * 16 + cl;
        float v = (col > row) ? 0.f : accP[mf][nf][r];
        dsum += v;
        SP[wid * 32 * PST + rl * PST + col] = f2bs(v);
      }
      dsum += __shfl_xor(dsum, 1);
      dsum += __shfl_xor(dsum, 2);
      dsum += __shfl_xor(dsum, 4);
      dsum += __shfl_xor(dsum, 8);
      float dden = __shfl(accD[mf][r], lane & 48);
      dtot[mf][r] = dden + dsum;
    }
  __syncthreads();

  f32x4 pacc[2][4];
#pragma unroll
  for (int m = 0; m < 2; ++m)
#pragma unroll
    for (int n = 0; n < 4; ++n) pacc[m][n] = f32x4{0.f, 0.f, 0.f, 0.f};
#pragma unroll
  for (int kk = 0; kk < 4; ++kk) {
    int kb = kk * 32 + (rq << 3);
    bf16x8 paf[2];
#pragma unroll
    for (int mf = 0; mf < 2; ++mf)
      paf[mf] = *(const bf16x8*)&SP[wid * 32 * PST + (mf * 16 + cl) * PST + kb];
#pragma unroll
    for (int nf = 0; nf < 4; ++nf) {
      bf16x8 bv = *(const bf16x8*)&Vt[(nf * 16 + cl) * PST + kb];
#pragma unroll
      for (int mf = 0; mf < 2; ++mf)
        pacc[mf][nf] = __builtin_amdgcn_mfma_f32_16x16x32_bf16(paf[mf], bv,
                                                               pacc[mf][nf], 0, 0, 0);
    }
  }
#pragma unroll
  for (int mf = 0; mf < 2; ++mf)
#pragma unroll
    for (int r = 0; r < 4; ++r) {
      int row = i0 + mf * 16 + (rq << 2) + r;
      float inv = 1.0f / dtot[mf][r];
      size_t ob = ((size_t)b * SEQ + (size_t)c * CHK + row) * DMODEL + h * HD;
#pragma unroll
      for (int nf = 0; nf < 4; ++nf) {
        int d = nf * 16 + cl;
        float v = (accI[mf][nf][r] + pacc[mf][nf][r]) * inv;
        ctxb[ob + d] = f2bs(v);
      }
    }
}

// ---------------- launch ----------------
extern "C" void kernel_launch(void* const* d_in, const int* in_sizes, int n_in,
                              void* d_out, int out_size, void* d_ws, size_t ws_size,
                              hipStream_t stream) {
  (void)in_sizes; (void)n_in; (void)out_size;
  const float* query = (const float*)d_in[0];
  const float* key_  = (const float*)d_in[1];
  const float* value = (const float*)d_in[2];
  const float* Wq = (const float*)d_in[3];
  const float* bq = (const float*)d_in[4];
  const float* Wk = (const float*)d_in[5];
  const float* bk = (const float*)d_in[6];
  const float* Wv = (const float*)d_in[7];
  const float* bv = (const float*)d_in[8];
  const float* Wo = (const float*)d_in[9];
  const float* bo = (const float*)d_in[10];
  const float* rf = (const float*)d_in[11];

  constexpr size_t SZ_INBF = (size_t)NROWS * DMODEL * 2;
  constexpr size_t SZ_QP   = (size_t)NBH * SEQ * NRFP * 2;
  constexpr size_t SZ_WT   = (size_t)DMODEL * DMODEL * 2;
  constexpr size_t SZ_SCH  = (size_t)NBH * NCH * HD * SROW * 2;
  constexpr size_t SZ_KS   = (size_t)NBH * NCH * NRF * 4;
  constexpr size_t SZ_KSB  = (size_t)NBH * NCH * NRFP * 2;
  constexpr size_t SZ_RFB  = (size_t)NRFP * HD * 2;

  constexpr size_t O_QP   = 0;
  constexpr size_t O_KP   = O_QP + SZ_QP;
  constexpr size_t O_WT   = O_KP + SZ_QP;
  constexpr size_t O_QPR  = O_WT + 4 * SZ_WT;
  constexpr size_t O_SCH  = O_QPR + 3 * SZ_INBF;
  constexpr size_t O_SPR  = O_SCH + SZ_SCH;
  constexpr size_t O_KSUM = O_SPR + SZ_SCH;
  constexpr size_t O_KSB  = O_KSUM + SZ_KS;
  constexpr size_t O_CTXB = O_KSB + SZ_KSB;
  constexpr size_t O_RFB  = O_CTXB + SZ_INBF;
  constexpr size_t O_END  = O_RFB + SZ_RFB;
  if (ws_size < O_END) return;

  char* w = (char*)d_ws;
  short* Qbf  = (short*)(w + O_QP);   // bf16 inputs; overwritten by Qp after use
  short* Qp   = (short*)(w + O_QP);
  short* Kp   = (short*)(w + O_KP);
  short* WtB  = (short*)(w + O_WT);
  short* Vpr  = (short*)(w + O_QPR + 2 * SZ_INBF);
  short* Sct  = (short*)(w + O_SCH);
  short* Spt  = (short*)(w + O_SPR);
  float* ksum = (float*)(w + O_KSUM);
  short* ksb  = (short*)(w + O_KSB);
  short* ctxb = (short*)(w + O_CTXB);
  short* rfb  = (short*)(w + O_RFB);

  // NOTE: Qp overlays Qbf region. gemm_qkvf reads A (=Qbf/Kbf/Vbf) fully during its
  // GEMM phase before writing Qp rows of the same (bm,z) block; cross-block hazard:
  // a z=0 block writing Qp[bh][l0..] touches bytes of Qbf rows it already consumed
  // (row range [bm,bm+128) x full DMODEL vs write [bm rows][288 of one head]) --
  // but OTHER blocks (different bn, same bm) still need Qbf rows [bm,bm+128)!
  // So keep Qp SEPARATE from Qbf: use the (now unused) Qpr/Kpr region instead.
  Qp = (short*)(w + O_QPR);                 // reuse dead Qpr slot (16.78MB < SZ_QP? no)
  // SZ_QP (18.87MB) > SZ_INBF (8.39MB): Qp spans Qpr+Kpr slots? Qpr+Kpr = 16.78MB < 18.87MB.
  // Not enough. Keep original separate regions: Qp at O_QP requires Qbf elsewhere.
  // Simplest safe layout: inputs Qbf/Kbf/Vbf live in SCH region (dead until chunksum),
  // but chunksum runs after... SCH written by chunksum AFTER qkvf done -> safe.
  // => place Qbf at O_SCH (3*8.39=25.2MB <= SZ_SCH+SZ_SCH? SZ_SCH=20.97MB each, Spt adjacent).
  short* QbfX = (short*)(w + O_SCH);        // 25.2MB spans Sct(20.97)+start of Spt -- both
                                            // written only by chunksum/prefix (after qkvf).
  Qbf = QbfX;
  Qp  = (short*)(w + O_QP);

  prep_kernel<<<dim3(64, 32, 5), 256, 0, stream>>>(query, key_, value, Wq, Wk, Wv,
                                                   Wo, rf, Qbf, WtB, rfb);
  gemm_qkvf<<<dim3(16, 32, 3), 256, 0, stream>>>(Qbf, WtB, bq, bk, bv, rfb, Vpr,
                                                 Qp, Kp);
  chunksum_mfma<<<dim3(NCH, NBH), 256, 0, stream>>>(Kp, Vpr, Sct, ksum);
  prefix_all<<<dim3(81, NBH), 256, 0, stream>>>(Sct, Spt, ksum, ksb);
  attn_mfma<<<dim3(NCH, NBH), 256, 0, stream>>>(Qp, Kp, Vpr, Spt, ksb, ctxb);
  gemm_out<<<dim3(16, 32), 256, 0, stream>>>(ctxb, WtB + 3 * (size_t)DMODEL * DMODEL,
                                             bo, (float*)d_out);
}